// Round 11
// baseline (223.281 us; speedup 1.0000x reference)
//
#include <hip/hip_runtime.h>
#include <math.h>

#define NB 16
#define NT 512
#define NSZ 512
#define NH 8
#define NHD 64
#define MAXR 16

#define C_D0 6.3f
#define C_STD 1.4f
#define C_GAMMA 2.0f

#define NEGINF (-1e30f)
#define LOG2E 1.4426950408889634f
#define C1F   0.18033688011112042f   // 0.125 * log2(e)

typedef unsigned short u16;
typedef __attribute__((ext_vector_type(8))) short bf16x8;
typedef __attribute__((ext_vector_type(4))) float f32x4;
typedef __attribute__((ext_vector_type(8))) unsigned short u16x8;

__device__ __forceinline__ u16 f2b(float f) {
    union { float f; unsigned int u; } c; c.f = f;
    unsigned int u = c.u + 0x7FFFu + ((c.u >> 16) & 1u);
    return (u16)(u >> 16);
}
__device__ __forceinline__ float b2f(u16 h) {
    union { unsigned int u; float f; } c; c.u = ((unsigned int)h) << 16;
    return c.f;
}

#if __has_builtin(__builtin_amdgcn_exp2f)
__device__ __forceinline__ float exp2_fast(float x) { return __builtin_amdgcn_exp2f(x); }
#else
__device__ __forceinline__ float exp2_fast(float x) { return exp2f(x); }
#endif

#define GL2LDS(gp, lp) __builtin_amdgcn_global_load_lds( \
    (const __attribute__((address_space(1))) void*)(gp), \
    (__attribute__((address_space(3))) void*)(lp), 16, 0, 0)

// swizzled u16-index of 16B chunk c in row r (row = 8 chunks = 64 bf16)
#define SWU(r, c) ((((r) * 8) + ((c) ^ ((r) & 7))) * 8)

// ---------------------------------------------------------------------------
// fp32 -> bf16 convert (weights only)
// ---------------------------------------------------------------------------
__global__ __launch_bounds__(256) void cvt4_bf16(
    const float* __restrict__ s0, const float* __restrict__ s1,
    const float* __restrict__ s2, const float* __restrict__ s3,
    u16* __restrict__ d0, u16* __restrict__ d1,
    u16* __restrict__ d2, u16* __restrict__ d3, int n)
{
    const float* s; u16* d;
    switch (blockIdx.y) {
        case 0: s = s0; d = d0; break;
        case 1: s = s1; d = d1; break;
        case 2: s = s2; d = d2; break;
        default: s = s3; d = d3; break;
    }
    int i = (blockIdx.x * 256 + threadIdx.x) * 8;
    if (i >= n) return;
    float4 a = *(const float4*)&s[i];
    float4 b = *(const float4*)&s[i + 4];
    u16x8 v;
    v[0]=f2b(a.x); v[1]=f2b(a.y); v[2]=f2b(a.z); v[3]=f2b(a.w);
    v[4]=f2b(b.x); v[5]=f2b(b.y); v[6]=f2b(b.z); v[7]=f2b(b.w);
    *(u16x8*)&d[i] = v;
}

// ---------------------------------------------------------------------------
// QKV projections, z-batched. A fp32 reg-staged with in-flight bf16 convert.
// ---------------------------------------------------------------------------
__global__ __launch_bounds__(256) void gemm_qkv(
    const float* __restrict__ A0, const float* __restrict__ A1, const float* __restrict__ A2,
    const u16* __restrict__ Wc,
    const float* __restrict__ bq, const float* __restrict__ bk, const float* __restrict__ bv,
    u16* __restrict__ pkv)
{
    __shared__ u16 Al[128 * 32];
    __shared__ u16 Bl[128 * 32];
    const int z = blockIdx.z;
    const float* A = z == 0 ? A0 : (z == 1 ? A1 : A2);
    const u16* W = Wc + (size_t)z * NSZ * NSZ;
    const float* bias = z == 0 ? bq : (z == 1 ? bk : bv);
    const int tid = threadIdx.x;
    const int m0 = blockIdx.x * 128;
    const int n0 = blockIdx.y * 128;
    const int w = tid >> 6, lane = tid & 63;
    const int wm = (w >> 1) * 64, wn = (w & 1) * 64;
    const int fr = lane & 15, fk = lane >> 4;

    f32x4 acc[4][4] = {};
    for (int k0 = 0; k0 < NSZ; k0 += 32) {
        float4 a0[2], a1[2];
        #pragma unroll
        for (int p = 0; p < 2; ++p) {
            int s = tid + p * 256;
            int row = s >> 2, cb = s & 3;
            const float* ga = &A[(size_t)(m0 + row) * NSZ + k0 + cb * 8];
            a0[p] = *(const float4*)ga;
            a1[p] = *(const float4*)(ga + 4);
            GL2LDS(&W[(size_t)(n0 + row) * NSZ + k0 + cb * 8], &Bl[s * 8]);
        }
        #pragma unroll
        for (int p = 0; p < 2; ++p) {
            int s = tid + p * 256;
            u16x8 v;
            v[0]=f2b(a0[p].x); v[1]=f2b(a0[p].y); v[2]=f2b(a0[p].z); v[3]=f2b(a0[p].w);
            v[4]=f2b(a1[p].x); v[5]=f2b(a1[p].y); v[6]=f2b(a1[p].z); v[7]=f2b(a1[p].w);
            *(u16x8*)&Al[s * 8] = v;
        }
        __syncthreads();
        bf16x8 af[4], bfr[4];
        #pragma unroll
        for (int mf = 0; mf < 4; ++mf)
            af[mf] = *(const bf16x8*)&Al[(wm + mf * 16 + fr) * 32 + fk * 8];
        #pragma unroll
        for (int nf = 0; nf < 4; ++nf)
            bfr[nf] = *(const bf16x8*)&Bl[(wn + nf * 16 + fr) * 32 + fk * 8];
        #pragma unroll
        for (int mf = 0; mf < 4; ++mf)
            #pragma unroll
            for (int nf = 0; nf < 4; ++nf)
                acc[mf][nf] = __builtin_amdgcn_mfma_f32_16x16x32_bf16(
                    af[mf], bfr[nf], acc[mf][nf], 0, 0, 0);
        __syncthreads();
    }
    #pragma unroll
    for (int mf = 0; mf < 4; ++mf) {
        #pragma unroll
        for (int nf = 0; nf < 4; ++nf) {
            int col = n0 + wn + nf * 16 + fr;
            float bvv = bias[col];
            #pragma unroll
            for (int r = 0; r < 4; ++r) {
                int rowg = m0 + wm + mf * 16 + fk * 4 + r;
                pkv[(size_t)rowg * 1536 + z * 512 + col] = f2b(acc[mf][nf][r] + bvv);
            }
        }
    }
}

// ---------------------------------------------------------------------------
// Output projection (fp32 out). 64x128 tile, 2 blocks/CU.
// ---------------------------------------------------------------------------
__global__ __launch_bounds__(256) void gemm_out(
    const u16* __restrict__ A, const u16* __restrict__ W,
    const float* __restrict__ bias, float* __restrict__ Cout, int M, int N, int K)
{
    __shared__ u16 Al[64 * 32];
    __shared__ u16 Bl[128 * 32];
    const int tid = threadIdx.x;
    const int m0 = blockIdx.x * 64;
    const int n0 = blockIdx.y * 128;
    const int w = tid >> 6, lane = tid & 63;
    const int wm = (w >> 1) * 32, wn = (w & 1) * 64;
    const int fr = lane & 15, fk = lane >> 4;

    f32x4 acc[2][4] = {};
    for (int k0 = 0; k0 < K; k0 += 32) {
        {
            int row = tid >> 2, cb = tid & 3;
            GL2LDS(&A[(size_t)(m0 + row) * K + k0 + cb * 8], &Al[tid * 8]);
        }
        #pragma unroll
        for (int p = 0; p < 2; ++p) {
            int s = tid + p * 256;
            int row = s >> 2, cb = s & 3;
            GL2LDS(&W[(size_t)(n0 + row) * K + k0 + cb * 8], &Bl[s * 8]);
        }
        __syncthreads();
        bf16x8 af[2], bfr[4];
        #pragma unroll
        for (int mf = 0; mf < 2; ++mf)
            af[mf] = *(const bf16x8*)&Al[(wm + mf * 16 + fr) * 32 + fk * 8];
        #pragma unroll
        for (int nf = 0; nf < 4; ++nf)
            bfr[nf] = *(const bf16x8*)&Bl[(wn + nf * 16 + fr) * 32 + fk * 8];
        #pragma unroll
        for (int mf = 0; mf < 2; ++mf)
            #pragma unroll
            for (int nf = 0; nf < 4; ++nf)
                acc[mf][nf] = __builtin_amdgcn_mfma_f32_16x16x32_bf16(
                    af[mf], bfr[nf], acc[mf][nf], 0, 0, 0);
        __syncthreads();
    }
    #pragma unroll
    for (int mf = 0; mf < 2; ++mf) {
        #pragma unroll
        for (int nf = 0; nf < 4; ++nf) {
            int col = n0 + wn + nf * 16 + fr;
            float bv = bias[col];
            #pragma unroll
            for (int r = 0; r < 4; ++r) {
                int rowg = m0 + wm + mf * 16 + fk * 4 + r;
                Cout[(size_t)rowg * N + col] = acc[mf][nf][r] + bv;
            }
        }
    }
}

// ---------------------------------------------------------------------------
// Fused 3x depthwise conv1d(k=5) + 3 scalar gates + mD. xn raw fp32 key.
// R11: streamed conv accumulation (no x[5][8] array) + __launch_bounds__(256,8)
// to stay <=64 VGPR -> 8 waves/SIMD (was 68 VGPR -> 4 waves/SIMD, 25% occ).
// Per-channel FP accumulation order unchanged (j=0..4) -> bit-identical.
// ---------------------------------------------------------------------------
__global__ __launch_bounds__(256, 8) void conv_gate_all(
    const float* __restrict__ xn, u16* __restrict__ pkv,
    const float* __restrict__ Wcq, const float* __restrict__ Wck, const float* __restrict__ Wcv,
    const float* __restrict__ Wgq, const float* __restrict__ bgq,
    const float* __restrict__ Wgk, const float* __restrict__ bgk,
    const float* __restrict__ Wgv, const float* __restrict__ bgv,
    const float* __restrict__ WmD, const float* __restrict__ bmD,
    float* __restrict__ mD)
{
    const int w = threadIdx.x >> 6, lane = threadIdx.x & 63;
    const int bt = blockIdx.x * 4 + w;
    const int b = bt >> 9, tpos = bt & (NT - 1);
    const int c0 = lane * 8;

    float aq[8] = {}, ak[8] = {}, av[8] = {};
    #pragma unroll
    for (int j = 0; j < 5; ++j) {
        int tt = tpos + j - 2;
        if (tt >= 0 && tt < NT) {
            const float4* xp = (const float4*)&xn[((size_t)(b*NT + tt))*NSZ + c0];
            float4 u0 = xp[0], u1 = xp[1];
            float x8[8] = {u0.x, u0.y, u0.z, u0.w, u1.x, u1.y, u1.z, u1.w};
            #pragma unroll
            for (int i = 0; i < 8; ++i) {
                int c = c0 + i;
                aq[i] += x8[i] * Wcq[c*5 + j];
                ak[i] += x8[i] * Wck[c*5 + j];
                av[i] += x8[i] * Wcv[c*5 + j];
            }
        }
    }
    const size_t rb = (size_t)bt * 1536;
    u16x8 q8 = *(const u16x8*)&pkv[rb + c0];
    u16x8 k8 = *(const u16x8*)&pkv[rb + 512 + c0];
    u16x8 v8 = *(const u16x8*)&pkv[rb + 1024 + c0];

    float sq = 0.f, sk = 0.f, sv = 0.f;
    #pragma unroll
    for (int i = 0; i < 8; ++i) {
        int c = c0 + i;
        sq += b2f(q8[i]) * Wgq[c] + aq[i] * Wgq[512 + c];
        sk += b2f(k8[i]) * Wgk[c] + ak[i] * Wgk[512 + c];
        sv += b2f(v8[i]) * Wgv[c] + av[i] * Wgv[512 + c];
    }
    #pragma unroll
    for (int o = 1; o < 64; o <<= 1) {
        sq += __shfl_xor(sq, o, 64);
        sk += __shfl_xor(sk, o, 64);
        sv += __shfl_xor(sv, o, 64);
    }
    float gq = 1.f / (1.f + expf(-(sq + bgq[0])));
    float gk = 1.f / (1.f + expf(-(sk + bgk[0])));
    float gv = 1.f / (1.f + expf(-(sv + bgv[0])));

    u16x8 oq8, ok8, ov8;
    float smd = 0.f;
    #pragma unroll
    for (int i = 0; i < 8; ++i) {
        float oq = (1.f - gq) * b2f(q8[i]) + gq * aq[i];
        oq8[i] = f2b(oq);
        ok8[i] = f2b((1.f - gk) * b2f(k8[i]) + gk * ak[i]);
        ov8[i] = f2b((1.f - gv) * b2f(v8[i]) + gv * av[i]);
        smd += oq * WmD[c0 + i];
    }
    *(u16x8*)&pkv[rb + c0]        = oq8;
    *(u16x8*)&pkv[rb + 512 + c0]  = ok8;
    *(u16x8*)&pkv[rb + 1024 + c0] = ov8;
    #pragma unroll
    for (int o = 1; o < 64; o <<= 1) smd += __shfl_xor(smd, o, 64);
    if (lane == 0)
        mD[bt] = C_D0 + 2.f * C_STD * tanhf((smd + bmD[0]) / C_GAMMA);
}

// ---------------------------------------------------------------------------
// V transpose: pkv v-section (b,t,h*64+d) -> vpT[(b*8+h)*64+d][t]
// ---------------------------------------------------------------------------
__global__ __launch_bounds__(256) void vtrans(
    const u16* __restrict__ pkv, u16* __restrict__ vpT)
{
    __shared__ u16 lt[64][72];
    const int t0 = blockIdx.x * 64;
    const int h = blockIdx.y, b = blockIdx.z;
    const int tid = threadIdx.x;
    #pragma unroll
    for (int p = 0; p < 2; ++p) {
        int s = tid + p * 256;
        int t = s >> 3, c8 = s & 7;
        u16x8 v = *(const u16x8*)&pkv[((size_t)(b*NT + t0 + t))*1536 + 1024 + h*NHD + c8*8];
        *(u16x8*)&lt[t][c8 * 8] = v;
    }
    __syncthreads();
    #pragma unroll
    for (int p = 0; p < 2; ++p) {
        int s = tid + p * 256;
        int d = s >> 3, c8 = s & 7;
        u16x8 o;
        #pragma unroll
        for (int j = 0; j < 8; ++j) o[j] = lt[c8 * 8 + j][d];
        *(u16x8*)&vpT[((size_t)((b*NH + h)*NHD + d))*NT + t0 + c8*8] = o;
    }
}

// ---------------------------------------------------------------------------
// MFMA flash attention — shifted 2-tile window (unchanged from R10).
// ---------------------------------------------------------------------------
__global__ __launch_bounds__(256) void attn_mfma(
    const u16* __restrict__ pkv, const u16* __restrict__ vpT,
    const float* __restrict__ mD, const int* __restrict__ mask,
    const float* __restrict__ rpe, u16* __restrict__ cxh)
{
    __shared__ __align__(16) char smem[38144];
    u16*  QP    = (u16*)(smem);              // Q (prologue), P (loop), wA (epi)
    u16*  Kl    = (u16*)(smem + 8192);       // K tile; epi: rvl linear / out-bounce
    u16*  Vl    = (u16*)(smem + 16384);      // V tile; prologue: rpk; epi: rvT
    u16*  rpk   = (u16*)(smem + 16384);
    u16*  rvl16 = (u16*)(smem + 8192);
    u16*  qdrl  = (u16*)(smem + 24576);      // [64][36] bf16
    float* wbufl= (float*)(smem + 29184);    // [64][34] fp32 (col 33 stays 0)
    float* inv2s= (float*)(smem + 37888);    // [64]

    const int tid  = threadIdx.x;
    const int lane = tid & 63;
    const int w    = tid >> 6;
    const int wq0  = w * 16;
    const int fr   = lane & 15;
    const int fq   = lane >> 4;
    const int b    = blockIdx.x >> 3;
    const int h    = blockIdx.x & 7;
    const int q0   = blockIdx.y * 64;

    const size_t qbase  = ((size_t)(b*NT + q0)) * 1536 + h * NHD;
    const size_t kbaseg = ((size_t)b * NT) * 1536 + 512 + h * NHD;
    const size_t vbaseg = ((size_t)((b*NH + h) * NHD)) * NT;

    // ---- sequence length L (first masked key), per-wave shuffle-min ----
    int Lm = 512;
    #pragma unroll
    for (int j = 0; j < 8; ++j) {
        if (mask[b * NT + lane + 64 * j]) Lm = min(Lm, lane + 64 * j);
    }
    #pragma unroll
    for (int o = 1; o < 64; o <<= 1) Lm = min(Lm, __shfl_xor(Lm, o, 64));
    const int L = Lm;
    const int w0 = max(0, min(q0 - 32, L - 128));

    // ---- prologue: reg-load Q, K[w0], V[w0]; swizzled ds_write of Q, K ----
    int r_[2], cs_[2];
    u16x8 qreg[2], kreg[2], vreg[2];
    #pragma unroll
    for (int p = 0; p < 2; ++p) {
        int s = tid + p * 256;
        r_[p] = s >> 3; cs_[p] = s & 7;
        qreg[p] = *(const u16x8*)(pkv + qbase  + (size_t)r_[p] * 1536 + cs_[p] * 8);
        kreg[p] = *(const u16x8*)(pkv + kbaseg + (size_t)(w0 + r_[p]) * 1536 + cs_[p] * 8);
        vreg[p] = *(const u16x8*)(vpT + vbaseg + (size_t)r_[p] * NT + w0 + cs_[p] * 8);
    }
    #pragma unroll
    for (int p = 0; p < 2; ++p) {
        *(u16x8*)(QP + SWU(r_[p], cs_[p])) = qreg[p];
        *(u16x8*)(Kl + SWU(r_[p], cs_[p])) = kreg[p];
    }
    // rpe_k -> rpk (in Vl space): 264 chunks, strided (264 > 256 threads!)
    for (int idx = tid; idx < 264; idx += 256) {
        int r = idx >> 3, c = idx & 7;
        float4 f0 = *(const float4*)&rpe[r * 128 + c * 8];
        float4 f1 = *(const float4*)&rpe[r * 128 + c * 8 + 4];
        u16x8 vv;
        vv[0]=f2b(f0.x); vv[1]=f2b(f0.y); vv[2]=f2b(f0.z); vv[3]=f2b(f0.w);
        vv[4]=f2b(f1.x); vv[5]=f2b(f1.y); vv[6]=f2b(f1.z); vv[7]=f2b(f1.w);
        *(u16x8*)(rpk + SWU(r, c)) = vv;
    }
    if (tid < 120) {   // zero rows 33..47
        u16x8 vv = {0,0,0,0,0,0,0,0};
        *(u16x8*)(rpk + (((33 + (tid >> 3)) * 8) + (tid & 7)) * 8) = vv;
    }
    if (tid < 64) {
        float md = mD[b * NT + q0 + tid];
        inv2s[tid] = 2.f * LOG2E / (md * md);
    }
    for (int i = tid; i < 64 * 34; i += 256) wbufl[i] = 0.f;
    __syncthreads();                                // (P0)

    // persistent Q A-frags (QP becomes Pl afterwards)
    bf16x8 aq0 = *(const bf16x8*)(QP + SWU(wq0 + fr, fq));
    bf16x8 aq1 = *(const bf16x8*)(QP + SWU(wq0 + fr, 4 + fq));

    // qdr[q][rd] = q . rpe_k[rd] via MFMA (reads rpk in Vl space)
    {
        f32x4 qd[3] = {};
        #pragma unroll
        for (int nf = 0; nf < 3; ++nf) {
            bf16x8 b0 = *(const bf16x8*)(rpk + SWU(nf * 16 + fr, fq));
            bf16x8 b1 = *(const bf16x8*)(rpk + SWU(nf * 16 + fr, 4 + fq));
            qd[nf] = __builtin_amdgcn_mfma_f32_16x16x32_bf16(aq0, b0, qd[nf], 0, 0, 0);
            qd[nf] = __builtin_amdgcn_mfma_f32_16x16x32_bf16(aq1, b1, qd[nf], 0, 0, 0);
        }
        #pragma unroll
        for (int nf = 0; nf < 3; ++nf) {
            int rd = nf * 16 + fr;
            if (rd < 33) {
                #pragma unroll
                for (int r = 0; r < 4; ++r)
                    qdrl[(wq0 + fq * 4 + r) * 36 + rd] = f2b(qd[nf][r]);
            }
        }
    }
    __syncthreads();                                // (P1) qdr done; rpk dead
    // V[w0] ds_write into Vl (visible at first iter's barrier (1))
    #pragma unroll
    for (int p = 0; p < 2; ++p)
        *(u16x8*)(Vl + SWU(r_[p], cs_[p])) = vreg[p];

    f32x4 O[4] = {};
    float m2[4] = {NEGINF, NEGINF, NEGINF, NEGINF};
    float li[4] = {};

    #pragma unroll
    for (int t = 0; t < 2; ++t) {
        const int kb = w0 + t * 64;
        const bool pre = (t == 0);
        u16x8 kreg2[2], vreg2[2];
        if (pre) {
            const int kn = kb + 64;
            #pragma unroll
            for (int p = 0; p < 2; ++p) {
                kreg2[p] = *(const u16x8*)(pkv + kbaseg + (size_t)(kn + r_[p]) * 1536 + cs_[p] * 8);
                vreg2[p] = *(const u16x8*)(vpT + vbaseg + (size_t)r_[p] * NT + kn + cs_[p] * 8);
            }
        }
        int mk[4];
        #pragma unroll
        for (int nf = 0; nf < 4; ++nf) mk[nf] = (kb + nf * 16 + fr) >= L;

        // ---- QK^T ----
        f32x4 s_[4] = {};
        #pragma unroll
        for (int nf = 0; nf < 4; ++nf) {
            bf16x8 b0 = *(const bf16x8*)(Kl + SWU(nf * 16 + fr, fq));
            bf16x8 b1 = *(const bf16x8*)(Kl + SWU(nf * 16 + fr, 4 + fq));
            s_[nf] = __builtin_amdgcn_mfma_f32_16x16x32_bf16(aq0, b0, s_[nf], 0, 0, 0);
            s_[nf] = __builtin_amdgcn_mfma_f32_16x16x32_bf16(aq1, b1, s_[nf], 0, 0, 0);
        }
        // ---- softmax (log2 domain) ----
        const bool leftfar  = (kb + 79 <= q0);
        const bool rightfar = (kb >= q0 + 79);
        const bool mid = !leftfar && !rightfar;

        float p_[4][4], alpha[4], rsum_[4], ls_[4], rs_[4];
        #pragma unroll
        for (int r = 0; r < 4; ++r) {
            const int lq = wq0 + fq * 4 + r;
            const int qg = q0 + lq;
            const float iv = inv2s[lq];
            const float qf = leftfar ? b2f(qdrl[lq * 36]) : (rightfar ? b2f(qdrl[lq * 36 + 32]) : 0.f);
            float mx = NEGINF;
            #pragma unroll
            for (int nf = 0; nf < 4; ++nf) {
                const int kg = kb + nf * 16 + fr;
                float sc;
                if (mk[nf]) sc = NEGINF;
                else {
                    float qr = mid ? b2f(qdrl[lq * 36 + (min(max(kg - qg, -MAXR), MAXR) + MAXR)]) : qf;
                    float fd = (float)(qg - kg);
                    sc = (s_[nf][r] + qr) * C1F - fd * fd * iv;
                }
                p_[r][nf] = sc;
                mx = fmaxf(mx, sc);
            }
            mx = fmaxf(mx, __shfl_xor(mx, 1, 64));
            mx = fmaxf(mx, __shfl_xor(mx, 2, 64));
            mx = fmaxf(mx, __shfl_xor(mx, 4, 64));
            mx = fmaxf(mx, __shfl_xor(mx, 8, 64));
            float mn = fmaxf(m2[r], mx);
            alpha[r] = exp2_fast(m2[r] - mn);
            m2[r] = mn;
            float rsum = 0.f, ls = 0.f, rs = 0.f;
            #pragma unroll
            for (int nf = 0; nf < 4; ++nf) {
                float pv = exp2_fast(p_[r][nf] - mn);
                p_[r][nf] = pv;
                rsum += pv;
                if (mid) {
                    int kg = kb + nf * 16 + fr;
                    if (kg <= qg - MAXR) ls += pv;
                    else if (kg >= qg + MAXR) rs += pv;
                }
            }
            rsum += __shfl_xor(rsum, 1, 64); rsum += __shfl_xor(rsum, 2, 64);
            rsum += __shfl_xor(rsum, 4, 64); rsum += __shfl_xor(rsum, 8, 64);
            if (mid) {
                ls += __shfl_xor(ls, 1, 64); ls += __shfl_xor(ls, 2, 64);
                ls += __shfl_xor(ls, 4, 64); ls += __shfl_xor(ls, 8, 64);
                rs += __shfl_xor(rs, 1, 64); rs += __shfl_xor(rs, 2, 64);
                rs += __shfl_xor(rs, 4, 64); rs += __shfl_xor(rs, 8, 64);
            }
            li[r] = li[r] * alpha[r] + rsum;
            rsum_[r] = rsum; ls_[r] = ls; rs_[r] = rs;
        }
        // O rescale
        #pragma unroll
        for (int nf = 0; nf < 4; ++nf) {
            O[nf][0] *= alpha[0]; O[nf][1] *= alpha[1];
            O[nf][2] *= alpha[2]; O[nf][3] *= alpha[3];
        }
        // wbuf rescale + tile contributions
        #pragma unroll
        for (int r = 0; r < 4; ++r) {
            int lq = wq0 + fq * 4 + r;
            if (alpha[r] != 1.f) {
                for (int c = fr; c < 33; c += 16) wbufl[lq * 34 + c] *= alpha[r];
            }
        }
        if (fr == 0) {
            #pragma unroll
            for (int r = 0; r < 4; ++r) {
                int lq = wq0 + fq * 4 + r;
                if (leftfar)       wbufl[lq * 34]      += rsum_[r];
                else if (rightfar) wbufl[lq * 34 + 32] += rsum_[r];
                else { wbufl[lq * 34] += ls_[r]; wbufl[lq * 34 + 32] += rs_[r]; }
            }
        }
        if (mid) {
            #pragma unroll
            for (int r = 0; r < 4; ++r) {
                int lq = wq0 + fq * 4 + r, qg = q0 + lq;
                #pragma unroll
                for (int nf = 0; nf < 4; ++nf) {
                    int d = kb + nf * 16 + fr - qg;
                    if (d > -MAXR && d < MAXR) wbufl[lq * 34 + d + MAXR] += p_[r][nf];
                }
            }
        }
        // ---- P -> bf16 LDS (swizzled, in QP space) ----
        #pragma unroll
        for (int r = 0; r < 4; ++r) {
            int lq = wq0 + fq * 4 + r;
            #pragma unroll
            for (int nf = 0; nf < 4; ++nf) {
                int k = nf * 16 + fr;
                QP[lq * 64 + (((k >> 3) ^ (lq & 7)) << 3) + (k & 7)] = f2b(p_[r][nf]);
            }
        }
        __syncthreads();    // (1) P + V(t) visible; all QK reads of Kl done
        // K(t+1) into Kl (QK done; PV doesn't touch Kl)
        if (pre) {
            #pragma unroll
            for (int p = 0; p < 2; ++p)
                *(u16x8*)(Kl + SWU(r_[p], cs_[p])) = kreg2[p];
        }
        // ---- PV ----
        bf16x8 ap0 = *(const bf16x8*)(QP + SWU(wq0 + fr, fq));
        bf16x8 ap1 = *(const bf16x8*)(QP + SWU(wq0 + fr, 4 + fq));
        #pragma unroll
        for (int nf = 0; nf < 4; ++nf) {
            bf16x8 v0 = *(const bf16x8*)(Vl + SWU(nf * 16 + fr, fq));
            bf16x8 v1 = *(const bf16x8*)(Vl + SWU(nf * 16 + fr, 4 + fq));
            O[nf] = __builtin_amdgcn_mfma_f32_16x16x32_bf16(ap0, v0, O[nf], 0, 0, 0);
            O[nf] = __builtin_amdgcn_mfma_f32_16x16x32_bf16(ap1, v1, O[nf], 0, 0, 0);
        }
        __syncthreads();    // (2) PV reads of Vl/QP done; K(t+1) visible
        // V(t+1) into Vl (visible at next iter's barrier (1))
        if (pre) {
            #pragma unroll
            for (int p = 0; p < 2; ++p)
                *(u16x8*)(Vl + SWU(r_[p], cs_[p])) = vreg2[p];
        }
    }

    // ---- epilogue: O += wbuf @ rpe_v via MFMA ----
    for (int idx = tid; idx < 264; idx += 256) {   // strided: 264 > 256
        int r = idx >> 3, c = idx & 7;
        float4 f0 = *(const float4*)&rpe[r * 128 + 64 + c * 8];
        float4 f1 = *(const float4*)&rpe[r * 128 + 64 + c * 8 + 4];
        u16x8 vv;
        vv[0]=f2b(f0.x); vv[1]=f2b(f0.y); vv[2]=f2b(f0.z); vv[3]=f2b(f0.w);
        vv[4]=f2b(f1.x); vv[5]=f2b(f1.y); vv[6]=f2b(f1.z); vv[7]=f2b(f1.w);
        *(u16x8*)(rvl16 + (r * 8 + c) * 8) = vv;
    }
    // wA[q][rd] bf16 swizzled into QP; cols 34..63 zero (col 33 already 0)
    #pragma unroll
    for (int p = 0; p < 2; ++p) {
        int r = r_[p], cs = cs_[p];
        u16x8 vv;
        #pragma unroll
        for (int j = 0; j < 8; ++j) {
            int col = cs * 8 + j;
            vv[j] = (col < 34) ? f2b(wbufl[r * 34 + col]) : (u16)0;
        }
        *(u16x8*)(QP + SWU(r, cs)) = vv;
    }
    __syncthreads();   // (E1) rvl + wA ready (wbuf reads complete)
    // Build rvT[d][rd] bf16 swizzled into Vl from linear rvl16
    #pragma unroll
    for (int p = 0; p < 2; ++p) {
        int d = r_[p], cs = cs_[p];
        u16x8 vv;
        #pragma unroll
        for (int j = 0; j < 8; ++j) {
            int rd = cs * 8 + j;
            vv[j] = (rd < 33) ? rvl16[rd * 64 + d] : (u16)0;
        }
        *(u16x8*)(Vl + SWU(d, cs)) = vv;
    }
    __syncthreads();   // (E2) rvT ready
    {
        bf16x8 aw0 = *(const bf16x8*)(QP + SWU(wq0 + fr, fq));
        bf16x8 aw1 = *(const bf16x8*)(QP + SWU(wq0 + fr, 4 + fq));
        #pragma unroll
        for (int nf = 0; nf < 4; ++nf) {
            bf16x8 b0 = *(const bf16x8*)(Vl + SWU(nf * 16 + fr, fq));
            bf16x8 b1 = *(const bf16x8*)(Vl + SWU(nf * 16 + fr, 4 + fq));
            O[nf] = __builtin_amdgcn_mfma_f32_16x16x32_bf16(aw0, b0, O[nf], 0, 0, 0);
            O[nf] = __builtin_amdgcn_mfma_f32_16x16x32_bf16(aw1, b1, O[nf], 0, 0, 0);
        }
    }
    float invl[4];
    #pragma unroll
    for (int r = 0; r < 4; ++r) invl[r] = 1.f / li[r];
    #pragma unroll
    for (int r = 0; r < 4; ++r) {
        int lq = wq0 + fq * 4 + r;
        #pragma unroll
        for (int nf = 0; nf < 4; ++nf)
            Kl[lq * 64 + nf * 16 + fr] = f2b(O[nf][r] * invl[r]);   // linear bounce
    }
    __syncthreads();   // (E3)
    #pragma unroll
    for (int j = 0; j < 2; ++j) {
        int s = w * 128 + j * 64 + lane;
        int rr = s >> 3, c8 = s & 7;
        u16x8 vv = *(const u16x8*)(Kl + rr * 64 + c8 * 8);
        *(u16x8*)&cxh[((size_t)(b*NT + q0 + rr)) * 512 + h * NHD + c8 * 8] = vv;
    }
}

// ---------------------------------------------------------------------------
extern "C" void kernel_launch(void* const* d_in, const int* in_sizes, int n_in,
                              void* d_out, int out_size, void* d_ws, size_t ws_size,
                              hipStream_t stream) {
    const float* key   = (const float*)d_in[0];
    const float* value = (const float*)d_in[1];
    const float* query = (const float*)d_in[2];
    const int*   mask  = (const int*)d_in[3];
    const float* Wq  = (const float*)d_in[4];
    const float* bq  = (const float*)d_in[5];
    const float* Wk  = (const float*)d_in[6];
    const float* bk  = (const float*)d_in[7];
    const float* Wv  = (const float*)d_in[8];
    const float* bv  = (const float*)d_in[9];
    const float* Wcq = (const float*)d_in[10];
    const float* Wck = (const float*)d_in[11];
    const float* Wcv = (const float*)d_in[12];
    const float* Wgq = (const float*)d_in[13];
    const float* bgq = (const float*)d_in[14];
    const float* Wgk = (const float*)d_in[15];
    const float* bgk = (const float*)d_in[16];
    const float* Wgv = (const float*)d_in[17];
    const float* bgv = (const float*)d_in[18];
    const float* WmD = (const float*)d_in[19];
    const float* bmD = (const float*)d_in[20];
    const float* rpe = (const float*)d_in[21];
    const float* Wo  = (const float*)d_in[22];
    const float* bo  = (const float*)d_in[23];
    float* out = (float*)d_out;

    const size_t NTOK = (size_t)NB * NT;            // 8192
    const size_t NE   = NTOK * NSZ;                 // 4,194,304
    const size_t NW   = (size_t)NSZ * NSZ;          // 262,144

    u16* ws16 = (u16*)d_ws;
    u16* pkv  = ws16;                // (8192, 1536) q|k|v
    u16* wcat = pkv + NTOK * 1536;   // 3 x (512,512)
    u16* woh  = wcat + 3 * NW;
    u16* vpT  = woh + NW;            // (16*8*64, 512)
    u16* cxh  = vpT + NE;            // (8192, 512)
    float* mDb = (float*)(cxh + NE);

    cvt4_bf16<<<dim3((unsigned)(NW/8/256), 4), 256, 0, stream>>>(
        Wq, Wk, Wv, Wo, wcat, wcat + NW, wcat + 2*NW, woh, (int)NW);

    gemm_qkv<<<dim3(64, 4, 3), 256, 0, stream>>>(
        query, key, value, wcat, bq, bk, bv, pkv);

    conv_gate_all<<<(int)(NTOK / 4), 256, 0, stream>>>(
        key, pkv, Wcq, Wck, Wcv, Wgq, bgq, Wgk, bgk, Wgv, bgv, WmD, bmD, mDb);

    vtrans<<<dim3(8, 8, 16), 256, 0, stream>>>(pkv, vpT);

    attn_mfma<<<dim3(128, 8), 256, 0, stream>>>(pkv, vpT, mDb, mask, rpe, cxh);

    gemm_out<<<dim3(128, 4), 256, 0, stream>>>(cxh, woh, bo, out, (int)NTOK, NSZ, NSZ);
}

// Round 12
// 208.804 us; speedup vs baseline: 1.0693x; 1.0693x over previous
//
#include <hip/hip_runtime.h>
#include <math.h>

#define NB 16
#define NT 512
#define NSZ 512
#define NH 8
#define NHD 64
#define MAXR 16

#define C_D0 6.3f
#define C_STD 1.4f
#define C_GAMMA 2.0f

#define NEGINF (-1e30f)
#define LOG2E 1.4426950408889634f
#define C1F   0.18033688011112042f   // 0.125 * log2(e)

typedef unsigned short u16;
typedef __attribute__((ext_vector_type(8))) short bf16x8;
typedef __attribute__((ext_vector_type(4))) float f32x4;
typedef __attribute__((ext_vector_type(8))) unsigned short u16x8;

__device__ __forceinline__ u16 f2b(float f) {
    union { float f; unsigned int u; } c; c.f = f;
    unsigned int u = c.u + 0x7FFFu + ((c.u >> 16) & 1u);
    return (u16)(u >> 16);
}
__device__ __forceinline__ float b2f(u16 h) {
    union { unsigned int u; float f; } c; c.u = ((unsigned int)h) << 16;
    return c.f;
}

#if __has_builtin(__builtin_amdgcn_exp2f)
__device__ __forceinline__ float exp2_fast(float x) { return __builtin_amdgcn_exp2f(x); }
#else
__device__ __forceinline__ float exp2_fast(float x) { return exp2f(x); }
#endif

#define GL2LDS(gp, lp) __builtin_amdgcn_global_load_lds( \
    (const __attribute__((address_space(1))) void*)(gp), \
    (__attribute__((address_space(3))) void*)(lp), 16, 0, 0)

// swizzled u16-index of 16B chunk c in row r (row = 8 chunks = 64 bf16)
#define SWU(r, c) ((((r) * 8) + ((c) ^ ((r) & 7))) * 8)

// ---------------------------------------------------------------------------
// fp32 -> bf16 convert (weights only)
// ---------------------------------------------------------------------------
__global__ __launch_bounds__(256) void cvt4_bf16(
    const float* __restrict__ s0, const float* __restrict__ s1,
    const float* __restrict__ s2, const float* __restrict__ s3,
    u16* __restrict__ d0, u16* __restrict__ d1,
    u16* __restrict__ d2, u16* __restrict__ d3, int n)
{
    const float* s; u16* d;
    switch (blockIdx.y) {
        case 0: s = s0; d = d0; break;
        case 1: s = s1; d = d1; break;
        case 2: s = s2; d = d2; break;
        default: s = s3; d = d3; break;
    }
    int i = (blockIdx.x * 256 + threadIdx.x) * 8;
    if (i >= n) return;
    float4 a = *(const float4*)&s[i];
    float4 b = *(const float4*)&s[i + 4];
    u16x8 v;
    v[0]=f2b(a.x); v[1]=f2b(a.y); v[2]=f2b(a.z); v[3]=f2b(a.w);
    v[4]=f2b(b.x); v[5]=f2b(b.y); v[6]=f2b(b.z); v[7]=f2b(b.w);
    *(u16x8*)&d[i] = v;
}

// ---------------------------------------------------------------------------
// QKV projections, z-batched. A fp32 reg-staged with in-flight bf16 convert.
// ---------------------------------------------------------------------------
__global__ __launch_bounds__(256) void gemm_qkv(
    const float* __restrict__ A0, const float* __restrict__ A1, const float* __restrict__ A2,
    const u16* __restrict__ Wc,
    const float* __restrict__ bq, const float* __restrict__ bk, const float* __restrict__ bv,
    u16* __restrict__ pkv)
{
    __shared__ u16 Al[128 * 32];
    __shared__ u16 Bl[128 * 32];
    const int z = blockIdx.z;
    const float* A = z == 0 ? A0 : (z == 1 ? A1 : A2);
    const u16* W = Wc + (size_t)z * NSZ * NSZ;
    const float* bias = z == 0 ? bq : (z == 1 ? bk : bv);
    const int tid = threadIdx.x;
    const int m0 = blockIdx.x * 128;
    const int n0 = blockIdx.y * 128;
    const int w = tid >> 6, lane = tid & 63;
    const int wm = (w >> 1) * 64, wn = (w & 1) * 64;
    const int fr = lane & 15, fk = lane >> 4;

    f32x4 acc[4][4] = {};
    for (int k0 = 0; k0 < NSZ; k0 += 32) {
        float4 a0[2], a1[2];
        #pragma unroll
        for (int p = 0; p < 2; ++p) {
            int s = tid + p * 256;
            int row = s >> 2, cb = s & 3;
            const float* ga = &A[(size_t)(m0 + row) * NSZ + k0 + cb * 8];
            a0[p] = *(const float4*)ga;
            a1[p] = *(const float4*)(ga + 4);
            GL2LDS(&W[(size_t)(n0 + row) * NSZ + k0 + cb * 8], &Bl[s * 8]);
        }
        #pragma unroll
        for (int p = 0; p < 2; ++p) {
            int s = tid + p * 256;
            u16x8 v;
            v[0]=f2b(a0[p].x); v[1]=f2b(a0[p].y); v[2]=f2b(a0[p].z); v[3]=f2b(a0[p].w);
            v[4]=f2b(a1[p].x); v[5]=f2b(a1[p].y); v[6]=f2b(a1[p].z); v[7]=f2b(a1[p].w);
            *(u16x8*)&Al[s * 8] = v;
        }
        __syncthreads();
        bf16x8 af[4], bfr[4];
        #pragma unroll
        for (int mf = 0; mf < 4; ++mf)
            af[mf] = *(const bf16x8*)&Al[(wm + mf * 16 + fr) * 32 + fk * 8];
        #pragma unroll
        for (int nf = 0; nf < 4; ++nf)
            bfr[nf] = *(const bf16x8*)&Bl[(wn + nf * 16 + fr) * 32 + fk * 8];
        #pragma unroll
        for (int mf = 0; mf < 4; ++mf)
            #pragma unroll
            for (int nf = 0; nf < 4; ++nf)
                acc[mf][nf] = __builtin_amdgcn_mfma_f32_16x16x32_bf16(
                    af[mf], bfr[nf], acc[mf][nf], 0, 0, 0);
        __syncthreads();
    }
    #pragma unroll
    for (int mf = 0; mf < 4; ++mf) {
        #pragma unroll
        for (int nf = 0; nf < 4; ++nf) {
            int col = n0 + wn + nf * 16 + fr;
            float bvv = bias[col];
            #pragma unroll
            for (int r = 0; r < 4; ++r) {
                int rowg = m0 + wm + mf * 16 + fk * 4 + r;
                pkv[(size_t)rowg * 1536 + z * 512 + col] = f2b(acc[mf][nf][r] + bvv);
            }
        }
    }
}

// ---------------------------------------------------------------------------
// Output projection (fp32 out). 64x128 tile, 2 blocks/CU.
// ---------------------------------------------------------------------------
__global__ __launch_bounds__(256) void gemm_out(
    const u16* __restrict__ A, const u16* __restrict__ W,
    const float* __restrict__ bias, float* __restrict__ Cout, int M, int N, int K)
{
    __shared__ u16 Al[64 * 32];
    __shared__ u16 Bl[128 * 32];
    const int tid = threadIdx.x;
    const int m0 = blockIdx.x * 64;
    const int n0 = blockIdx.y * 128;
    const int w = tid >> 6, lane = tid & 63;
    const int wm = (w >> 1) * 32, wn = (w & 1) * 64;
    const int fr = lane & 15, fk = lane >> 4;

    f32x4 acc[2][4] = {};
    for (int k0 = 0; k0 < K; k0 += 32) {
        {
            int row = tid >> 2, cb = tid & 3;
            GL2LDS(&A[(size_t)(m0 + row) * K + k0 + cb * 8], &Al[tid * 8]);
        }
        #pragma unroll
        for (int p = 0; p < 2; ++p) {
            int s = tid + p * 256;
            int row = s >> 2, cb = s & 3;
            GL2LDS(&W[(size_t)(n0 + row) * K + k0 + cb * 8], &Bl[s * 8]);
        }
        __syncthreads();
        bf16x8 af[2], bfr[4];
        #pragma unroll
        for (int mf = 0; mf < 2; ++mf)
            af[mf] = *(const bf16x8*)&Al[(wm + mf * 16 + fr) * 32 + fk * 8];
        #pragma unroll
        for (int nf = 0; nf < 4; ++nf)
            bfr[nf] = *(const bf16x8*)&Bl[(wn + nf * 16 + fr) * 32 + fk * 8];
        #pragma unroll
        for (int mf = 0; mf < 2; ++mf)
            #pragma unroll
            for (int nf = 0; nf < 4; ++nf)
                acc[mf][nf] = __builtin_amdgcn_mfma_f32_16x16x32_bf16(
                    af[mf], bfr[nf], acc[mf][nf], 0, 0, 0);
        __syncthreads();
    }
    #pragma unroll
    for (int mf = 0; mf < 2; ++mf) {
        #pragma unroll
        for (int nf = 0; nf < 4; ++nf) {
            int col = n0 + wn + nf * 16 + fr;
            float bv = bias[col];
            #pragma unroll
            for (int r = 0; r < 4; ++r) {
                int rowg = m0 + wm + mf * 16 + fk * 4 + r;
                Cout[(size_t)rowg * N + col] = acc[mf][nf][r] + bv;
            }
        }
    }
}

// ---------------------------------------------------------------------------
// Fused 3x depthwise conv1d(k=5) + 3 scalar gates + mD. xn raw fp32 key.
// R12: streamed conv (natural ~50 VGPR) + __launch_bounds__(256, 6)
// (budget 512/6=85 VGPR -> NO spill; R11's (256,8) made the allocator cut to
// 32 VGPR and spill accumulators -> 52 MB scratch traffic, 3x regression).
// ---------------------------------------------------------------------------
__global__ __launch_bounds__(256, 6) void conv_gate_all(
    const float* __restrict__ xn, u16* __restrict__ pkv,
    const float* __restrict__ Wcq, const float* __restrict__ Wck, const float* __restrict__ Wcv,
    const float* __restrict__ Wgq, const float* __restrict__ bgq,
    const float* __restrict__ Wgk, const float* __restrict__ bgk,
    const float* __restrict__ Wgv, const float* __restrict__ bgv,
    const float* __restrict__ WmD, const float* __restrict__ bmD,
    float* __restrict__ mD)
{
    const int w = threadIdx.x >> 6, lane = threadIdx.x & 63;
    const int bt = blockIdx.x * 4 + w;
    const int b = bt >> 9, tpos = bt & (NT - 1);
    const int c0 = lane * 8;

    float aq[8] = {}, ak[8] = {}, av[8] = {};
    #pragma unroll
    for (int j = 0; j < 5; ++j) {
        int tt = tpos + j - 2;
        if (tt >= 0 && tt < NT) {
            const float4* xp = (const float4*)&xn[((size_t)(b*NT + tt))*NSZ + c0];
            float4 u0 = xp[0], u1 = xp[1];
            float x8[8] = {u0.x, u0.y, u0.z, u0.w, u1.x, u1.y, u1.z, u1.w};
            #pragma unroll
            for (int i = 0; i < 8; ++i) {
                int c = c0 + i;
                aq[i] += x8[i] * Wcq[c*5 + j];
                ak[i] += x8[i] * Wck[c*5 + j];
                av[i] += x8[i] * Wcv[c*5 + j];
            }
        }
    }
    const size_t rb = (size_t)bt * 1536;
    u16x8 q8 = *(const u16x8*)&pkv[rb + c0];
    u16x8 k8 = *(const u16x8*)&pkv[rb + 512 + c0];
    u16x8 v8 = *(const u16x8*)&pkv[rb + 1024 + c0];

    float sq = 0.f, sk = 0.f, sv = 0.f;
    #pragma unroll
    for (int i = 0; i < 8; ++i) {
        int c = c0 + i;
        sq += b2f(q8[i]) * Wgq[c] + aq[i] * Wgq[512 + c];
        sk += b2f(k8[i]) * Wgk[c] + ak[i] * Wgk[512 + c];
        sv += b2f(v8[i]) * Wgv[c] + av[i] * Wgv[512 + c];
    }
    #pragma unroll
    for (int o = 1; o < 64; o <<= 1) {
        sq += __shfl_xor(sq, o, 64);
        sk += __shfl_xor(sk, o, 64);
        sv += __shfl_xor(sv, o, 64);
    }
    float gq = 1.f / (1.f + expf(-(sq + bgq[0])));
    float gk = 1.f / (1.f + expf(-(sk + bgk[0])));
    float gv = 1.f / (1.f + expf(-(sv + bgv[0])));

    u16x8 oq8, ok8, ov8;
    float smd = 0.f;
    #pragma unroll
    for (int i = 0; i < 8; ++i) {
        float oq = (1.f - gq) * b2f(q8[i]) + gq * aq[i];
        oq8[i] = f2b(oq);
        ok8[i] = f2b((1.f - gk) * b2f(k8[i]) + gk * ak[i]);
        ov8[i] = f2b((1.f - gv) * b2f(v8[i]) + gv * av[i]);
        smd += oq * WmD[c0 + i];
    }
    *(u16x8*)&pkv[rb + c0]        = oq8;
    *(u16x8*)&pkv[rb + 512 + c0]  = ok8;
    *(u16x8*)&pkv[rb + 1024 + c0] = ov8;
    #pragma unroll
    for (int o = 1; o < 64; o <<= 1) smd += __shfl_xor(smd, o, 64);
    if (lane == 0)
        mD[bt] = C_D0 + 2.f * C_STD * tanhf((smd + bmD[0]) / C_GAMMA);
}

// ---------------------------------------------------------------------------
// V transpose: pkv v-section (b,t,h*64+d) -> vpT[(b*8+h)*64+d][t]
// ---------------------------------------------------------------------------
__global__ __launch_bounds__(256) void vtrans(
    const u16* __restrict__ pkv, u16* __restrict__ vpT)
{
    __shared__ u16 lt[64][72];
    const int t0 = blockIdx.x * 64;
    const int h = blockIdx.y, b = blockIdx.z;
    const int tid = threadIdx.x;
    #pragma unroll
    for (int p = 0; p < 2; ++p) {
        int s = tid + p * 256;
        int t = s >> 3, c8 = s & 7;
        u16x8 v = *(const u16x8*)&pkv[((size_t)(b*NT + t0 + t))*1536 + 1024 + h*NHD + c8*8];
        *(u16x8*)&lt[t][c8 * 8] = v;
    }
    __syncthreads();
    #pragma unroll
    for (int p = 0; p < 2; ++p) {
        int s = tid + p * 256;
        int d = s >> 3, c8 = s & 7;
        u16x8 o;
        #pragma unroll
        for (int j = 0; j < 8; ++j) o[j] = lt[c8 * 8 + j][d];
        *(u16x8*)&vpT[((size_t)((b*NH + h)*NHD + d))*NT + t0 + c8*8] = o;
    }
}

// ---------------------------------------------------------------------------
// MFMA flash attention — shifted 2-tile window (unchanged from R10).
// ---------------------------------------------------------------------------
__global__ __launch_bounds__(256) void attn_mfma(
    const u16* __restrict__ pkv, const u16* __restrict__ vpT,
    const float* __restrict__ mD, const int* __restrict__ mask,
    const float* __restrict__ rpe, u16* __restrict__ cxh)
{
    __shared__ __align__(16) char smem[38144];
    u16*  QP    = (u16*)(smem);              // Q (prologue), P (loop), wA (epi)
    u16*  Kl    = (u16*)(smem + 8192);       // K tile; epi: rvl linear / out-bounce
    u16*  Vl    = (u16*)(smem + 16384);      // V tile; prologue: rpk; epi: rvT
    u16*  rpk   = (u16*)(smem + 16384);
    u16*  rvl16 = (u16*)(smem + 8192);
    u16*  qdrl  = (u16*)(smem + 24576);      // [64][36] bf16
    float* wbufl= (float*)(smem + 29184);    // [64][34] fp32 (col 33 stays 0)
    float* inv2s= (float*)(smem + 37888);    // [64]

    const int tid  = threadIdx.x;
    const int lane = tid & 63;
    const int w    = tid >> 6;
    const int wq0  = w * 16;
    const int fr   = lane & 15;
    const int fq   = lane >> 4;
    const int b    = blockIdx.x >> 3;
    const int h    = blockIdx.x & 7;
    const int q0   = blockIdx.y * 64;

    const size_t qbase  = ((size_t)(b*NT + q0)) * 1536 + h * NHD;
    const size_t kbaseg = ((size_t)b * NT) * 1536 + 512 + h * NHD;
    const size_t vbaseg = ((size_t)((b*NH + h) * NHD)) * NT;

    // ---- sequence length L (first masked key), per-wave shuffle-min ----
    int Lm = 512;
    #pragma unroll
    for (int j = 0; j < 8; ++j) {
        if (mask[b * NT + lane + 64 * j]) Lm = min(Lm, lane + 64 * j);
    }
    #pragma unroll
    for (int o = 1; o < 64; o <<= 1) Lm = min(Lm, __shfl_xor(Lm, o, 64));
    const int L = Lm;
    const int w0 = max(0, min(q0 - 32, L - 128));

    // ---- prologue: reg-load Q, K[w0], V[w0]; swizzled ds_write of Q, K ----
    int r_[2], cs_[2];
    u16x8 qreg[2], kreg[2], vreg[2];
    #pragma unroll
    for (int p = 0; p < 2; ++p) {
        int s = tid + p * 256;
        r_[p] = s >> 3; cs_[p] = s & 7;
        qreg[p] = *(const u16x8*)(pkv + qbase  + (size_t)r_[p] * 1536 + cs_[p] * 8);
        kreg[p] = *(const u16x8*)(pkv + kbaseg + (size_t)(w0 + r_[p]) * 1536 + cs_[p] * 8);
        vreg[p] = *(const u16x8*)(vpT + vbaseg + (size_t)r_[p] * NT + w0 + cs_[p] * 8);
    }
    #pragma unroll
    for (int p = 0; p < 2; ++p) {
        *(u16x8*)(QP + SWU(r_[p], cs_[p])) = qreg[p];
        *(u16x8*)(Kl + SWU(r_[p], cs_[p])) = kreg[p];
    }
    // rpe_k -> rpk (in Vl space): 264 chunks, strided (264 > 256 threads!)
    for (int idx = tid; idx < 264; idx += 256) {
        int r = idx >> 3, c = idx & 7;
        float4 f0 = *(const float4*)&rpe[r * 128 + c * 8];
        float4 f1 = *(const float4*)&rpe[r * 128 + c * 8 + 4];
        u16x8 vv;
        vv[0]=f2b(f0.x); vv[1]=f2b(f0.y); vv[2]=f2b(f0.z); vv[3]=f2b(f0.w);
        vv[4]=f2b(f1.x); vv[5]=f2b(f1.y); vv[6]=f2b(f1.z); vv[7]=f2b(f1.w);
        *(u16x8*)(rpk + SWU(r, c)) = vv;
    }
    if (tid < 120) {   // zero rows 33..47
        u16x8 vv = {0,0,0,0,0,0,0,0};
        *(u16x8*)(rpk + (((33 + (tid >> 3)) * 8) + (tid & 7)) * 8) = vv;
    }
    if (tid < 64) {
        float md = mD[b * NT + q0 + tid];
        inv2s[tid] = 2.f * LOG2E / (md * md);
    }
    for (int i = tid; i < 64 * 34; i += 256) wbufl[i] = 0.f;
    __syncthreads();                                // (P0)

    // persistent Q A-frags (QP becomes Pl afterwards)
    bf16x8 aq0 = *(const bf16x8*)(QP + SWU(wq0 + fr, fq));
    bf16x8 aq1 = *(const bf16x8*)(QP + SWU(wq0 + fr, 4 + fq));

    // qdr[q][rd] = q . rpe_k[rd] via MFMA (reads rpk in Vl space)
    {
        f32x4 qd[3] = {};
        #pragma unroll
        for (int nf = 0; nf < 3; ++nf) {
            bf16x8 b0 = *(const bf16x8*)(rpk + SWU(nf * 16 + fr, fq));
            bf16x8 b1 = *(const bf16x8*)(rpk + SWU(nf * 16 + fr, 4 + fq));
            qd[nf] = __builtin_amdgcn_mfma_f32_16x16x32_bf16(aq0, b0, qd[nf], 0, 0, 0);
            qd[nf] = __builtin_amdgcn_mfma_f32_16x16x32_bf16(aq1, b1, qd[nf], 0, 0, 0);
        }
        #pragma unroll
        for (int nf = 0; nf < 3; ++nf) {
            int rd = nf * 16 + fr;
            if (rd < 33) {
                #pragma unroll
                for (int r = 0; r < 4; ++r)
                    qdrl[(wq0 + fq * 4 + r) * 36 + rd] = f2b(qd[nf][r]);
            }
        }
    }
    __syncthreads();                                // (P1) qdr done; rpk dead
    // V[w0] ds_write into Vl (visible at first iter's barrier (1))
    #pragma unroll
    for (int p = 0; p < 2; ++p)
        *(u16x8*)(Vl + SWU(r_[p], cs_[p])) = vreg[p];

    f32x4 O[4] = {};
    float m2[4] = {NEGINF, NEGINF, NEGINF, NEGINF};
    float li[4] = {};

    #pragma unroll
    for (int t = 0; t < 2; ++t) {
        const int kb = w0 + t * 64;
        const bool pre = (t == 0);
        u16x8 kreg2[2], vreg2[2];
        if (pre) {
            const int kn = kb + 64;
            #pragma unroll
            for (int p = 0; p < 2; ++p) {
                kreg2[p] = *(const u16x8*)(pkv + kbaseg + (size_t)(kn + r_[p]) * 1536 + cs_[p] * 8);
                vreg2[p] = *(const u16x8*)(vpT + vbaseg + (size_t)r_[p] * NT + kn + cs_[p] * 8);
            }
        }
        int mk[4];
        #pragma unroll
        for (int nf = 0; nf < 4; ++nf) mk[nf] = (kb + nf * 16 + fr) >= L;

        // ---- QK^T ----
        f32x4 s_[4] = {};
        #pragma unroll
        for (int nf = 0; nf < 4; ++nf) {
            bf16x8 b0 = *(const bf16x8*)(Kl + SWU(nf * 16 + fr, fq));
            bf16x8 b1 = *(const bf16x8*)(Kl + SWU(nf * 16 + fr, 4 + fq));
            s_[nf] = __builtin_amdgcn_mfma_f32_16x16x32_bf16(aq0, b0, s_[nf], 0, 0, 0);
            s_[nf] = __builtin_amdgcn_mfma_f32_16x16x32_bf16(aq1, b1, s_[nf], 0, 0, 0);
        }
        // ---- softmax (log2 domain) ----
        const bool leftfar  = (kb + 79 <= q0);
        const bool rightfar = (kb >= q0 + 79);
        const bool mid = !leftfar && !rightfar;

        float p_[4][4], alpha[4], rsum_[4], ls_[4], rs_[4];
        #pragma unroll
        for (int r = 0; r < 4; ++r) {
            const int lq = wq0 + fq * 4 + r;
            const int qg = q0 + lq;
            const float iv = inv2s[lq];
            const float qf = leftfar ? b2f(qdrl[lq * 36]) : (rightfar ? b2f(qdrl[lq * 36 + 32]) : 0.f);
            float mx = NEGINF;
            #pragma unroll
            for (int nf = 0; nf < 4; ++nf) {
                const int kg = kb + nf * 16 + fr;
                float sc;
                if (mk[nf]) sc = NEGINF;
                else {
                    float qr = mid ? b2f(qdrl[lq * 36 + (min(max(kg - qg, -MAXR), MAXR) + MAXR)]) : qf;
                    float fd = (float)(qg - kg);
                    sc = (s_[nf][r] + qr) * C1F - fd * fd * iv;
                }
                p_[r][nf] = sc;
                mx = fmaxf(mx, sc);
            }
            mx = fmaxf(mx, __shfl_xor(mx, 1, 64));
            mx = fmaxf(mx, __shfl_xor(mx, 2, 64));
            mx = fmaxf(mx, __shfl_xor(mx, 4, 64));
            mx = fmaxf(mx, __shfl_xor(mx, 8, 64));
            float mn = fmaxf(m2[r], mx);
            alpha[r] = exp2_fast(m2[r] - mn);
            m2[r] = mn;
            float rsum = 0.f, ls = 0.f, rs = 0.f;
            #pragma unroll
            for (int nf = 0; nf < 4; ++nf) {
                float pv = exp2_fast(p_[r][nf] - mn);
                p_[r][nf] = pv;
                rsum += pv;
                if (mid) {
                    int kg = kb + nf * 16 + fr;
                    if (kg <= qg - MAXR) ls += pv;
                    else if (kg >= qg + MAXR) rs += pv;
                }
            }
            rsum += __shfl_xor(rsum, 1, 64); rsum += __shfl_xor(rsum, 2, 64);
            rsum += __shfl_xor(rsum, 4, 64); rsum += __shfl_xor(rsum, 8, 64);
            if (mid) {
                ls += __shfl_xor(ls, 1, 64); ls += __shfl_xor(ls, 2, 64);
                ls += __shfl_xor(ls, 4, 64); ls += __shfl_xor(ls, 8, 64);
                rs += __shfl_xor(rs, 1, 64); rs += __shfl_xor(rs, 2, 64);
                rs += __shfl_xor(rs, 4, 64); rs += __shfl_xor(rs, 8, 64);
            }
            li[r] = li[r] * alpha[r] + rsum;
            rsum_[r] = rsum; ls_[r] = ls; rs_[r] = rs;
        }
        // O rescale
        #pragma unroll
        for (int nf = 0; nf < 4; ++nf) {
            O[nf][0] *= alpha[0]; O[nf][1] *= alpha[1];
            O[nf][2] *= alpha[2]; O[nf][3] *= alpha[3];
        }
        // wbuf rescale + tile contributions
        #pragma unroll
        for (int r = 0; r < 4; ++r) {
            int lq = wq0 + fq * 4 + r;
            if (alpha[r] != 1.f) {
                for (int c = fr; c < 33; c += 16) wbufl[lq * 34 + c] *= alpha[r];
            }
        }
        if (fr == 0) {
            #pragma unroll
            for (int r = 0; r < 4; ++r) {
                int lq = wq0 + fq * 4 + r;
                if (leftfar)       wbufl[lq * 34]      += rsum_[r];
                else if (rightfar) wbufl[lq * 34 + 32] += rsum_[r];
                else { wbufl[lq * 34] += ls_[r]; wbufl[lq * 34 + 32] += rs_[r]; }
            }
        }
        if (mid) {
            #pragma unroll
            for (int r = 0; r < 4; ++r) {
                int lq = wq0 + fq * 4 + r, qg = q0 + lq;
                #pragma unroll
                for (int nf = 0; nf < 4; ++nf) {
                    int d = kb + nf * 16 + fr - qg;
                    if (d > -MAXR && d < MAXR) wbufl[lq * 34 + d + MAXR] += p_[r][nf];
                }
            }
        }
        // ---- P -> bf16 LDS (swizzled, in QP space) ----
        #pragma unroll
        for (int r = 0; r < 4; ++r) {
            int lq = wq0 + fq * 4 + r;
            #pragma unroll
            for (int nf = 0; nf < 4; ++nf) {
                int k = nf * 16 + fr;
                QP[lq * 64 + (((k >> 3) ^ (lq & 7)) << 3) + (k & 7)] = f2b(p_[r][nf]);
            }
        }
        __syncthreads();    // (1) P + V(t) visible; all QK reads of Kl done
        // K(t+1) into Kl (QK done; PV doesn't touch Kl)
        if (pre) {
            #pragma unroll
            for (int p = 0; p < 2; ++p)
                *(u16x8*)(Kl + SWU(r_[p], cs_[p])) = kreg2[p];
        }
        // ---- PV ----
        bf16x8 ap0 = *(const bf16x8*)(QP + SWU(wq0 + fr, fq));
        bf16x8 ap1 = *(const bf16x8*)(QP + SWU(wq0 + fr, 4 + fq));
        #pragma unroll
        for (int nf = 0; nf < 4; ++nf) {
            bf16x8 v0 = *(const bf16x8*)(Vl + SWU(nf * 16 + fr, fq));
            bf16x8 v1 = *(const bf16x8*)(Vl + SWU(nf * 16 + fr, 4 + fq));
            O[nf] = __builtin_amdgcn_mfma_f32_16x16x32_bf16(ap0, v0, O[nf], 0, 0, 0);
            O[nf] = __builtin_amdgcn_mfma_f32_16x16x32_bf16(ap1, v1, O[nf], 0, 0, 0);
        }
        __syncthreads();    // (2) PV reads of Vl/QP done; K(t+1) visible
        // V(t+1) into Vl (visible at next iter's barrier (1))
        if (pre) {
            #pragma unroll
            for (int p = 0; p < 2; ++p)
                *(u16x8*)(Vl + SWU(r_[p], cs_[p])) = vreg2[p];
        }
    }

    // ---- epilogue: O += wbuf @ rpe_v via MFMA ----
    for (int idx = tid; idx < 264; idx += 256) {   // strided: 264 > 256
        int r = idx >> 3, c = idx & 7;
        float4 f0 = *(const float4*)&rpe[r * 128 + 64 + c * 8];
        float4 f1 = *(const float4*)&rpe[r * 128 + 64 + c * 8 + 4];
        u16x8 vv;
        vv[0]=f2b(f0.x); vv[1]=f2b(f0.y); vv[2]=f2b(f0.z); vv[3]=f2b(f0.w);
        vv[4]=f2b(f1.x); vv[5]=f2b(f1.y); vv[6]=f2b(f1.z); vv[7]=f2b(f1.w);
        *(u16x8*)(rvl16 + (r * 8 + c) * 8) = vv;
    }
    // wA[q][rd] bf16 swizzled into QP; cols 34..63 zero (col 33 already 0)
    #pragma unroll
    for (int p = 0; p < 2; ++p) {
        int r = r_[p], cs = cs_[p];
        u16x8 vv;
        #pragma unroll
        for (int j = 0; j < 8; ++j) {
            int col = cs * 8 + j;
            vv[j] = (col < 34) ? f2b(wbufl[r * 34 + col]) : (u16)0;
        }
        *(u16x8*)(QP + SWU(r, cs)) = vv;
    }
    __syncthreads();   // (E1) rvl + wA ready (wbuf reads complete)
    // Build rvT[d][rd] bf16 swizzled into Vl from linear rvl16
    #pragma unroll
    for (int p = 0; p < 2; ++p) {
        int d = r_[p], cs = cs_[p];
        u16x8 vv;
        #pragma unroll
        for (int j = 0; j < 8; ++j) {
            int rd = cs * 8 + j;
            vv[j] = (rd < 33) ? rvl16[rd * 64 + d] : (u16)0;
        }
        *(u16x8*)(Vl + SWU(d, cs)) = vv;
    }
    __syncthreads();   // (E2) rvT ready
    {
        bf16x8 aw0 = *(const bf16x8*)(QP + SWU(wq0 + fr, fq));
        bf16x8 aw1 = *(const bf16x8*)(QP + SWU(wq0 + fr, 4 + fq));
        #pragma unroll
        for (int nf = 0; nf < 4; ++nf) {
            bf16x8 b0 = *(const bf16x8*)(Vl + SWU(nf * 16 + fr, fq));
            bf16x8 b1 = *(const bf16x8*)(Vl + SWU(nf * 16 + fr, 4 + fq));
            O[nf] = __builtin_amdgcn_mfma_f32_16x16x32_bf16(aw0, b0, O[nf], 0, 0, 0);
            O[nf] = __builtin_amdgcn_mfma_f32_16x16x32_bf16(aw1, b1, O[nf], 0, 0, 0);
        }
    }
    float invl[4];
    #pragma unroll
    for (int r = 0; r < 4; ++r) invl[r] = 1.f / li[r];
    #pragma unroll
    for (int r = 0; r < 4; ++r) {
        int lq = wq0 + fq * 4 + r;
        #pragma unroll
        for (int nf = 0; nf < 4; ++nf)
            Kl[lq * 64 + nf * 16 + fr] = f2b(O[nf][r] * invl[r]);   // linear bounce
    }
    __syncthreads();   // (E3)
    #pragma unroll
    for (int j = 0; j < 2; ++j) {
        int s = w * 128 + j * 64 + lane;
        int rr = s >> 3, c8 = s & 7;
        u16x8 vv = *(const u16x8*)(Kl + rr * 64 + c8 * 8);
        *(u16x8*)&cxh[((size_t)(b*NT + q0 + rr)) * 512 + h * NHD + c8 * 8] = vv;
    }
}

// ---------------------------------------------------------------------------
extern "C" void kernel_launch(void* const* d_in, const int* in_sizes, int n_in,
                              void* d_out, int out_size, void* d_ws, size_t ws_size,
                              hipStream_t stream) {
    const float* key   = (const float*)d_in[0];
    const float* value = (const float*)d_in[1];
    const float* query = (const float*)d_in[2];
    const int*   mask  = (const int*)d_in[3];
    const float* Wq  = (const float*)d_in[4];
    const float* bq  = (const float*)d_in[5];
    const float* Wk  = (const float*)d_in[6];
    const float* bk  = (const float*)d_in[7];
    const float* Wv  = (const float*)d_in[8];
    const float* bv  = (const float*)d_in[9];
    const float* Wcq = (const float*)d_in[10];
    const float* Wck = (const float*)d_in[11];
    const float* Wcv = (const float*)d_in[12];
    const float* Wgq = (const float*)d_in[13];
    const float* bgq = (const float*)d_in[14];
    const float* Wgk = (const float*)d_in[15];
    const float* bgk = (const float*)d_in[16];
    const float* Wgv = (const float*)d_in[17];
    const float* bgv = (const float*)d_in[18];
    const float* WmD = (const float*)d_in[19];
    const float* bmD = (const float*)d_in[20];
    const float* rpe = (const float*)d_in[21];
    const float* Wo  = (const float*)d_in[22];
    const float* bo  = (const float*)d_in[23];
    float* out = (float*)d_out;

    const size_t NTOK = (size_t)NB * NT;            // 8192
    const size_t NE   = NTOK * NSZ;                 // 4,194,304
    const size_t NW   = (size_t)NSZ * NSZ;          // 262,144

    u16* ws16 = (u16*)d_ws;
    u16* pkv  = ws16;                // (8192, 1536) q|k|v
    u16* wcat = pkv + NTOK * 1536;   // 3 x (512,512)
    u16* woh  = wcat + 3 * NW;
    u16* vpT  = woh + NW;            // (16*8*64, 512)
    u16* cxh  = vpT + NE;            // (8192, 512)
    float* mDb = (float*)(cxh + NE);

    cvt4_bf16<<<dim3((unsigned)(NW/8/256), 4), 256, 0, stream>>>(
        Wq, Wk, Wv, Wo, wcat, wcat + NW, wcat + 2*NW, woh, (int)NW);

    gemm_qkv<<<dim3(64, 4, 3), 256, 0, stream>>>(
        query, key, value, wcat, bq, bk, bv, pkv);

    conv_gate_all<<<(int)(NTOK / 4), 256, 0, stream>>>(
        key, pkv, Wcq, Wck, Wcv, Wgq, bgq, Wgk, bgk, Wgv, bgv, WmD, bmD, mDb);

    vtrans<<<dim3(8, 8, 16), 256, 0, stream>>>(pkv, vpT);

    attn_mfma<<<dim3(128, 8), 256, 0, stream>>>(pkv, vpT, mDb, mask, rpe, cxh);

    gemm_out<<<dim3(128, 4), 256, 0, stream>>>(cxh, woh, bo, out, (int)NTOK, NSZ, NSZ);
}

// Round 13
// 116.568 us; speedup vs baseline: 1.9155x; 1.7913x over previous
//
#include <hip/hip_runtime.h>
#include <math.h>

#define NB 16
#define NT 512
#define NSZ 512
#define NH 8
#define NHD 64
#define MAXR 16

#define C_D0 6.3f
#define C_STD 1.4f
#define C_GAMMA 2.0f

#define NEGINF (-1e30f)
#define LOG2E 1.4426950408889634f
#define C1F   0.18033688011112042f   // 0.125 * log2(e)

typedef unsigned short u16;
typedef __attribute__((ext_vector_type(8))) short bf16x8;
typedef __attribute__((ext_vector_type(4))) float f32x4;
typedef __attribute__((ext_vector_type(8))) unsigned short u16x8;

__device__ __forceinline__ u16 f2b(float f) {
    union { float f; unsigned int u; } c; c.f = f;
    unsigned int u = c.u + 0x7FFFu + ((c.u >> 16) & 1u);
    return (u16)(u >> 16);
}
__device__ __forceinline__ float b2f(u16 h) {
    union { unsigned int u; float f; } c; c.u = ((unsigned int)h) << 16;
    return c.f;
}

#if __has_builtin(__builtin_amdgcn_exp2f)
__device__ __forceinline__ float exp2_fast(float x) { return __builtin_amdgcn_exp2f(x); }
#else
__device__ __forceinline__ float exp2_fast(float x) { return exp2f(x); }
#endif

#define GL2LDS(gp, lp) __builtin_amdgcn_global_load_lds( \
    (const __attribute__((address_space(1))) void*)(gp), \
    (__attribute__((address_space(3))) void*)(lp), 16, 0, 0)

// swizzled u16-index of 16B chunk c in row r (row = 8 chunks = 64 bf16)
#define SWU(r, c) ((((r) * 8) + ((c) ^ ((r) & 7))) * 8)

// ---------------------------------------------------------------------------
// fp32 -> bf16 convert (weights only)
// ---------------------------------------------------------------------------
__global__ __launch_bounds__(256) void cvt4_bf16(
    const float* __restrict__ s0, const float* __restrict__ s1,
    const float* __restrict__ s2, const float* __restrict__ s3,
    u16* __restrict__ d0, u16* __restrict__ d1,
    u16* __restrict__ d2, u16* __restrict__ d3, int n)
{
    const float* s; u16* d;
    switch (blockIdx.y) {
        case 0: s = s0; d = d0; break;
        case 1: s = s1; d = d1; break;
        case 2: s = s2; d = d2; break;
        default: s = s3; d = d3; break;
    }
    int i = (blockIdx.x * 256 + threadIdx.x) * 8;
    if (i >= n) return;
    float4 a = *(const float4*)&s[i];
    float4 b = *(const float4*)&s[i + 4];
    u16x8 v;
    v[0]=f2b(a.x); v[1]=f2b(a.y); v[2]=f2b(a.z); v[3]=f2b(a.w);
    v[4]=f2b(b.x); v[5]=f2b(b.y); v[6]=f2b(b.z); v[7]=f2b(b.w);
    *(u16x8*)&d[i] = v;
}

// ---------------------------------------------------------------------------
// Conv-weight transpose: Wc_z[512][5] -> WcT[z][5][512]  (fp32, one-time)
// ---------------------------------------------------------------------------
__global__ __launch_bounds__(256) void wprep(
    const float* __restrict__ Wcq, const float* __restrict__ Wck,
    const float* __restrict__ Wcv, float* __restrict__ WcT)
{
    const int z = blockIdx.y;
    const float* src = z == 0 ? Wcq : (z == 1 ? Wck : Wcv);
    int idx = blockIdx.x * 256 + threadIdx.x;
    if (idx >= 2560) return;
    int c = idx / 5, j = idx % 5;
    WcT[(size_t)z * 2560 + j * 512 + c] = src[idx];
}

// ---------------------------------------------------------------------------
// QKV projections, z-batched. A fp32 reg-staged with in-flight bf16 convert.
// ---------------------------------------------------------------------------
__global__ __launch_bounds__(256) void gemm_qkv(
    const float* __restrict__ A0, const float* __restrict__ A1, const float* __restrict__ A2,
    const u16* __restrict__ Wc,
    const float* __restrict__ bq, const float* __restrict__ bk, const float* __restrict__ bv,
    u16* __restrict__ pkv)
{
    __shared__ u16 Al[128 * 32];
    __shared__ u16 Bl[128 * 32];
    const int z = blockIdx.z;
    const float* A = z == 0 ? A0 : (z == 1 ? A1 : A2);
    const u16* W = Wc + (size_t)z * NSZ * NSZ;
    const float* bias = z == 0 ? bq : (z == 1 ? bk : bv);
    const int tid = threadIdx.x;
    const int m0 = blockIdx.x * 128;
    const int n0 = blockIdx.y * 128;
    const int w = tid >> 6, lane = tid & 63;
    const int wm = (w >> 1) * 64, wn = (w & 1) * 64;
    const int fr = lane & 15, fk = lane >> 4;

    f32x4 acc[4][4] = {};
    for (int k0 = 0; k0 < NSZ; k0 += 32) {
        float4 a0[2], a1[2];
        #pragma unroll
        for (int p = 0; p < 2; ++p) {
            int s = tid + p * 256;
            int row = s >> 2, cb = s & 3;
            const float* ga = &A[(size_t)(m0 + row) * NSZ + k0 + cb * 8];
            a0[p] = *(const float4*)ga;
            a1[p] = *(const float4*)(ga + 4);
            GL2LDS(&W[(size_t)(n0 + row) * NSZ + k0 + cb * 8], &Bl[s * 8]);
        }
        #pragma unroll
        for (int p = 0; p < 2; ++p) {
            int s = tid + p * 256;
            u16x8 v;
            v[0]=f2b(a0[p].x); v[1]=f2b(a0[p].y); v[2]=f2b(a0[p].z); v[3]=f2b(a0[p].w);
            v[4]=f2b(a1[p].x); v[5]=f2b(a1[p].y); v[6]=f2b(a1[p].z); v[7]=f2b(a1[p].w);
            *(u16x8*)&Al[s * 8] = v;
        }
        __syncthreads();
        bf16x8 af[4], bfr[4];
        #pragma unroll
        for (int mf = 0; mf < 4; ++mf)
            af[mf] = *(const bf16x8*)&Al[(wm + mf * 16 + fr) * 32 + fk * 8];
        #pragma unroll
        for (int nf = 0; nf < 4; ++nf)
            bfr[nf] = *(const bf16x8*)&Bl[(wn + nf * 16 + fr) * 32 + fk * 8];
        #pragma unroll
        for (int mf = 0; mf < 4; ++mf)
            #pragma unroll
            for (int nf = 0; nf < 4; ++nf)
                acc[mf][nf] = __builtin_amdgcn_mfma_f32_16x16x32_bf16(
                    af[mf], bfr[nf], acc[mf][nf], 0, 0, 0);
        __syncthreads();
    }
    #pragma unroll
    for (int mf = 0; mf < 4; ++mf) {
        #pragma unroll
        for (int nf = 0; nf < 4; ++nf) {
            int col = n0 + wn + nf * 16 + fr;
            float bvv = bias[col];
            #pragma unroll
            for (int r = 0; r < 4; ++r) {
                int rowg = m0 + wm + mf * 16 + fk * 4 + r;
                pkv[(size_t)rowg * 1536 + z * 512 + col] = f2b(acc[mf][nf][r] + bvv);
            }
        }
    }
}

// ---------------------------------------------------------------------------
// Output projection (fp32 out). 64x128 tile, 2 blocks/CU.
// ---------------------------------------------------------------------------
__global__ __launch_bounds__(256) void gemm_out(
    const u16* __restrict__ A, const u16* __restrict__ W,
    const float* __restrict__ bias, float* __restrict__ Cout, int M, int N, int K)
{
    __shared__ u16 Al[64 * 32];
    __shared__ u16 Bl[128 * 32];
    const int tid = threadIdx.x;
    const int m0 = blockIdx.x * 64;
    const int n0 = blockIdx.y * 128;
    const int w = tid >> 6, lane = tid & 63;
    const int wm = (w >> 1) * 32, wn = (w & 1) * 64;
    const int fr = lane & 15, fk = lane >> 4;

    f32x4 acc[2][4] = {};
    for (int k0 = 0; k0 < K; k0 += 32) {
        {
            int row = tid >> 2, cb = tid & 3;
            GL2LDS(&A[(size_t)(m0 + row) * K + k0 + cb * 8], &Al[tid * 8]);
        }
        #pragma unroll
        for (int p = 0; p < 2; ++p) {
            int s = tid + p * 256;
            int row = s >> 2, cb = s & 3;
            GL2LDS(&W[(size_t)(n0 + row) * K + k0 + cb * 8], &Bl[s * 8]);
        }
        __syncthreads();
        bf16x8 af[2], bfr[4];
        #pragma unroll
        for (int mf = 0; mf < 2; ++mf)
            af[mf] = *(const bf16x8*)&Al[(wm + mf * 16 + fr) * 32 + fk * 8];
        #pragma unroll
        for (int nf = 0; nf < 4; ++nf)
            bfr[nf] = *(const bf16x8*)&Bl[(wn + nf * 16 + fr) * 32 + fk * 8];
        #pragma unroll
        for (int mf = 0; mf < 2; ++mf)
            #pragma unroll
            for (int nf = 0; nf < 4; ++nf)
                acc[mf][nf] = __builtin_amdgcn_mfma_f32_16x16x32_bf16(
                    af[mf], bfr[nf], acc[mf][nf], 0, 0, 0);
        __syncthreads();
    }
    #pragma unroll
    for (int mf = 0; mf < 2; ++mf) {
        #pragma unroll
        for (int nf = 0; nf < 4; ++nf) {
            int col = n0 + wn + nf * 16 + fr;
            float bv = bias[col];
            #pragma unroll
            for (int r = 0; r < 4; ++r) {
                int rowg = m0 + wm + mf * 16 + fk * 4 + r;
                Cout[(size_t)rowg * N + col] = acc[mf][nf][r] + bv;
            }
        }
    }
}

// ---------------------------------------------------------------------------
// Fused 3x depthwise conv1d(k=5) + 3 scalar gates + mD.
// R13: R10's proven upfront x[5][8] structure (ILP), NO launch_bounds hint
// (R11/R12 lesson: forcing the allocator spilled or serialized). Conv weights
// read from the wprep-transposed WcT[z][5][512] as coalesced float4 pairs;
// gate weights + WmD explicitly vectorized (G13).
// ---------------------------------------------------------------------------
__global__ void conv_gate_all(
    const float* __restrict__ xn, u16* __restrict__ pkv,
    const float* __restrict__ WcT,
    const float* __restrict__ Wgq, const float* __restrict__ bgq,
    const float* __restrict__ Wgk, const float* __restrict__ bgk,
    const float* __restrict__ Wgv, const float* __restrict__ bgv,
    const float* __restrict__ WmD, const float* __restrict__ bmD,
    float* __restrict__ mD)
{
    const int w = threadIdx.x >> 6, lane = threadIdx.x & 63;
    const int bt = blockIdx.x * 4 + w;
    const int b = bt >> 9, tpos = bt & (NT - 1);
    const int c0 = lane * 8;

    // upfront x rows (5 independent load pairs -> ILP)
    float x[5][8];
    #pragma unroll
    for (int j = 0; j < 5; ++j) {
        int tt = tpos + j - 2;
        if (tt >= 0 && tt < NT) {
            const float4* xp = (const float4*)&xn[((size_t)(b*NT + tt))*NSZ + c0];
            float4 u0 = xp[0], u1 = xp[1];
            x[j][0]=u0.x; x[j][1]=u0.y; x[j][2]=u0.z; x[j][3]=u0.w;
            x[j][4]=u1.x; x[j][5]=u1.y; x[j][6]=u1.z; x[j][7]=u1.w;
        } else {
            #pragma unroll
            for (int i = 0; i < 8; ++i) x[j][i] = 0.f;
        }
    }
    // conv: coalesced weight vec-loads from WcT
    float aq[8] = {}, ak[8] = {}, av[8] = {};
    #pragma unroll
    for (int j = 0; j < 5; ++j) {
        const float* wq = &WcT[j * 512 + c0];
        const float* wk = &WcT[2560 + j * 512 + c0];
        const float* wv = &WcT[5120 + j * 512 + c0];
        float4 q0 = *(const float4*)wq, q1 = *(const float4*)(wq + 4);
        float4 k0 = *(const float4*)wk, k1 = *(const float4*)(wk + 4);
        float4 v0 = *(const float4*)wv, v1 = *(const float4*)(wv + 4);
        float wq8[8] = {q0.x,q0.y,q0.z,q0.w,q1.x,q1.y,q1.z,q1.w};
        float wk8[8] = {k0.x,k0.y,k0.z,k0.w,k1.x,k1.y,k1.z,k1.w};
        float wv8[8] = {v0.x,v0.y,v0.z,v0.w,v1.x,v1.y,v1.z,v1.w};
        #pragma unroll
        for (int i = 0; i < 8; ++i) {
            aq[i] += x[j][i] * wq8[i];
            ak[i] += x[j][i] * wk8[i];
            av[i] += x[j][i] * wv8[i];
        }
    }
    const size_t rb = (size_t)bt * 1536;
    u16x8 q8 = *(const u16x8*)&pkv[rb + c0];
    u16x8 k8 = *(const u16x8*)&pkv[rb + 512 + c0];
    u16x8 v8 = *(const u16x8*)&pkv[rb + 1024 + c0];

    // gate dots: explicit float4 loads of Wg low/high halves
    float gql[8], gqh[8], gkl[8], gkh[8], gvl[8], gvh[8];
    {
        float4 a0 = *(const float4*)&Wgq[c0],      a1 = *(const float4*)&Wgq[c0 + 4];
        float4 a2 = *(const float4*)&Wgq[512 + c0], a3 = *(const float4*)&Wgq[512 + c0 + 4];
        gql[0]=a0.x;gql[1]=a0.y;gql[2]=a0.z;gql[3]=a0.w;gql[4]=a1.x;gql[5]=a1.y;gql[6]=a1.z;gql[7]=a1.w;
        gqh[0]=a2.x;gqh[1]=a2.y;gqh[2]=a2.z;gqh[3]=a2.w;gqh[4]=a3.x;gqh[5]=a3.y;gqh[6]=a3.z;gqh[7]=a3.w;
        float4 b0 = *(const float4*)&Wgk[c0],      b1 = *(const float4*)&Wgk[c0 + 4];
        float4 b2 = *(const float4*)&Wgk[512 + c0], b3 = *(const float4*)&Wgk[512 + c0 + 4];
        gkl[0]=b0.x;gkl[1]=b0.y;gkl[2]=b0.z;gkl[3]=b0.w;gkl[4]=b1.x;gkl[5]=b1.y;gkl[6]=b1.z;gkl[7]=b1.w;
        gkh[0]=b2.x;gkh[1]=b2.y;gkh[2]=b2.z;gkh[3]=b2.w;gkh[4]=b3.x;gkh[5]=b3.y;gkh[6]=b3.z;gkh[7]=b3.w;
        float4 c0v = *(const float4*)&Wgv[c0],      c1v = *(const float4*)&Wgv[c0 + 4];
        float4 c2v = *(const float4*)&Wgv[512 + c0], c3v = *(const float4*)&Wgv[512 + c0 + 4];
        gvl[0]=c0v.x;gvl[1]=c0v.y;gvl[2]=c0v.z;gvl[3]=c0v.w;gvl[4]=c1v.x;gvl[5]=c1v.y;gvl[6]=c1v.z;gvl[7]=c1v.w;
        gvh[0]=c2v.x;gvh[1]=c2v.y;gvh[2]=c2v.z;gvh[3]=c2v.w;gvh[4]=c3v.x;gvh[5]=c3v.y;gvh[6]=c3v.z;gvh[7]=c3v.w;
    }
    float sq = 0.f, sk = 0.f, sv = 0.f;
    #pragma unroll
    for (int i = 0; i < 8; ++i) {
        sq += b2f(q8[i]) * gql[i] + aq[i] * gqh[i];
        sk += b2f(k8[i]) * gkl[i] + ak[i] * gkh[i];
        sv += b2f(v8[i]) * gvl[i] + av[i] * gvh[i];
    }
    #pragma unroll
    for (int o = 1; o < 64; o <<= 1) {
        sq += __shfl_xor(sq, o, 64);
        sk += __shfl_xor(sk, o, 64);
        sv += __shfl_xor(sv, o, 64);
    }
    float gq = 1.f / (1.f + expf(-(sq + bgq[0])));
    float gk = 1.f / (1.f + expf(-(sk + bgk[0])));
    float gv = 1.f / (1.f + expf(-(sv + bgv[0])));

    float wm8[8];
    {
        float4 m0 = *(const float4*)&WmD[c0], m1 = *(const float4*)&WmD[c0 + 4];
        wm8[0]=m0.x;wm8[1]=m0.y;wm8[2]=m0.z;wm8[3]=m0.w;wm8[4]=m1.x;wm8[5]=m1.y;wm8[6]=m1.z;wm8[7]=m1.w;
    }
    u16x8 oq8, ok8, ov8;
    float smd = 0.f;
    #pragma unroll
    for (int i = 0; i < 8; ++i) {
        float oq = (1.f - gq) * b2f(q8[i]) + gq * aq[i];
        oq8[i] = f2b(oq);
        ok8[i] = f2b((1.f - gk) * b2f(k8[i]) + gk * ak[i]);
        ov8[i] = f2b((1.f - gv) * b2f(v8[i]) + gv * av[i]);
        smd += oq * wm8[i];
    }
    *(u16x8*)&pkv[rb + c0]        = oq8;
    *(u16x8*)&pkv[rb + 512 + c0]  = ok8;
    *(u16x8*)&pkv[rb + 1024 + c0] = ov8;
    #pragma unroll
    for (int o = 1; o < 64; o <<= 1) smd += __shfl_xor(smd, o, 64);
    if (lane == 0)
        mD[bt] = C_D0 + 2.f * C_STD * tanhf((smd + bmD[0]) / C_GAMMA);
}

// ---------------------------------------------------------------------------
// V transpose: pkv v-section (b,t,h*64+d) -> vpT[(b*8+h)*64+d][t]
// ---------------------------------------------------------------------------
__global__ __launch_bounds__(256) void vtrans(
    const u16* __restrict__ pkv, u16* __restrict__ vpT)
{
    __shared__ u16 lt[64][72];
    const int t0 = blockIdx.x * 64;
    const int h = blockIdx.y, b = blockIdx.z;
    const int tid = threadIdx.x;
    #pragma unroll
    for (int p = 0; p < 2; ++p) {
        int s = tid + p * 256;
        int t = s >> 3, c8 = s & 7;
        u16x8 v = *(const u16x8*)&pkv[((size_t)(b*NT + t0 + t))*1536 + 1024 + h*NHD + c8*8];
        *(u16x8*)&lt[t][c8 * 8] = v;
    }
    __syncthreads();
    #pragma unroll
    for (int p = 0; p < 2; ++p) {
        int s = tid + p * 256;
        int d = s >> 3, c8 = s & 7;
        u16x8 o;
        #pragma unroll
        for (int j = 0; j < 8; ++j) o[j] = lt[c8 * 8 + j][d];
        *(u16x8*)&vpT[((size_t)((b*NH + h)*NHD + d))*NT + t0 + c8*8] = o;
    }
}

// ---------------------------------------------------------------------------
// MFMA flash attention — shifted 2-tile window (unchanged from R10).
// ---------------------------------------------------------------------------
__global__ __launch_bounds__(256) void attn_mfma(
    const u16* __restrict__ pkv, const u16* __restrict__ vpT,
    const float* __restrict__ mD, const int* __restrict__ mask,
    const float* __restrict__ rpe, u16* __restrict__ cxh)
{
    __shared__ __align__(16) char smem[38144];
    u16*  QP    = (u16*)(smem);              // Q (prologue), P (loop), wA (epi)
    u16*  Kl    = (u16*)(smem + 8192);       // K tile; epi: rvl linear / out-bounce
    u16*  Vl    = (u16*)(smem + 16384);      // V tile; prologue: rpk; epi: rvT
    u16*  rpk   = (u16*)(smem + 16384);
    u16*  rvl16 = (u16*)(smem + 8192);
    u16*  qdrl  = (u16*)(smem + 24576);      // [64][36] bf16
    float* wbufl= (float*)(smem + 29184);    // [64][34] fp32 (col 33 stays 0)
    float* inv2s= (float*)(smem + 37888);    // [64]

    const int tid  = threadIdx.x;
    const int lane = tid & 63;
    const int w    = tid >> 6;
    const int wq0  = w * 16;
    const int fr   = lane & 15;
    const int fq   = lane >> 4;
    const int b    = blockIdx.x >> 3;
    const int h    = blockIdx.x & 7;
    const int q0   = blockIdx.y * 64;

    const size_t qbase  = ((size_t)(b*NT + q0)) * 1536 + h * NHD;
    const size_t kbaseg = ((size_t)b * NT) * 1536 + 512 + h * NHD;
    const size_t vbaseg = ((size_t)((b*NH + h) * NHD)) * NT;

    // ---- sequence length L (first masked key), per-wave shuffle-min ----
    int Lm = 512;
    #pragma unroll
    for (int j = 0; j < 8; ++j) {
        if (mask[b * NT + lane + 64 * j]) Lm = min(Lm, lane + 64 * j);
    }
    #pragma unroll
    for (int o = 1; o < 64; o <<= 1) Lm = min(Lm, __shfl_xor(Lm, o, 64));
    const int L = Lm;
    const int w0 = max(0, min(q0 - 32, L - 128));

    // ---- prologue: reg-load Q, K[w0], V[w0]; swizzled ds_write of Q, K ----
    int r_[2], cs_[2];
    u16x8 qreg[2], kreg[2], vreg[2];
    #pragma unroll
    for (int p = 0; p < 2; ++p) {
        int s = tid + p * 256;
        r_[p] = s >> 3; cs_[p] = s & 7;
        qreg[p] = *(const u16x8*)(pkv + qbase  + (size_t)r_[p] * 1536 + cs_[p] * 8);
        kreg[p] = *(const u16x8*)(pkv + kbaseg + (size_t)(w0 + r_[p]) * 1536 + cs_[p] * 8);
        vreg[p] = *(const u16x8*)(vpT + vbaseg + (size_t)r_[p] * NT + w0 + cs_[p] * 8);
    }
    #pragma unroll
    for (int p = 0; p < 2; ++p) {
        *(u16x8*)(QP + SWU(r_[p], cs_[p])) = qreg[p];
        *(u16x8*)(Kl + SWU(r_[p], cs_[p])) = kreg[p];
    }
    // rpe_k -> rpk (in Vl space): 264 chunks, strided (264 > 256 threads!)
    for (int idx = tid; idx < 264; idx += 256) {
        int r = idx >> 3, c = idx & 7;
        float4 f0 = *(const float4*)&rpe[r * 128 + c * 8];
        float4 f1 = *(const float4*)&rpe[r * 128 + c * 8 + 4];
        u16x8 vv;
        vv[0]=f2b(f0.x); vv[1]=f2b(f0.y); vv[2]=f2b(f0.z); vv[3]=f2b(f0.w);
        vv[4]=f2b(f1.x); vv[5]=f2b(f1.y); vv[6]=f2b(f1.z); vv[7]=f2b(f1.w);
        *(u16x8*)(rpk + SWU(r, c)) = vv;
    }
    if (tid < 120) {   // zero rows 33..47
        u16x8 vv = {0,0,0,0,0,0,0,0};
        *(u16x8*)(rpk + (((33 + (tid >> 3)) * 8) + (tid & 7)) * 8) = vv;
    }
    if (tid < 64) {
        float md = mD[b * NT + q0 + tid];
        inv2s[tid] = 2.f * LOG2E / (md * md);
    }
    for (int i = tid; i < 64 * 34; i += 256) wbufl[i] = 0.f;
    __syncthreads();                                // (P0)

    // persistent Q A-frags (QP becomes Pl afterwards)
    bf16x8 aq0 = *(const bf16x8*)(QP + SWU(wq0 + fr, fq));
    bf16x8 aq1 = *(const bf16x8*)(QP + SWU(wq0 + fr, 4 + fq));

    // qdr[q][rd] = q . rpe_k[rd] via MFMA (reads rpk in Vl space)
    {
        f32x4 qd[3] = {};
        #pragma unroll
        for (int nf = 0; nf < 3; ++nf) {
            bf16x8 b0 = *(const bf16x8*)(rpk + SWU(nf * 16 + fr, fq));
            bf16x8 b1 = *(const bf16x8*)(rpk + SWU(nf * 16 + fr, 4 + fq));
            qd[nf] = __builtin_amdgcn_mfma_f32_16x16x32_bf16(aq0, b0, qd[nf], 0, 0, 0);
            qd[nf] = __builtin_amdgcn_mfma_f32_16x16x32_bf16(aq1, b1, qd[nf], 0, 0, 0);
        }
        #pragma unroll
        for (int nf = 0; nf < 3; ++nf) {
            int rd = nf * 16 + fr;
            if (rd < 33) {
                #pragma unroll
                for (int r = 0; r < 4; ++r)
                    qdrl[(wq0 + fq * 4 + r) * 36 + rd] = f2b(qd[nf][r]);
            }
        }
    }
    __syncthreads();                                // (P1) qdr done; rpk dead
    // V[w0] ds_write into Vl (visible at first iter's barrier (1))
    #pragma unroll
    for (int p = 0; p < 2; ++p)
        *(u16x8*)(Vl + SWU(r_[p], cs_[p])) = vreg[p];

    f32x4 O[4] = {};
    float m2[4] = {NEGINF, NEGINF, NEGINF, NEGINF};
    float li[4] = {};

    #pragma unroll
    for (int t = 0; t < 2; ++t) {
        const int kb = w0 + t * 64;
        const bool pre = (t == 0);
        u16x8 kreg2[2], vreg2[2];
        if (pre) {
            const int kn = kb + 64;
            #pragma unroll
            for (int p = 0; p < 2; ++p) {
                kreg2[p] = *(const u16x8*)(pkv + kbaseg + (size_t)(kn + r_[p]) * 1536 + cs_[p] * 8);
                vreg2[p] = *(const u16x8*)(vpT + vbaseg + (size_t)r_[p] * NT + kn + cs_[p] * 8);
            }
        }
        int mk[4];
        #pragma unroll
        for (int nf = 0; nf < 4; ++nf) mk[nf] = (kb + nf * 16 + fr) >= L;

        // ---- QK^T ----
        f32x4 s_[4] = {};
        #pragma unroll
        for (int nf = 0; nf < 4; ++nf) {
            bf16x8 b0 = *(const bf16x8*)(Kl + SWU(nf * 16 + fr, fq));
            bf16x8 b1 = *(const bf16x8*)(Kl + SWU(nf * 16 + fr, 4 + fq));
            s_[nf] = __builtin_amdgcn_mfma_f32_16x16x32_bf16(aq0, b0, s_[nf], 0, 0, 0);
            s_[nf] = __builtin_amdgcn_mfma_f32_16x16x32_bf16(aq1, b1, s_[nf], 0, 0, 0);
        }
        // ---- softmax (log2 domain) ----
        const bool leftfar  = (kb + 79 <= q0);
        const bool rightfar = (kb >= q0 + 79);
        const bool mid = !leftfar && !rightfar;

        float p_[4][4], alpha[4], rsum_[4], ls_[4], rs_[4];
        #pragma unroll
        for (int r = 0; r < 4; ++r) {
            const int lq = wq0 + fq * 4 + r;
            const int qg = q0 + lq;
            const float iv = inv2s[lq];
            const float qf = leftfar ? b2f(qdrl[lq * 36]) : (rightfar ? b2f(qdrl[lq * 36 + 32]) : 0.f);
            float mx = NEGINF;
            #pragma unroll
            for (int nf = 0; nf < 4; ++nf) {
                const int kg = kb + nf * 16 + fr;
                float sc;
                if (mk[nf]) sc = NEGINF;
                else {
                    float qr = mid ? b2f(qdrl[lq * 36 + (min(max(kg - qg, -MAXR), MAXR) + MAXR)]) : qf;
                    float fd = (float)(qg - kg);
                    sc = (s_[nf][r] + qr) * C1F - fd * fd * iv;
                }
                p_[r][nf] = sc;
                mx = fmaxf(mx, sc);
            }
            mx = fmaxf(mx, __shfl_xor(mx, 1, 64));
            mx = fmaxf(mx, __shfl_xor(mx, 2, 64));
            mx = fmaxf(mx, __shfl_xor(mx, 4, 64));
            mx = fmaxf(mx, __shfl_xor(mx, 8, 64));
            float mn = fmaxf(m2[r], mx);
            alpha[r] = exp2_fast(m2[r] - mn);
            m2[r] = mn;
            float rsum = 0.f, ls = 0.f, rs = 0.f;
            #pragma unroll
            for (int nf = 0; nf < 4; ++nf) {
                float pv = exp2_fast(p_[r][nf] - mn);
                p_[r][nf] = pv;
                rsum += pv;
                if (mid) {
                    int kg = kb + nf * 16 + fr;
                    if (kg <= qg - MAXR) ls += pv;
                    else if (kg >= qg + MAXR) rs += pv;
                }
            }
            rsum += __shfl_xor(rsum, 1, 64); rsum += __shfl_xor(rsum, 2, 64);
            rsum += __shfl_xor(rsum, 4, 64); rsum += __shfl_xor(rsum, 8, 64);
            if (mid) {
                ls += __shfl_xor(ls, 1, 64); ls += __shfl_xor(ls, 2, 64);
                ls += __shfl_xor(ls, 4, 64); ls += __shfl_xor(ls, 8, 64);
                rs += __shfl_xor(rs, 1, 64); rs += __shfl_xor(rs, 2, 64);
                rs += __shfl_xor(rs, 4, 64); rs += __shfl_xor(rs, 8, 64);
            }
            li[r] = li[r] * alpha[r] + rsum;
            rsum_[r] = rsum; ls_[r] = ls; rs_[r] = rs;
        }
        // O rescale
        #pragma unroll
        for (int nf = 0; nf < 4; ++nf) {
            O[nf][0] *= alpha[0]; O[nf][1] *= alpha[1];
            O[nf][2] *= alpha[2]; O[nf][3] *= alpha[3];
        }
        // wbuf rescale + tile contributions
        #pragma unroll
        for (int r = 0; r < 4; ++r) {
            int lq = wq0 + fq * 4 + r;
            if (alpha[r] != 1.f) {
                for (int c = fr; c < 33; c += 16) wbufl[lq * 34 + c] *= alpha[r];
            }
        }
        if (fr == 0) {
            #pragma unroll
            for (int r = 0; r < 4; ++r) {
                int lq = wq0 + fq * 4 + r;
                if (leftfar)       wbufl[lq * 34]      += rsum_[r];
                else if (rightfar) wbufl[lq * 34 + 32] += rsum_[r];
                else { wbufl[lq * 34] += ls_[r]; wbufl[lq * 34 + 32] += rs_[r]; }
            }
        }
        if (mid) {
            #pragma unroll
            for (int r = 0; r < 4; ++r) {
                int lq = wq0 + fq * 4 + r, qg = q0 + lq;
                #pragma unroll
                for (int nf = 0; nf < 4; ++nf) {
                    int d = kb + nf * 16 + fr - qg;
                    if (d > -MAXR && d < MAXR) wbufl[lq * 34 + d + MAXR] += p_[r][nf];
                }
            }
        }
        // ---- P -> bf16 LDS (swizzled, in QP space) ----
        #pragma unroll
        for (int r = 0; r < 4; ++r) {
            int lq = wq0 + fq * 4 + r;
            #pragma unroll
            for (int nf = 0; nf < 4; ++nf) {
                int k = nf * 16 + fr;
                QP[lq * 64 + (((k >> 3) ^ (lq & 7)) << 3) + (k & 7)] = f2b(p_[r][nf]);
            }
        }
        __syncthreads();    // (1) P + V(t) visible; all QK reads of Kl done
        // K(t+1) into Kl (QK done; PV doesn't touch Kl)
        if (pre) {
            #pragma unroll
            for (int p = 0; p < 2; ++p)
                *(u16x8*)(Kl + SWU(r_[p], cs_[p])) = kreg2[p];
        }
        // ---- PV ----
        bf16x8 ap0 = *(const bf16x8*)(QP + SWU(wq0 + fr, fq));
        bf16x8 ap1 = *(const bf16x8*)(QP + SWU(wq0 + fr, 4 + fq));
        #pragma unroll
        for (int nf = 0; nf < 4; ++nf) {
            bf16x8 v0 = *(const bf16x8*)(Vl + SWU(nf * 16 + fr, fq));
            bf16x8 v1 = *(const bf16x8*)(Vl + SWU(nf * 16 + fr, 4 + fq));
            O[nf] = __builtin_amdgcn_mfma_f32_16x16x32_bf16(ap0, v0, O[nf], 0, 0, 0);
            O[nf] = __builtin_amdgcn_mfma_f32_16x16x32_bf16(ap1, v1, O[nf], 0, 0, 0);
        }
        __syncthreads();    // (2) PV reads of Vl/QP done; K(t+1) visible
        // V(t+1) into Vl (visible at next iter's barrier (1))
        if (pre) {
            #pragma unroll
            for (int p = 0; p < 2; ++p)
                *(u16x8*)(Vl + SWU(r_[p], cs_[p])) = vreg2[p];
        }
    }

    // ---- epilogue: O += wbuf @ rpe_v via MFMA ----
    for (int idx = tid; idx < 264; idx += 256) {   // strided: 264 > 256
        int r = idx >> 3, c = idx & 7;
        float4 f0 = *(const float4*)&rpe[r * 128 + 64 + c * 8];
        float4 f1 = *(const float4*)&rpe[r * 128 + 64 + c * 8 + 4];
        u16x8 vv;
        vv[0]=f2b(f0.x); vv[1]=f2b(f0.y); vv[2]=f2b(f0.z); vv[3]=f2b(f0.w);
        vv[4]=f2b(f1.x); vv[5]=f2b(f1.y); vv[6]=f2b(f1.z); vv[7]=f2b(f1.w);
        *(u16x8*)(rvl16 + (r * 8 + c) * 8) = vv;
    }
    // wA[q][rd] bf16 swizzled into QP; cols 34..63 zero (col 33 already 0)
    #pragma unroll
    for (int p = 0; p < 2; ++p) {
        int r = r_[p], cs = cs_[p];
        u16x8 vv;
        #pragma unroll
        for (int j = 0; j < 8; ++j) {
            int col = cs * 8 + j;
            vv[j] = (col < 34) ? f2b(wbufl[r * 34 + col]) : (u16)0;
        }
        *(u16x8*)(QP + SWU(r, cs)) = vv;
    }
    __syncthreads();   // (E1) rvl + wA ready (wbuf reads complete)
    // Build rvT[d][rd] bf16 swizzled into Vl from linear rvl16
    #pragma unroll
    for (int p = 0; p < 2; ++p) {
        int d = r_[p], cs = cs_[p];
        u16x8 vv;
        #pragma unroll
        for (int j = 0; j < 8; ++j) {
            int rd = cs * 8 + j;
            vv[j] = (rd < 33) ? rvl16[rd * 64 + d] : (u16)0;
        }
        *(u16x8*)(Vl + SWU(d, cs)) = vv;
    }
    __syncthreads();   // (E2) rvT ready
    {
        bf16x8 aw0 = *(const bf16x8*)(QP + SWU(wq0 + fr, fq));
        bf16x8 aw1 = *(const bf16x8*)(QP + SWU(wq0 + fr, 4 + fq));
        #pragma unroll
        for (int nf = 0; nf < 4; ++nf) {
            bf16x8 b0 = *(const bf16x8*)(Vl + SWU(nf * 16 + fr, fq));
            bf16x8 b1 = *(const bf16x8*)(Vl + SWU(nf * 16 + fr, 4 + fq));
            O[nf] = __builtin_amdgcn_mfma_f32_16x16x32_bf16(aw0, b0, O[nf], 0, 0, 0);
            O[nf] = __builtin_amdgcn_mfma_f32_16x16x32_bf16(aw1, b1, O[nf], 0, 0, 0);
        }
    }
    float invl[4];
    #pragma unroll
    for (int r = 0; r < 4; ++r) invl[r] = 1.f / li[r];
    #pragma unroll
    for (int r = 0; r < 4; ++r) {
        int lq = wq0 + fq * 4 + r;
        #pragma unroll
        for (int nf = 0; nf < 4; ++nf)
            Kl[lq * 64 + nf * 16 + fr] = f2b(O[nf][r] * invl[r]);   // linear bounce
    }
    __syncthreads();   // (E3)
    #pragma unroll
    for (int j = 0; j < 2; ++j) {
        int s = w * 128 + j * 64 + lane;
        int rr = s >> 3, c8 = s & 7;
        u16x8 vv = *(const u16x8*)(Kl + rr * 64 + c8 * 8);
        *(u16x8*)&cxh[((size_t)(b*NT + q0 + rr)) * 512 + h * NHD + c8 * 8] = vv;
    }
}

// ---------------------------------------------------------------------------
extern "C" void kernel_launch(void* const* d_in, const int* in_sizes, int n_in,
                              void* d_out, int out_size, void* d_ws, size_t ws_size,
                              hipStream_t stream) {
    const float* key   = (const float*)d_in[0];
    const float* value = (const float*)d_in[1];
    const float* query = (const float*)d_in[2];
    const int*   mask  = (const int*)d_in[3];
    const float* Wq  = (const float*)d_in[4];
    const float* bq  = (const float*)d_in[5];
    const float* Wk  = (const float*)d_in[6];
    const float* bk  = (const float*)d_in[7];
    const float* Wv  = (const float*)d_in[8];
    const float* bv  = (const float*)d_in[9];
    const float* Wcq = (const float*)d_in[10];
    const float* Wck = (const float*)d_in[11];
    const float* Wcv = (const float*)d_in[12];
    const float* Wgq = (const float*)d_in[13];
    const float* bgq = (const float*)d_in[14];
    const float* Wgk = (const float*)d_in[15];
    const float* bgk = (const float*)d_in[16];
    const float* Wgv = (const float*)d_in[17];
    const float* bgv = (const float*)d_in[18];
    const float* WmD = (const float*)d_in[19];
    const float* bmD = (const float*)d_in[20];
    const float* rpe = (const float*)d_in[21];
    const float* Wo  = (const float*)d_in[22];
    const float* bo  = (const float*)d_in[23];
    float* out = (float*)d_out;

    const size_t NTOK = (size_t)NB * NT;            // 8192
    const size_t NE   = NTOK * NSZ;                 // 4,194,304
    const size_t NW   = (size_t)NSZ * NSZ;          // 262,144

    u16* ws16 = (u16*)d_ws;
    u16* pkv  = ws16;                // (8192, 1536) q|k|v
    u16* wcat = pkv + NTOK * 1536;   // 3 x (512,512)
    u16* woh  = wcat + 3 * NW;
    u16* vpT  = woh + NW;            // (16*8*64, 512)
    u16* cxh  = vpT + NE;            // (8192, 512)
    float* mDb = (float*)(cxh + NE);
    float* WcT = mDb + NTOK;         // 3 x (5,512) fp32

    cvt4_bf16<<<dim3((unsigned)(NW/8/256), 4), 256, 0, stream>>>(
        Wq, Wk, Wv, Wo, wcat, wcat + NW, wcat + 2*NW, woh, (int)NW);
    wprep<<<dim3(10, 3), 256, 0, stream>>>(Wcq, Wck, Wcv, WcT);

    gemm_qkv<<<dim3(64, 4, 3), 256, 0, stream>>>(
        query, key, value, wcat, bq, bk, bv, pkv);

    conv_gate_all<<<(int)(NTOK / 4), 256, 0, stream>>>(
        key, pkv, WcT, Wgq, bgq, Wgk, bgk, Wgv, bgv, WmD, bmD, mDb);

    vtrans<<<dim3(8, 8, 16), 256, 0, stream>>>(pkv, vpT);

    attn_mfma<<<dim3(128, 8), 256, 0, stream>>>(pkv, vpT, mDb, mask, rpe, cxh);

    gemm_out<<<dim3(128, 4), 256, 0, stream>>>(cxh, woh, bo, out, (int)NTOK, NSZ, NSZ);
}

// Round 14
// 115.615 us; speedup vs baseline: 1.9312x; 1.0082x over previous
//
#include <hip/hip_runtime.h>
#include <math.h>

#define NB 16
#define NT 512
#define NSZ 512
#define NH 8
#define NHD 64
#define MAXR 16

#define C_D0 6.3f
#define C_STD 1.4f
#define C_GAMMA 2.0f

#define NEGINF (-1e30f)
#define LOG2E 1.4426950408889634f
#define C1F   0.18033688011112042f   // 0.125 * log2(e)

typedef unsigned short u16;
typedef __attribute__((ext_vector_type(8))) short bf16x8;
typedef __attribute__((ext_vector_type(4))) float f32x4;
typedef __attribute__((ext_vector_type(8))) unsigned short u16x8;

__device__ __forceinline__ u16 f2b(float f) {
    union { float f; unsigned int u; } c; c.f = f;
    unsigned int u = c.u + 0x7FFFu + ((c.u >> 16) & 1u);
    return (u16)(u >> 16);
}
__device__ __forceinline__ float b2f(u16 h) {
    union { unsigned int u; float f; } c; c.u = ((unsigned int)h) << 16;
    return c.f;
}

#if __has_builtin(__builtin_amdgcn_exp2f)
__device__ __forceinline__ float exp2_fast(float x) { return __builtin_amdgcn_exp2f(x); }
#else
__device__ __forceinline__ float exp2_fast(float x) { return exp2f(x); }
#endif

#define GL2LDS(gp, lp) __builtin_amdgcn_global_load_lds( \
    (const __attribute__((address_space(1))) void*)(gp), \
    (__attribute__((address_space(3))) void*)(lp), 16, 0, 0)

// swizzled u16-index of 16B chunk c in row r (8-chunk rows = 64 bf16)
#define SWU(r, c) ((((r) * 8) + ((c) ^ ((r) & 7))) * 8)
// swizzled u16-index for 16-chunk rows (128 bf16 per row)
#define SWU16(r, c) ((((r) * 16) + ((c) ^ ((r) & 7))) * 8)

// ---------------------------------------------------------------------------
// fp32 -> bf16 convert (weights only)
// ---------------------------------------------------------------------------
__global__ __launch_bounds__(256) void cvt4_bf16(
    const float* __restrict__ s0, const float* __restrict__ s1,
    const float* __restrict__ s2, const float* __restrict__ s3,
    u16* __restrict__ d0, u16* __restrict__ d1,
    u16* __restrict__ d2, u16* __restrict__ d3, int n)
{
    const float* s; u16* d;
    switch (blockIdx.y) {
        case 0: s = s0; d = d0; break;
        case 1: s = s1; d = d1; break;
        case 2: s = s2; d = d2; break;
        default: s = s3; d = d3; break;
    }
    int i = (blockIdx.x * 256 + threadIdx.x) * 8;
    if (i >= n) return;
    float4 a = *(const float4*)&s[i];
    float4 b = *(const float4*)&s[i + 4];
    u16x8 v;
    v[0]=f2b(a.x); v[1]=f2b(a.y); v[2]=f2b(a.z); v[3]=f2b(a.w);
    v[4]=f2b(b.x); v[5]=f2b(b.y); v[6]=f2b(b.z); v[7]=f2b(b.w);
    *(u16x8*)&d[i] = v;
}

// ---------------------------------------------------------------------------
// Conv-weight transpose: Wc_z[512][5] -> WcT[z][5][512]  (fp32, one-time)
// ---------------------------------------------------------------------------
__global__ __launch_bounds__(256) void wprep(
    const float* __restrict__ Wcq, const float* __restrict__ Wck,
    const float* __restrict__ Wcv, float* __restrict__ WcT)
{
    const int z = blockIdx.y;
    const float* src = z == 0 ? Wcq : (z == 1 ? Wck : Wcv);
    int idx = blockIdx.x * 256 + threadIdx.x;
    if (idx >= 2560) return;
    int c = idx / 5, j = idx % 5;
    WcT[(size_t)z * 2560 + j * 512 + c] = src[idx];
}

// ---------------------------------------------------------------------------
// QKV projections, z-batched. R14: 64x128 tile (gemm_out skeleton) ->
// 1536 blocks = 6/CU (was 128x128 @ 768 blocks = 3/CU, 21% occupancy).
// A fp32 reg-staged with in-flight bf16 convert (same rounding as before).
// ---------------------------------------------------------------------------
__global__ __launch_bounds__(256) void gemm_qkv(
    const float* __restrict__ A0, const float* __restrict__ A1, const float* __restrict__ A2,
    const u16* __restrict__ Wc,
    const float* __restrict__ bq, const float* __restrict__ bk, const float* __restrict__ bv,
    u16* __restrict__ pkv)
{
    __shared__ u16 Al[64 * 32];
    __shared__ u16 Bl[128 * 32];
    const int z = blockIdx.z;
    const float* A = z == 0 ? A0 : (z == 1 ? A1 : A2);
    const u16* W = Wc + (size_t)z * NSZ * NSZ;
    const float* bias = z == 0 ? bq : (z == 1 ? bk : bv);
    const int tid = threadIdx.x;
    const int m0 = blockIdx.x * 64;
    const int n0 = blockIdx.y * 128;
    const int w = tid >> 6, lane = tid & 63;
    const int wm = (w >> 1) * 32, wn = (w & 1) * 64;
    const int fr = lane & 15, fk = lane >> 4;

    f32x4 acc[2][4] = {};
    for (int k0 = 0; k0 < NSZ; k0 += 32) {
        float4 a0, a1;
        {
            int row = tid >> 2, cb = tid & 3;
            const float* ga = &A[(size_t)(m0 + row) * NSZ + k0 + cb * 8];
            a0 = *(const float4*)ga;
            a1 = *(const float4*)(ga + 4);
        }
        #pragma unroll
        for (int p = 0; p < 2; ++p) {
            int s = tid + p * 256;
            int row = s >> 2, cb = s & 3;
            GL2LDS(&W[(size_t)(n0 + row) * NSZ + k0 + cb * 8], &Bl[s * 8]);
        }
        {
            u16x8 v;
            v[0]=f2b(a0.x); v[1]=f2b(a0.y); v[2]=f2b(a0.z); v[3]=f2b(a0.w);
            v[4]=f2b(a1.x); v[5]=f2b(a1.y); v[6]=f2b(a1.z); v[7]=f2b(a1.w);
            *(u16x8*)&Al[tid * 8] = v;
        }
        __syncthreads();
        bf16x8 af[2], bfr[4];
        #pragma unroll
        for (int mf = 0; mf < 2; ++mf)
            af[mf] = *(const bf16x8*)&Al[(wm + mf * 16 + fr) * 32 + fk * 8];
        #pragma unroll
        for (int nf = 0; nf < 4; ++nf)
            bfr[nf] = *(const bf16x8*)&Bl[(wn + nf * 16 + fr) * 32 + fk * 8];
        #pragma unroll
        for (int mf = 0; mf < 2; ++mf)
            #pragma unroll
            for (int nf = 0; nf < 4; ++nf)
                acc[mf][nf] = __builtin_amdgcn_mfma_f32_16x16x32_bf16(
                    af[mf], bfr[nf], acc[mf][nf], 0, 0, 0);
        __syncthreads();
    }
    #pragma unroll
    for (int mf = 0; mf < 2; ++mf) {
        #pragma unroll
        for (int nf = 0; nf < 4; ++nf) {
            int col = n0 + wn + nf * 16 + fr;
            float bvv = bias[col];
            #pragma unroll
            for (int r = 0; r < 4; ++r) {
                int rowg = m0 + wm + mf * 16 + fk * 4 + r;
                pkv[(size_t)rowg * 1536 + z * 512 + col] = f2b(acc[mf][nf][r] + bvv);
            }
        }
    }
}

// ---------------------------------------------------------------------------
// Output projection (fp32 out). 64x128 tile (unchanged from R13).
// ---------------------------------------------------------------------------
__global__ __launch_bounds__(256) void gemm_out(
    const u16* __restrict__ A, const u16* __restrict__ W,
    const float* __restrict__ bias, float* __restrict__ Cout, int M, int N, int K)
{
    __shared__ u16 Al[64 * 32];
    __shared__ u16 Bl[128 * 32];
    const int tid = threadIdx.x;
    const int m0 = blockIdx.x * 64;
    const int n0 = blockIdx.y * 128;
    const int w = tid >> 6, lane = tid & 63;
    const int wm = (w >> 1) * 32, wn = (w & 1) * 64;
    const int fr = lane & 15, fk = lane >> 4;

    f32x4 acc[2][4] = {};
    for (int k0 = 0; k0 < K; k0 += 32) {
        {
            int row = tid >> 2, cb = tid & 3;
            GL2LDS(&A[(size_t)(m0 + row) * K + k0 + cb * 8], &Al[tid * 8]);
        }
        #pragma unroll
        for (int p = 0; p < 2; ++p) {
            int s = tid + p * 256;
            int row = s >> 2, cb = s & 3;
            GL2LDS(&W[(size_t)(n0 + row) * K + k0 + cb * 8], &Bl[s * 8]);
        }
        __syncthreads();
        bf16x8 af[2], bfr[4];
        #pragma unroll
        for (int mf = 0; mf < 2; ++mf)
            af[mf] = *(const bf16x8*)&Al[(wm + mf * 16 + fr) * 32 + fk * 8];
        #pragma unroll
        for (int nf = 0; nf < 4; ++nf)
            bfr[nf] = *(const bf16x8*)&Bl[(wn + nf * 16 + fr) * 32 + fk * 8];
        #pragma unroll
        for (int mf = 0; mf < 2; ++mf)
            #pragma unroll
            for (int nf = 0; nf < 4; ++nf)
                acc[mf][nf] = __builtin_amdgcn_mfma_f32_16x16x32_bf16(
                    af[mf], bfr[nf], acc[mf][nf], 0, 0, 0);
        __syncthreads();
    }
    #pragma unroll
    for (int mf = 0; mf < 2; ++mf) {
        #pragma unroll
        for (int nf = 0; nf < 4; ++nf) {
            int col = n0 + wn + nf * 16 + fr;
            float bv = bias[col];
            #pragma unroll
            for (int r = 0; r < 4; ++r) {
                int rowg = m0 + wm + mf * 16 + fk * 4 + r;
                Cout[(size_t)rowg * N + col] = acc[mf][nf][r] + bv;
            }
        }
    }
}

// ---------------------------------------------------------------------------
// Fused 3x depthwise conv1d(k=5) + 3 scalar gates + mD (R13 proven version).
// ---------------------------------------------------------------------------
__global__ void conv_gate_all(
    const float* __restrict__ xn, u16* __restrict__ pkv,
    const float* __restrict__ WcT,
    const float* __restrict__ Wgq, const float* __restrict__ bgq,
    const float* __restrict__ Wgk, const float* __restrict__ bgk,
    const float* __restrict__ Wgv, const float* __restrict__ bgv,
    const float* __restrict__ WmD, const float* __restrict__ bmD,
    float* __restrict__ mD)
{
    const int w = threadIdx.x >> 6, lane = threadIdx.x & 63;
    const int bt = blockIdx.x * 4 + w;
    const int b = bt >> 9, tpos = bt & (NT - 1);
    const int c0 = lane * 8;

    float x[5][8];
    #pragma unroll
    for (int j = 0; j < 5; ++j) {
        int tt = tpos + j - 2;
        if (tt >= 0 && tt < NT) {
            const float4* xp = (const float4*)&xn[((size_t)(b*NT + tt))*NSZ + c0];
            float4 u0 = xp[0], u1 = xp[1];
            x[j][0]=u0.x; x[j][1]=u0.y; x[j][2]=u0.z; x[j][3]=u0.w;
            x[j][4]=u1.x; x[j][5]=u1.y; x[j][6]=u1.z; x[j][7]=u1.w;
        } else {
            #pragma unroll
            for (int i = 0; i < 8; ++i) x[j][i] = 0.f;
        }
    }
    float aq[8] = {}, ak[8] = {}, av[8] = {};
    #pragma unroll
    for (int j = 0; j < 5; ++j) {
        const float* wq = &WcT[j * 512 + c0];
        const float* wk = &WcT[2560 + j * 512 + c0];
        const float* wv = &WcT[5120 + j * 512 + c0];
        float4 q0 = *(const float4*)wq, q1 = *(const float4*)(wq + 4);
        float4 k0 = *(const float4*)wk, k1 = *(const float4*)(wk + 4);
        float4 v0 = *(const float4*)wv, v1 = *(const float4*)(wv + 4);
        float wq8[8] = {q0.x,q0.y,q0.z,q0.w,q1.x,q1.y,q1.z,q1.w};
        float wk8[8] = {k0.x,k0.y,k0.z,k0.w,k1.x,k1.y,k1.z,k1.w};
        float wv8[8] = {v0.x,v0.y,v0.z,v0.w,v1.x,v1.y,v1.z,v1.w};
        #pragma unroll
        for (int i = 0; i < 8; ++i) {
            aq[i] += x[j][i] * wq8[i];
            ak[i] += x[j][i] * wk8[i];
            av[i] += x[j][i] * wv8[i];
        }
    }
    const size_t rb = (size_t)bt * 1536;
    u16x8 q8 = *(const u16x8*)&pkv[rb + c0];
    u16x8 k8 = *(const u16x8*)&pkv[rb + 512 + c0];
    u16x8 v8 = *(const u16x8*)&pkv[rb + 1024 + c0];

    float gql[8], gqh[8], gkl[8], gkh[8], gvl[8], gvh[8];
    {
        float4 a0 = *(const float4*)&Wgq[c0],      a1 = *(const float4*)&Wgq[c0 + 4];
        float4 a2 = *(const float4*)&Wgq[512 + c0], a3 = *(const float4*)&Wgq[512 + c0 + 4];
        gql[0]=a0.x;gql[1]=a0.y;gql[2]=a0.z;gql[3]=a0.w;gql[4]=a1.x;gql[5]=a1.y;gql[6]=a1.z;gql[7]=a1.w;
        gqh[0]=a2.x;gqh[1]=a2.y;gqh[2]=a2.z;gqh[3]=a2.w;gqh[4]=a3.x;gqh[5]=a3.y;gqh[6]=a3.z;gqh[7]=a3.w;
        float4 b0 = *(const float4*)&Wgk[c0],      b1 = *(const float4*)&Wgk[c0 + 4];
        float4 b2 = *(const float4*)&Wgk[512 + c0], b3 = *(const float4*)&Wgk[512 + c0 + 4];
        gkl[0]=b0.x;gkl[1]=b0.y;gkl[2]=b0.z;gkl[3]=b0.w;gkl[4]=b1.x;gkl[5]=b1.y;gkl[6]=b1.z;gkl[7]=b1.w;
        gkh[0]=b2.x;gkh[1]=b2.y;gkh[2]=b2.z;gkh[3]=b2.w;gkh[4]=b3.x;gkh[5]=b3.y;gkh[6]=b3.z;gkh[7]=b3.w;
        float4 c0v = *(const float4*)&Wgv[c0],      c1v = *(const float4*)&Wgv[c0 + 4];
        float4 c2v = *(const float4*)&Wgv[512 + c0], c3v = *(const float4*)&Wgv[512 + c0 + 4];
        gvl[0]=c0v.x;gvl[1]=c0v.y;gvl[2]=c0v.z;gvl[3]=c0v.w;gvl[4]=c1v.x;gvl[5]=c1v.y;gvl[6]=c1v.z;gvl[7]=c1v.w;
        gvh[0]=c2v.x;gvh[1]=c2v.y;gvh[2]=c2v.z;gvh[3]=c2v.w;gvh[4]=c3v.x;gvh[5]=c3v.y;gvh[6]=c3v.z;gvh[7]=c3v.w;
    }
    float sq = 0.f, sk = 0.f, sv = 0.f;
    #pragma unroll
    for (int i = 0; i < 8; ++i) {
        sq += b2f(q8[i]) * gql[i] + aq[i] * gqh[i];
        sk += b2f(k8[i]) * gkl[i] + ak[i] * gkh[i];
        sv += b2f(v8[i]) * gvl[i] + av[i] * gvh[i];
    }
    #pragma unroll
    for (int o = 1; o < 64; o <<= 1) {
        sq += __shfl_xor(sq, o, 64);
        sk += __shfl_xor(sk, o, 64);
        sv += __shfl_xor(sv, o, 64);
    }
    float gq = 1.f / (1.f + expf(-(sq + bgq[0])));
    float gk = 1.f / (1.f + expf(-(sk + bgk[0])));
    float gv = 1.f / (1.f + expf(-(sv + bgv[0])));

    float wm8[8];
    {
        float4 m0 = *(const float4*)&WmD[c0], m1 = *(const float4*)&WmD[c0 + 4];
        wm8[0]=m0.x;wm8[1]=m0.y;wm8[2]=m0.z;wm8[3]=m0.w;wm8[4]=m1.x;wm8[5]=m1.y;wm8[6]=m1.z;wm8[7]=m1.w;
    }
    u16x8 oq8, ok8, ov8;
    float smd = 0.f;
    #pragma unroll
    for (int i = 0; i < 8; ++i) {
        float oq = (1.f - gq) * b2f(q8[i]) + gq * aq[i];
        oq8[i] = f2b(oq);
        ok8[i] = f2b((1.f - gk) * b2f(k8[i]) + gk * ak[i]);
        ov8[i] = f2b((1.f - gv) * b2f(v8[i]) + gv * av[i]);
        smd += oq * wm8[i];
    }
    *(u16x8*)&pkv[rb + c0]        = oq8;
    *(u16x8*)&pkv[rb + 512 + c0]  = ok8;
    *(u16x8*)&pkv[rb + 1024 + c0] = ov8;
    #pragma unroll
    for (int o = 1; o < 64; o <<= 1) smd += __shfl_xor(smd, o, 64);
    if (lane == 0)
        mD[bt] = C_D0 + 2.f * C_STD * tanhf((smd + bmD[0]) / C_GAMMA);
}

// ---------------------------------------------------------------------------
// V transpose: pkv v-section (b,t,h*64+d) -> vpT[(b*8+h)*64+d][t]
// ---------------------------------------------------------------------------
__global__ __launch_bounds__(256) void vtrans(
    const u16* __restrict__ pkv, u16* __restrict__ vpT)
{
    __shared__ u16 lt[64][72];
    const int t0 = blockIdx.x * 64;
    const int h = blockIdx.y, b = blockIdx.z;
    const int tid = threadIdx.x;
    #pragma unroll
    for (int p = 0; p < 2; ++p) {
        int s = tid + p * 256;
        int t = s >> 3, c8 = s & 7;
        u16x8 v = *(const u16x8*)&pkv[((size_t)(b*NT + t0 + t))*1536 + 1024 + h*NHD + c8*8];
        *(u16x8*)&lt[t][c8 * 8] = v;
    }
    __syncthreads();
    #pragma unroll
    for (int p = 0; p < 2; ++p) {
        int s = tid + p * 256;
        int d = s >> 3, c8 = s & 7;
        u16x8 o;
        #pragma unroll
        for (int j = 0; j < 8; ++j) o[j] = lt[c8 * 8 + j][d];
        *(u16x8*)&vpT[((size_t)((b*NH + h)*NHD + d))*NT + t0 + c8*8] = o;
    }
}

// ---------------------------------------------------------------------------
// MFMA flash attention — R14: single-pass over the full 128-wide window.
// K[128]/V[128] staged once; one QK pass, ONE global-max softmax (no online
// rescale, no running m/l, no K/V prefetch), one PV. wbuf is write-once ->
// stored directly as the bf16 epilogue A-operand (wA). 5 barriers total.
// Window/masking identical to R10-R13 (w0 = max(0,min(q0-32,L-128))).
// ---------------------------------------------------------------------------
__global__ __launch_bounds__(256) void attn_mfma(
    const u16* __restrict__ pkv, const u16* __restrict__ vpT,
    const float* __restrict__ mD, const int* __restrict__ mask,
    const float* __restrict__ rpe, u16* __restrict__ cxh)
{
    __shared__ __align__(16) char smem[70400];
    u16*  Ql    = (u16*)(smem);              // [64][8ch] swz (8 KB)
    u16*  Kl    = (u16*)(smem + 8192);       // [128][8ch] swz (16 KB)
    u16*  Vl    = (u16*)(smem + 24576);      // [64][16ch] swz (16 KB); epi: rvT [64][8ch] swz
    u16*  Pl    = (u16*)(smem + 40960);      // prologue: rpk [48][8ch]; loop: P [64][16ch]; epi: out-bounce
    u16*  rpk   = (u16*)(smem + 40960);
    u16*  wA16  = (u16*)(smem + 57344);      // [64][8ch] swz bf16, write-once buckets (8 KB)
    u16*  qdrl  = (u16*)(smem + 65536);      // [64][36] bf16
    float* inv2s= (float*)(smem + 70144);    // [64]

    const int tid  = threadIdx.x;
    const int lane = tid & 63;
    const int w    = tid >> 6;
    const int wq0  = w * 16;
    const int fr   = lane & 15;
    const int fq   = lane >> 4;
    const int b    = blockIdx.x >> 3;
    const int h    = blockIdx.x & 7;
    const int q0   = blockIdx.y * 64;

    const size_t qbase  = ((size_t)(b*NT + q0)) * 1536 + h * NHD;
    const size_t kbaseg = ((size_t)b * NT) * 1536 + 512 + h * NHD;
    const size_t vbaseg = ((size_t)((b*NH + h) * NHD)) * NT;

    // ---- sequence length L, window base w0 ----
    int Lm = 512;
    #pragma unroll
    for (int j = 0; j < 8; ++j) {
        if (mask[b * NT + lane + 64 * j]) Lm = min(Lm, lane + 64 * j);
    }
    #pragma unroll
    for (int o = 1; o < 64; o <<= 1) Lm = min(Lm, __shfl_xor(Lm, o, 64));
    const int L = Lm;
    const int w0 = max(0, min(q0 - 32, L - 128));

    // ---- prologue: stage Q[64], K[128], V[128], rpk; zero wA ----
    #pragma unroll
    for (int p = 0; p < 2; ++p) {           // Q: 512 chunks
        int s = tid + p * 256;
        int r = s >> 3, c = s & 7;
        u16x8 v = *(const u16x8*)(pkv + qbase + (size_t)r * 1536 + c * 8);
        *(u16x8*)(Ql + SWU(r, c)) = v;
    }
    #pragma unroll
    for (int p = 0; p < 4; ++p) {           // K: 128 rows x 8 chunks
        int s = tid + p * 256;
        int r = s >> 3, c = s & 7;
        u16x8 v = *(const u16x8*)(pkv + kbaseg + (size_t)(w0 + r) * 1536 + c * 8);
        *(u16x8*)(Kl + SWU(r, c)) = v;
    }
    #pragma unroll
    for (int p = 0; p < 4; ++p) {           // V: 64 rows(d) x 16 chunks(t)
        int s = tid + p * 256;
        int d = s >> 4, cc = s & 15;
        u16x8 v = *(const u16x8*)(vpT + vbaseg + (size_t)d * NT + w0 + cc * 8);
        *(u16x8*)(Vl + SWU16(d, cc)) = v;
    }
    for (int idx = tid; idx < 264; idx += 256) {   // rpe_k -> rpk (in Pl space)
        int r = idx >> 3, c = idx & 7;
        float4 f0 = *(const float4*)&rpe[r * 128 + c * 8];
        float4 f1 = *(const float4*)&rpe[r * 128 + c * 8 + 4];
        u16x8 vv;
        vv[0]=f2b(f0.x); vv[1]=f2b(f0.y); vv[2]=f2b(f0.z); vv[3]=f2b(f0.w);
        vv[4]=f2b(f1.x); vv[5]=f2b(f1.y); vv[6]=f2b(f1.z); vv[7]=f2b(f1.w);
        *(u16x8*)(rpk + SWU(r, c)) = vv;
    }
    if (tid < 120) {                        // zero rpk rows 33..47
        u16x8 vv = {0,0,0,0,0,0,0,0};
        *(u16x8*)(rpk + (((33 + (tid >> 3)) * 8) + (tid & 7)) * 8) = vv;
    }
    {   // zero wA (write-once buckets; cols 34..63 stay 0 for the epilogue MFMA)
        u16x8 z = {0,0,0,0,0,0,0,0};
        #pragma unroll
        for (int p = 0; p < 2; ++p) *(u16x8*)(wA16 + (tid + p * 256) * 8) = z;
    }
    if (tid < 64) {
        float md = mD[b * NT + q0 + tid];
        inv2s[tid] = 2.f * LOG2E / (md * md);
    }
    __syncthreads();                        // (P0) everything staged

    // persistent Q A-frags
    bf16x8 aq0 = *(const bf16x8*)(Ql + SWU(wq0 + fr, fq));
    bf16x8 aq1 = *(const bf16x8*)(Ql + SWU(wq0 + fr, 4 + fq));

    // qdr[q][rd] = q . rpe_k[rd] via MFMA
    {
        f32x4 qd[3] = {};
        #pragma unroll
        for (int nf = 0; nf < 3; ++nf) {
            bf16x8 b0 = *(const bf16x8*)(rpk + SWU(nf * 16 + fr, fq));
            bf16x8 b1 = *(const bf16x8*)(rpk + SWU(nf * 16 + fr, 4 + fq));
            qd[nf] = __builtin_amdgcn_mfma_f32_16x16x32_bf16(aq0, b0, qd[nf], 0, 0, 0);
            qd[nf] = __builtin_amdgcn_mfma_f32_16x16x32_bf16(aq1, b1, qd[nf], 0, 0, 0);
        }
        #pragma unroll
        for (int nf = 0; nf < 3; ++nf) {
            int rd = nf * 16 + fr;
            if (rd < 33) {
                #pragma unroll
                for (int r = 0; r < 4; ++r)
                    qdrl[(wq0 + fq * 4 + r) * 36 + rd] = f2b(qd[nf][r]);
            }
        }
    }
    __syncthreads();                        // (P1) rpk reads done -> Pl free for P

    // ---- QK^T over the full 128-wide window (8 col-frags) ----
    f32x4 s_[8] = {};
    #pragma unroll
    for (int nf = 0; nf < 8; ++nf) {
        bf16x8 b0 = *(const bf16x8*)(Kl + SWU(nf * 16 + fr, fq));
        bf16x8 b1 = *(const bf16x8*)(Kl + SWU(nf * 16 + fr, 4 + fq));
        s_[nf] = __builtin_amdgcn_mfma_f32_16x16x32_bf16(aq0, b0, s_[nf], 0, 0, 0);
        s_[nf] = __builtin_amdgcn_mfma_f32_16x16x32_bf16(aq1, b1, s_[nf], 0, 0, 0);
    }

    // ---- single-pass softmax (log2 domain, global max) ----
    float li[4];
    #pragma unroll
    for (int r = 0; r < 4; ++r) {
        const int lq = wq0 + fq * 4 + r;
        const int qg = q0 + lq;
        const float iv = inv2s[lq];
        float sc[8];
        float mx = NEGINF;
        #pragma unroll
        for (int nf = 0; nf < 8; ++nf) {
            const int kg = w0 + nf * 16 + fr;
            float v;
            if (kg >= L) v = NEGINF;
            else {
                int rd = min(max(kg - qg, -MAXR), MAXR) + MAXR;
                float qr = b2f(qdrl[lq * 36 + rd]);
                float fd = (float)(qg - kg);
                v = (s_[nf][r] + qr) * C1F - fd * fd * iv;
            }
            sc[nf] = v;
            mx = fmaxf(mx, v);
        }
        mx = fmaxf(mx, __shfl_xor(mx, 1, 64));
        mx = fmaxf(mx, __shfl_xor(mx, 2, 64));
        mx = fmaxf(mx, __shfl_xor(mx, 4, 64));
        mx = fmaxf(mx, __shfl_xor(mx, 8, 64));
        float rsum = 0.f, ls = 0.f, rs = 0.f;
        #pragma unroll
        for (int nf = 0; nf < 8; ++nf) {
            const int kg = w0 + nf * 16 + fr;
            float pv = exp2_fast(sc[nf] - mx);
            s_[nf][r] = pv;                 // reuse s_ as P storage
            rsum += pv;
            int d = kg - qg;
            if (d <= -MAXR) ls += pv;
            else if (d >= MAXR) rs += pv;
            else {
                int bkt = d + MAXR;         // 1..31, single writer per (row,bucket)
                wA16[(lq * 8 + ((bkt >> 3) ^ (lq & 7))) * 8 + (bkt & 7)] = f2b(pv);
            }
        }
        rsum += __shfl_xor(rsum, 1, 64); rsum += __shfl_xor(rsum, 2, 64);
        rsum += __shfl_xor(rsum, 4, 64); rsum += __shfl_xor(rsum, 8, 64);
        ls += __shfl_xor(ls, 1, 64); ls += __shfl_xor(ls, 2, 64);
        ls += __shfl_xor(ls, 4, 64); ls += __shfl_xor(ls, 8, 64);
        rs += __shfl_xor(rs, 1, 64); rs += __shfl_xor(rs, 2, 64);
        rs += __shfl_xor(rs, 4, 64); rs += __shfl_xor(rs, 8, 64);
        li[r] = rsum;
        if (fr == 0) {
            wA16[(lq * 8 + (0 ^ (lq & 7))) * 8 + 0] = f2b(ls);   // bucket 0
            wA16[(lq * 8 + (4 ^ (lq & 7))) * 8 + 0] = f2b(rs);   // bucket 32
        }
    }

    // ---- P -> bf16 LDS [64][16ch] swz (intra-wave only; no barrier) ----
    #pragma unroll
    for (int r = 0; r < 4; ++r) {
        int lq = wq0 + fq * 4 + r;
        #pragma unroll
        for (int nf = 0; nf < 8; ++nf) {
            int k = nf * 16 + fr;
            int cc = k >> 3;
            Pl[(lq * 16 + (cc ^ (lq & 7))) * 8 + (k & 7)] = f2b(s_[nf][r]);
        }
    }

    // ---- PV: O[q][d] = P[q][0..127] @ V^T, 4 d-frags x 4 k-slices ----
    f32x4 O[4] = {};
    #pragma unroll
    for (int ks = 0; ks < 4; ++ks) {
        bf16x8 ap = *(const bf16x8*)(Pl + ((wq0 + fr) * 16 + ((ks * 4 + fq) ^ (fr & 7))) * 8);
        #pragma unroll
        for (int nf = 0; nf < 4; ++nf) {
            bf16x8 vf = *(const bf16x8*)(Vl + ((nf * 16 + fr) * 16 + ((ks * 4 + fq) ^ (fr & 7))) * 8);
            O[nf] = __builtin_amdgcn_mfma_f32_16x16x32_bf16(ap, vf, O[nf], 0, 0, 0);
        }
    }
    __syncthreads();   // (E1) all PV reads of Vl done -> Vl free for rvT

    // ---- build rvT[d][rd] bf16 swz in Vl directly from global rpe ----
    #pragma unroll
    for (int p = 0; p < 2; ++p) {
        int s = tid + p * 256;
        int d = s >> 3, cs = s & 7;
        u16x8 vv;
        #pragma unroll
        for (int j = 0; j < 8; ++j) {
            int rd = cs * 8 + j;
            vv[j] = (rd < 33) ? f2b(rpe[rd * 128 + 64 + d]) : (u16)0;
        }
        *(u16x8*)(Vl + SWU(d, cs)) = vv;
    }
    __syncthreads();   // (E2) rvT visible

    // ---- epilogue MFMA: O += wA @ rvT^T ----
    {
        bf16x8 aw0 = *(const bf16x8*)(wA16 + SWU(wq0 + fr, fq));
        bf16x8 aw1 = *(const bf16x8*)(wA16 + SWU(wq0 + fr, 4 + fq));
        #pragma unroll
        for (int nf = 0; nf < 4; ++nf) {
            bf16x8 b0 = *(const bf16x8*)(Vl + SWU(nf * 16 + fr, fq));
            bf16x8 b1 = *(const bf16x8*)(Vl + SWU(nf * 16 + fr, 4 + fq));
            O[nf] = __builtin_amdgcn_mfma_f32_16x16x32_bf16(aw0, b0, O[nf], 0, 0, 0);
            O[nf] = __builtin_amdgcn_mfma_f32_16x16x32_bf16(aw1, b1, O[nf], 0, 0, 0);
        }
    }
    float invl[4];
    #pragma unroll
    for (int r = 0; r < 4; ++r) invl[r] = 1.f / li[r];
    #pragma unroll
    for (int r = 0; r < 4; ++r) {
        int lq = wq0 + fq * 4 + r;
        #pragma unroll
        for (int nf = 0; nf < 4; ++nf)
            Pl[lq * 64 + nf * 16 + fr] = f2b(O[nf][r] * invl[r]);   // linear bounce
    }
    __syncthreads();   // (E3)
    #pragma unroll
    for (int j = 0; j < 2; ++j) {
        int s = w * 128 + j * 64 + lane;
        int rr = s >> 3, c8 = s & 7;
        u16x8 vv = *(const u16x8*)(Pl + rr * 64 + c8 * 8);
        *(u16x8*)&cxh[((size_t)(b*NT + q0 + rr)) * 512 + h * NHD + c8 * 8] = vv;
    }
}

// ---------------------------------------------------------------------------
extern "C" void kernel_launch(void* const* d_in, const int* in_sizes, int n_in,
                              void* d_out, int out_size, void* d_ws, size_t ws_size,
                              hipStream_t stream) {
    const float* key   = (const float*)d_in[0];
    const float* value = (const float*)d_in[1];
    const float* query = (const float*)d_in[2];
    const int*   mask  = (const int*)d_in[3];
    const float* Wq  = (const float*)d_in[4];
    const float* bq  = (const float*)d_in[5];
    const float* Wk  = (const float*)d_in[6];
    const float* bk  = (const float*)d_in[7];
    const float* Wv  = (const float*)d_in[8];
    const float* bv  = (const float*)d_in[9];
    const float* Wcq = (const float*)d_in[10];
    const float* Wck = (const float*)d_in[11];
    const float* Wcv = (const float*)d_in[12];
    const float* Wgq = (const float*)d_in[13];
    const float* bgq = (const float*)d_in[14];
    const float* Wgk = (const float*)d_in[15];
    const float* bgk = (const float*)d_in[16];
    const float* Wgv = (const float*)d_in[17];
    const float* bgv = (const float*)d_in[18];
    const float* WmD = (const float*)d_in[19];
    const float* bmD = (const float*)d_in[20];
    const float* rpe = (const float*)d_in[21];
    const float* Wo  = (const float*)d_in[22];
    const float* bo  = (const float*)d_in[23];
    float* out = (float*)d_out;

    const size_t NTOK = (size_t)NB * NT;            // 8192
    const size_t NE   = NTOK * NSZ;                 // 4,194,304
    const size_t NW   = (size_t)NSZ * NSZ;          // 262,144

    u16* ws16 = (u16*)d_ws;
    u16* pkv  = ws16;                // (8192, 1536) q|k|v
    u16* wcat = pkv + NTOK * 1536;   // 3 x (512,512)
    u16* woh  = wcat + 3 * NW;
    u16* vpT  = woh + NW;            // (16*8*64, 512)
    u16* cxh  = vpT + NE;            // (8192, 512)
    float* mDb = (float*)(cxh + NE);
    float* WcT = mDb + NTOK;         // 3 x (5,512) fp32

    cvt4_bf16<<<dim3((unsigned)(NW/8/256), 4), 256, 0, stream>>>(
        Wq, Wk, Wv, Wo, wcat, wcat + NW, wcat + 2*NW, woh, (int)NW);
    wprep<<<dim3(10, 3), 256, 0, stream>>>(Wcq, Wck, Wcv, WcT);

    gemm_qkv<<<dim3(128, 4, 3), 256, 0, stream>>>(
        query, key, value, wcat, bq, bk, bv, pkv);

    conv_gate_all<<<(int)(NTOK / 4), 256, 0, stream>>>(
        key, pkv, WcT, Wgq, bgq, Wgk, bgk, Wgv, bgv, WmD, bmD, mDb);

    vtrans<<<dim3(8, 8, 16), 256, 0, stream>>>(pkv, vpT);

    attn_mfma<<<dim3(128, 8), 256, 0, stream>>>(pkv, vpT, mDb, mask, rpe, cxh);

    gemm_out<<<dim3(128, 4), 256, 0, stream>>>(cxh, woh, bo, out, (int)NTOK, NSZ, NSZ);
}

// Round 15
// 114.785 us; speedup vs baseline: 1.9452x; 1.0072x over previous
//
#include <hip/hip_runtime.h>
#include <math.h>

#define NB 16
#define NT 512
#define NSZ 512
#define NH 8
#define NHD 64
#define MAXR 16

#define C_D0 6.3f
#define C_STD 1.4f
#define C_GAMMA 2.0f

#define NEGINF (-1e30f)
#define LOG2E 1.4426950408889634f
#define C1F   0.18033688011112042f   // 0.125 * log2(e)

typedef unsigned short u16;
typedef __attribute__((ext_vector_type(8))) short bf16x8;
typedef __attribute__((ext_vector_type(4))) float f32x4;
typedef __attribute__((ext_vector_type(8))) unsigned short u16x8;

__device__ __forceinline__ u16 f2b(float f) {
    union { float f; unsigned int u; } c; c.f = f;
    unsigned int u = c.u + 0x7FFFu + ((c.u >> 16) & 1u);
    return (u16)(u >> 16);
}
__device__ __forceinline__ float b2f(u16 h) {
    union { unsigned int u; float f; } c; c.u = ((unsigned int)h) << 16;
    return c.f;
}

#if __has_builtin(__builtin_amdgcn_exp2f)
__device__ __forceinline__ float exp2_fast(float x) { return __builtin_amdgcn_exp2f(x); }
#else
__device__ __forceinline__ float exp2_fast(float x) { return exp2f(x); }
#endif

#define GL2LDS(gp, lp) __builtin_amdgcn_global_load_lds( \
    (const __attribute__((address_space(1))) void*)(gp), \
    (__attribute__((address_space(3))) void*)(lp), 16, 0, 0)

// swizzled u16-index of 16B chunk c in row r (8-chunk rows = 64 bf16)
#define SWU(r, c) ((((r) * 8) + ((c) ^ ((r) & 7))) * 8)
// swizzled u16-index for 16-chunk rows (128 bf16 per row)
#define SWU16(r, c) ((((r) * 16) + ((c) ^ ((r) & 7))) * 8)

// ---------------------------------------------------------------------------
// fp32 -> bf16 convert (weights only)
// ---------------------------------------------------------------------------
__global__ __launch_bounds__(256) void cvt4_bf16(
    const float* __restrict__ s0, const float* __restrict__ s1,
    const float* __restrict__ s2, const float* __restrict__ s3,
    u16* __restrict__ d0, u16* __restrict__ d1,
    u16* __restrict__ d2, u16* __restrict__ d3, int n)
{
    const float* s; u16* d;
    switch (blockIdx.y) {
        case 0: s = s0; d = d0; break;
        case 1: s = s1; d = d1; break;
        case 2: s = s2; d = d2; break;
        default: s = s3; d = d3; break;
    }
    int i = (blockIdx.x * 256 + threadIdx.x) * 8;
    if (i >= n) return;
    float4 a = *(const float4*)&s[i];
    float4 b = *(const float4*)&s[i + 4];
    u16x8 v;
    v[0]=f2b(a.x); v[1]=f2b(a.y); v[2]=f2b(a.z); v[3]=f2b(a.w);
    v[4]=f2b(b.x); v[5]=f2b(b.y); v[6]=f2b(b.z); v[7]=f2b(b.w);
    *(u16x8*)&d[i] = v;
}

// ---------------------------------------------------------------------------
// Conv-weight transpose: Wc_z[512][5] -> WcT[z][5][512]  (fp32, one-time)
// ---------------------------------------------------------------------------
__global__ __launch_bounds__(256) void wprep(
    const float* __restrict__ Wcq, const float* __restrict__ Wck,
    const float* __restrict__ Wcv, float* __restrict__ WcT)
{
    const int z = blockIdx.y;
    const float* src = z == 0 ? Wcq : (z == 1 ? Wck : Wcv);
    int idx = blockIdx.x * 256 + threadIdx.x;
    if (idx >= 2560) return;
    int c = idx / 5, j = idx % 5;
    WcT[(size_t)z * 2560 + j * 512 + c] = src[idx];
}

// ---------------------------------------------------------------------------
// QKV projections, z-batched, 64x128 tile.
// R15: T3-minimal 2-phase pipeline — double-buffered LDS (24 KB), ONE barrier
// per K-step; next-step A-reg loads + W GL2LDS issued BEFORE current MFMA.
// ---------------------------------------------------------------------------
__global__ __launch_bounds__(256) void gemm_qkv(
    const float* __restrict__ A0, const float* __restrict__ A1, const float* __restrict__ A2,
    const u16* __restrict__ Wc,
    const float* __restrict__ bq, const float* __restrict__ bk, const float* __restrict__ bv,
    u16* __restrict__ pkv)
{
    __shared__ u16 Al[2][64 * 32];
    __shared__ u16 Bl[2][128 * 32];
    const int z = blockIdx.z;
    const float* A = z == 0 ? A0 : (z == 1 ? A1 : A2);
    const u16* W = Wc + (size_t)z * NSZ * NSZ;
    const float* bias = z == 0 ? bq : (z == 1 ? bk : bv);
    const int tid = threadIdx.x;
    const int m0 = blockIdx.x * 64;
    const int n0 = blockIdx.y * 128;
    const int w = tid >> 6, lane = tid & 63;
    const int wm = (w >> 1) * 32, wn = (w & 1) * 64;
    const int fr = lane & 15, fk = lane >> 4;

    const int arow = tid >> 2, acb = tid & 3;          // A: 256 chunks
    const int wrow0 = tid >> 2, wcb = tid & 3;         // W: 512 chunks (2 waves' worth)

    f32x4 acc[2][4] = {};

    // ---- prologue: stage t=0 into buf 0 ----
    {
        const float* ga = &A[(size_t)(m0 + arow) * NSZ + acb * 8];
        float4 a0 = *(const float4*)ga, a1 = *(const float4*)(ga + 4);
        #pragma unroll
        for (int p = 0; p < 2; ++p) {
            int s = tid + p * 256;
            int row = s >> 2, cb = s & 3;
            GL2LDS(&W[(size_t)(n0 + row) * NSZ + cb * 8], &Bl[0][s * 8]);
        }
        u16x8 v;
        v[0]=f2b(a0.x); v[1]=f2b(a0.y); v[2]=f2b(a0.z); v[3]=f2b(a0.w);
        v[4]=f2b(a1.x); v[5]=f2b(a1.y); v[6]=f2b(a1.z); v[7]=f2b(a1.w);
        *(u16x8*)&Al[0][tid * 8] = v;
    }
    __syncthreads();

    for (int t = 0; t < 16; ++t) {
        const int cur = t & 1, nxt = cur ^ 1;
        float4 a0n, a1n;
        const bool pre = (t < 15);
        if (pre) {
            const int k0 = (t + 1) * 32;
            const float* ga = &A[(size_t)(m0 + arow) * NSZ + k0 + acb * 8];
            a0n = *(const float4*)ga;
            a1n = *(const float4*)(ga + 4);
            #pragma unroll
            for (int p = 0; p < 2; ++p) {
                int s = tid + p * 256;
                int row = s >> 2, cb = s & 3;
                GL2LDS(&W[(size_t)(n0 + row) * NSZ + k0 + cb * 8], &Bl[nxt][s * 8]);
            }
        }
        // ---- compute on buf[cur] ----
        bf16x8 af[2], bfr[4];
        #pragma unroll
        for (int mf = 0; mf < 2; ++mf)
            af[mf] = *(const bf16x8*)&Al[cur][(wm + mf * 16 + fr) * 32 + fk * 8];
        #pragma unroll
        for (int nf = 0; nf < 4; ++nf)
            bfr[nf] = *(const bf16x8*)&Bl[cur][(wn + nf * 16 + fr) * 32 + fk * 8];
        #pragma unroll
        for (int mf = 0; mf < 2; ++mf)
            #pragma unroll
            for (int nf = 0; nf < 4; ++nf)
                acc[mf][nf] = __builtin_amdgcn_mfma_f32_16x16x32_bf16(
                    af[mf], bfr[nf], acc[mf][nf], 0, 0, 0);
        // ---- A(t+1) convert + ds_write after compute (load wait lands here) ----
        if (pre) {
            u16x8 v;
            v[0]=f2b(a0n.x); v[1]=f2b(a0n.y); v[2]=f2b(a0n.z); v[3]=f2b(a0n.w);
            v[4]=f2b(a1n.x); v[5]=f2b(a1n.y); v[6]=f2b(a1n.z); v[7]=f2b(a1n.w);
            *(u16x8*)&Al[nxt][tid * 8] = v;
        }
        __syncthreads();   // single barrier: buf[nxt] published, buf[cur] free
    }
    #pragma unroll
    for (int mf = 0; mf < 2; ++mf) {
        #pragma unroll
        for (int nf = 0; nf < 4; ++nf) {
            int col = n0 + wn + nf * 16 + fr;
            float bvv = bias[col];
            #pragma unroll
            for (int r = 0; r < 4; ++r) {
                int rowg = m0 + wm + mf * 16 + fk * 4 + r;
                pkv[(size_t)rowg * 1536 + z * 512 + col] = f2b(acc[mf][nf][r] + bvv);
            }
        }
    }
}

// ---------------------------------------------------------------------------
// Output projection (fp32 out). 64x128 tile, 2-phase pipeline (both via GL2LDS).
// ---------------------------------------------------------------------------
__global__ __launch_bounds__(256) void gemm_out(
    const u16* __restrict__ A, const u16* __restrict__ W,
    const float* __restrict__ bias, float* __restrict__ Cout, int M, int N, int K)
{
    __shared__ u16 Al[2][64 * 32];
    __shared__ u16 Bl[2][128 * 32];
    const int tid = threadIdx.x;
    const int m0 = blockIdx.x * 64;
    const int n0 = blockIdx.y * 128;
    const int w = tid >> 6, lane = tid & 63;
    const int wm = (w >> 1) * 32, wn = (w & 1) * 64;
    const int fr = lane & 15, fk = lane >> 4;

    f32x4 acc[2][4] = {};

    // prologue: stage t=0
    {
        int row = tid >> 2, cb = tid & 3;
        GL2LDS(&A[(size_t)(m0 + row) * K + cb * 8], &Al[0][tid * 8]);
        #pragma unroll
        for (int p = 0; p < 2; ++p) {
            int s = tid + p * 256;
            int r2 = s >> 2, c2 = s & 3;
            GL2LDS(&W[(size_t)(n0 + r2) * K + c2 * 8], &Bl[0][s * 8]);
        }
    }
    __syncthreads();

    const int nsteps = K / 32;
    for (int t = 0; t < nsteps; ++t) {
        const int cur = t & 1, nxt = cur ^ 1;
        if (t + 1 < nsteps) {
            const int k0 = (t + 1) * 32;
            int row = tid >> 2, cb = tid & 3;
            GL2LDS(&A[(size_t)(m0 + row) * K + k0 + cb * 8], &Al[nxt][tid * 8]);
            #pragma unroll
            for (int p = 0; p < 2; ++p) {
                int s = tid + p * 256;
                int r2 = s >> 2, c2 = s & 3;
                GL2LDS(&W[(size_t)(n0 + r2) * K + k0 + c2 * 8], &Bl[nxt][s * 8]);
            }
        }
        bf16x8 af[2], bfr[4];
        #pragma unroll
        for (int mf = 0; mf < 2; ++mf)
            af[mf] = *(const bf16x8*)&Al[cur][(wm + mf * 16 + fr) * 32 + fk * 8];
        #pragma unroll
        for (int nf = 0; nf < 4; ++nf)
            bfr[nf] = *(const bf16x8*)&Bl[cur][(wn + nf * 16 + fr) * 32 + fk * 8];
        #pragma unroll
        for (int mf = 0; mf < 2; ++mf)
            #pragma unroll
            for (int nf = 0; nf < 4; ++nf)
                acc[mf][nf] = __builtin_amdgcn_mfma_f32_16x16x32_bf16(
                    af[mf], bfr[nf], acc[mf][nf], 0, 0, 0);
        __syncthreads();
    }
    #pragma unroll
    for (int mf = 0; mf < 2; ++mf) {
        #pragma unroll
        for (int nf = 0; nf < 4; ++nf) {
            int col = n0 + wn + nf * 16 + fr;
            float bv = bias[col];
            #pragma unroll
            for (int r = 0; r < 4; ++r) {
                int rowg = m0 + wm + mf * 16 + fk * 4 + r;
                Cout[(size_t)rowg * N + col] = acc[mf][nf][r] + bv;
            }
        }
    }
}

// ---------------------------------------------------------------------------
// Fused 3x depthwise conv1d(k=5) + 3 scalar gates + mD (R13 proven version).
// ---------------------------------------------------------------------------
__global__ void conv_gate_all(
    const float* __restrict__ xn, u16* __restrict__ pkv,
    const float* __restrict__ WcT,
    const float* __restrict__ Wgq, const float* __restrict__ bgq,
    const float* __restrict__ Wgk, const float* __restrict__ bgk,
    const float* __restrict__ Wgv, const float* __restrict__ bgv,
    const float* __restrict__ WmD, const float* __restrict__ bmD,
    float* __restrict__ mD)
{
    const int w = threadIdx.x >> 6, lane = threadIdx.x & 63;
    const int bt = blockIdx.x * 4 + w;
    const int b = bt >> 9, tpos = bt & (NT - 1);
    const int c0 = lane * 8;

    float x[5][8];
    #pragma unroll
    for (int j = 0; j < 5; ++j) {
        int tt = tpos + j - 2;
        if (tt >= 0 && tt < NT) {
            const float4* xp = (const float4*)&xn[((size_t)(b*NT + tt))*NSZ + c0];
            float4 u0 = xp[0], u1 = xp[1];
            x[j][0]=u0.x; x[j][1]=u0.y; x[j][2]=u0.z; x[j][3]=u0.w;
            x[j][4]=u1.x; x[j][5]=u1.y; x[j][6]=u1.z; x[j][7]=u1.w;
        } else {
            #pragma unroll
            for (int i = 0; i < 8; ++i) x[j][i] = 0.f;
        }
    }
    float aq[8] = {}, ak[8] = {}, av[8] = {};
    #pragma unroll
    for (int j = 0; j < 5; ++j) {
        const float* wq = &WcT[j * 512 + c0];
        const float* wk = &WcT[2560 + j * 512 + c0];
        const float* wv = &WcT[5120 + j * 512 + c0];
        float4 q0 = *(const float4*)wq, q1 = *(const float4*)(wq + 4);
        float4 k0 = *(const float4*)wk, k1 = *(const float4*)(wk + 4);
        float4 v0 = *(const float4*)wv, v1 = *(const float4*)(wv + 4);
        float wq8[8] = {q0.x,q0.y,q0.z,q0.w,q1.x,q1.y,q1.z,q1.w};
        float wk8[8] = {k0.x,k0.y,k0.z,k0.w,k1.x,k1.y,k1.z,k1.w};
        float wv8[8] = {v0.x,v0.y,v0.z,v0.w,v1.x,v1.y,v1.z,v1.w};
        #pragma unroll
        for (int i = 0; i < 8; ++i) {
            aq[i] += x[j][i] * wq8[i];
            ak[i] += x[j][i] * wk8[i];
            av[i] += x[j][i] * wv8[i];
        }
    }
    const size_t rb = (size_t)bt * 1536;
    u16x8 q8 = *(const u16x8*)&pkv[rb + c0];
    u16x8 k8 = *(const u16x8*)&pkv[rb + 512 + c0];
    u16x8 v8 = *(const u16x8*)&pkv[rb + 1024 + c0];

    float gql[8], gqh[8], gkl[8], gkh[8], gvl[8], gvh[8];
    {
        float4 a0 = *(const float4*)&Wgq[c0],      a1 = *(const float4*)&Wgq[c0 + 4];
        float4 a2 = *(const float4*)&Wgq[512 + c0], a3 = *(const float4*)&Wgq[512 + c0 + 4];
        gql[0]=a0.x;gql[1]=a0.y;gql[2]=a0.z;gql[3]=a0.w;gql[4]=a1.x;gql[5]=a1.y;gql[6]=a1.z;gql[7]=a1.w;
        gqh[0]=a2.x;gqh[1]=a2.y;gqh[2]=a2.z;gqh[3]=a2.w;gqh[4]=a3.x;gqh[5]=a3.y;gqh[6]=a3.z;gqh[7]=a3.w;
        float4 b0 = *(const float4*)&Wgk[c0],      b1 = *(const float4*)&Wgk[c0 + 4];
        float4 b2 = *(const float4*)&Wgk[512 + c0], b3 = *(const float4*)&Wgk[512 + c0 + 4];
        gkl[0]=b0.x;gkl[1]=b0.y;gkl[2]=b0.z;gkl[3]=b0.w;gkl[4]=b1.x;gkl[5]=b1.y;gkl[6]=b1.z;gkl[7]=b1.w;
        gkh[0]=b2.x;gkh[1]=b2.y;gkh[2]=b2.z;gkh[3]=b2.w;gkh[4]=b3.x;gkh[5]=b3.y;gkh[6]=b3.z;gkh[7]=b3.w;
        float4 c0v = *(const float4*)&Wgv[c0],      c1v = *(const float4*)&Wgv[c0 + 4];
        float4 c2v = *(const float4*)&Wgv[512 + c0], c3v = *(const float4*)&Wgv[512 + c0 + 4];
        gvl[0]=c0v.x;gvl[1]=c0v.y;gvl[2]=c0v.z;gvl[3]=c0v.w;gvl[4]=c1v.x;gvl[5]=c1v.y;gvl[6]=c1v.z;gvl[7]=c1v.w;
        gvh[0]=c2v.x;gvh[1]=c2v.y;gvh[2]=c2v.z;gvh[3]=c2v.w;gvh[4]=c3v.x;gvh[5]=c3v.y;gvh[6]=c3v.z;gvh[7]=c3v.w;
    }
    float sq = 0.f, sk = 0.f, sv = 0.f;
    #pragma unroll
    for (int i = 0; i < 8; ++i) {
        sq += b2f(q8[i]) * gql[i] + aq[i] * gqh[i];
        sk += b2f(k8[i]) * gkl[i] + ak[i] * gkh[i];
        sv += b2f(v8[i]) * gvl[i] + av[i] * gvh[i];
    }
    #pragma unroll
    for (int o = 1; o < 64; o <<= 1) {
        sq += __shfl_xor(sq, o, 64);
        sk += __shfl_xor(sk, o, 64);
        sv += __shfl_xor(sv, o, 64);
    }
    float gq = 1.f / (1.f + expf(-(sq + bgq[0])));
    float gk = 1.f / (1.f + expf(-(sk + bgk[0])));
    float gv = 1.f / (1.f + expf(-(sv + bgv[0])));

    float wm8[8];
    {
        float4 m0 = *(const float4*)&WmD[c0], m1 = *(const float4*)&WmD[c0 + 4];
        wm8[0]=m0.x;wm8[1]=m0.y;wm8[2]=m0.z;wm8[3]=m0.w;wm8[4]=m1.x;wm8[5]=m1.y;wm8[6]=m1.z;wm8[7]=m1.w;
    }
    u16x8 oq8, ok8, ov8;
    float smd = 0.f;
    #pragma unroll
    for (int i = 0; i < 8; ++i) {
        float oq = (1.f - gq) * b2f(q8[i]) + gq * aq[i];
        oq8[i] = f2b(oq);
        ok8[i] = f2b((1.f - gk) * b2f(k8[i]) + gk * ak[i]);
        ov8[i] = f2b((1.f - gv) * b2f(v8[i]) + gv * av[i]);
        smd += oq * wm8[i];
    }
    *(u16x8*)&pkv[rb + c0]        = oq8;
    *(u16x8*)&pkv[rb + 512 + c0]  = ok8;
    *(u16x8*)&pkv[rb + 1024 + c0] = ov8;
    #pragma unroll
    for (int o = 1; o < 64; o <<= 1) smd += __shfl_xor(smd, o, 64);
    if (lane == 0)
        mD[bt] = C_D0 + 2.f * C_STD * tanhf((smd + bmD[0]) / C_GAMMA);
}

// ---------------------------------------------------------------------------
// V transpose: pkv v-section (b,t,h*64+d) -> vpT[(b*8+h)*64+d][t]
// ---------------------------------------------------------------------------
__global__ __launch_bounds__(256) void vtrans(
    const u16* __restrict__ pkv, u16* __restrict__ vpT)
{
    __shared__ u16 lt[64][72];
    const int t0 = blockIdx.x * 64;
    const int h = blockIdx.y, b = blockIdx.z;
    const int tid = threadIdx.x;
    #pragma unroll
    for (int p = 0; p < 2; ++p) {
        int s = tid + p * 256;
        int t = s >> 3, c8 = s & 7;
        u16x8 v = *(const u16x8*)&pkv[((size_t)(b*NT + t0 + t))*1536 + 1024 + h*NHD + c8*8];
        *(u16x8*)&lt[t][c8 * 8] = v;
    }
    __syncthreads();
    #pragma unroll
    for (int p = 0; p < 2; ++p) {
        int s = tid + p * 256;
        int d = s >> 3, c8 = s & 7;
        u16x8 o;
        #pragma unroll
        for (int j = 0; j < 8; ++j) o[j] = lt[c8 * 8 + j][d];
        *(u16x8*)&vpT[((size_t)((b*NH + h)*NHD + d))*NT + t0 + c8*8] = o;
    }
}

// ---------------------------------------------------------------------------
// MFMA flash attention — R14 single-pass version (unchanged).
// ---------------------------------------------------------------------------
__global__ __launch_bounds__(256) void attn_mfma(
    const u16* __restrict__ pkv, const u16* __restrict__ vpT,
    const float* __restrict__ mD, const int* __restrict__ mask,
    const float* __restrict__ rpe, u16* __restrict__ cxh)
{
    __shared__ __align__(16) char smem[70400];
    u16*  Ql    = (u16*)(smem);              // [64][8ch] swz (8 KB)
    u16*  Kl    = (u16*)(smem + 8192);       // [128][8ch] swz (16 KB)
    u16*  Vl    = (u16*)(smem + 24576);      // [64][16ch] swz (16 KB); epi: rvT
    u16*  Pl    = (u16*)(smem + 40960);      // rpk / P / out-bounce
    u16*  rpk   = (u16*)(smem + 40960);
    u16*  wA16  = (u16*)(smem + 57344);      // [64][8ch] swz bf16 buckets (8 KB)
    u16*  qdrl  = (u16*)(smem + 65536);      // [64][36] bf16
    float* inv2s= (float*)(smem + 70144);    // [64]

    const int tid  = threadIdx.x;
    const int lane = tid & 63;
    const int w    = tid >> 6;
    const int wq0  = w * 16;
    const int fr   = lane & 15;
    const int fq   = lane >> 4;
    const int b    = blockIdx.x >> 3;
    const int h    = blockIdx.x & 7;
    const int q0   = blockIdx.y * 64;

    const size_t qbase  = ((size_t)(b*NT + q0)) * 1536 + h * NHD;
    const size_t kbaseg = ((size_t)b * NT) * 1536 + 512 + h * NHD;
    const size_t vbaseg = ((size_t)((b*NH + h) * NHD)) * NT;

    int Lm = 512;
    #pragma unroll
    for (int j = 0; j < 8; ++j) {
        if (mask[b * NT + lane + 64 * j]) Lm = min(Lm, lane + 64 * j);
    }
    #pragma unroll
    for (int o = 1; o < 64; o <<= 1) Lm = min(Lm, __shfl_xor(Lm, o, 64));
    const int L = Lm;
    const int w0 = max(0, min(q0 - 32, L - 128));

    #pragma unroll
    for (int p = 0; p < 2; ++p) {
        int s = tid + p * 256;
        int r = s >> 3, c = s & 7;
        u16x8 v = *(const u16x8*)(pkv + qbase + (size_t)r * 1536 + c * 8);
        *(u16x8*)(Ql + SWU(r, c)) = v;
    }
    #pragma unroll
    for (int p = 0; p < 4; ++p) {
        int s = tid + p * 256;
        int r = s >> 3, c = s & 7;
        u16x8 v = *(const u16x8*)(pkv + kbaseg + (size_t)(w0 + r) * 1536 + c * 8);
        *(u16x8*)(Kl + SWU(r, c)) = v;
    }
    #pragma unroll
    for (int p = 0; p < 4; ++p) {
        int s = tid + p * 256;
        int d = s >> 4, cc = s & 15;
        u16x8 v = *(const u16x8*)(vpT + vbaseg + (size_t)d * NT + w0 + cc * 8);
        *(u16x8*)(Vl + SWU16(d, cc)) = v;
    }
    for (int idx = tid; idx < 264; idx += 256) {
        int r = idx >> 3, c = idx & 7;
        float4 f0 = *(const float4*)&rpe[r * 128 + c * 8];
        float4 f1 = *(const float4*)&rpe[r * 128 + c * 8 + 4];
        u16x8 vv;
        vv[0]=f2b(f0.x); vv[1]=f2b(f0.y); vv[2]=f2b(f0.z); vv[3]=f2b(f0.w);
        vv[4]=f2b(f1.x); vv[5]=f2b(f1.y); vv[6]=f2b(f1.z); vv[7]=f2b(f1.w);
        *(u16x8*)(rpk + SWU(r, c)) = vv;
    }
    if (tid < 120) {
        u16x8 vv = {0,0,0,0,0,0,0,0};
        *(u16x8*)(rpk + (((33 + (tid >> 3)) * 8) + (tid & 7)) * 8) = vv;
    }
    {
        u16x8 z = {0,0,0,0,0,0,0,0};
        #pragma unroll
        for (int p = 0; p < 2; ++p) *(u16x8*)(wA16 + (tid + p * 256) * 8) = z;
    }
    if (tid < 64) {
        float md = mD[b * NT + q0 + tid];
        inv2s[tid] = 2.f * LOG2E / (md * md);
    }
    __syncthreads();                        // (P0)

    bf16x8 aq0 = *(const bf16x8*)(Ql + SWU(wq0 + fr, fq));
    bf16x8 aq1 = *(const bf16x8*)(Ql + SWU(wq0 + fr, 4 + fq));

    {
        f32x4 qd[3] = {};
        #pragma unroll
        for (int nf = 0; nf < 3; ++nf) {
            bf16x8 b0 = *(const bf16x8*)(rpk + SWU(nf * 16 + fr, fq));
            bf16x8 b1 = *(const bf16x8*)(rpk + SWU(nf * 16 + fr, 4 + fq));
            qd[nf] = __builtin_amdgcn_mfma_f32_16x16x32_bf16(aq0, b0, qd[nf], 0, 0, 0);
            qd[nf] = __builtin_amdgcn_mfma_f32_16x16x32_bf16(aq1, b1, qd[nf], 0, 0, 0);
        }
        #pragma unroll
        for (int nf = 0; nf < 3; ++nf) {
            int rd = nf * 16 + fr;
            if (rd < 33) {
                #pragma unroll
                for (int r = 0; r < 4; ++r)
                    qdrl[(wq0 + fq * 4 + r) * 36 + rd] = f2b(qd[nf][r]);
            }
        }
    }
    __syncthreads();                        // (P1)

    f32x4 s_[8] = {};
    #pragma unroll
    for (int nf = 0; nf < 8; ++nf) {
        bf16x8 b0 = *(const bf16x8*)(Kl + SWU(nf * 16 + fr, fq));
        bf16x8 b1 = *(const bf16x8*)(Kl + SWU(nf * 16 + fr, 4 + fq));
        s_[nf] = __builtin_amdgcn_mfma_f32_16x16x32_bf16(aq0, b0, s_[nf], 0, 0, 0);
        s_[nf] = __builtin_amdgcn_mfma_f32_16x16x32_bf16(aq1, b1, s_[nf], 0, 0, 0);
    }

    float li[4];
    #pragma unroll
    for (int r = 0; r < 4; ++r) {
        const int lq = wq0 + fq * 4 + r;
        const int qg = q0 + lq;
        const float iv = inv2s[lq];
        float sc[8];
        float mx = NEGINF;
        #pragma unroll
        for (int nf = 0; nf < 8; ++nf) {
            const int kg = w0 + nf * 16 + fr;
            float v;
            if (kg >= L) v = NEGINF;
            else {
                int rd = min(max(kg - qg, -MAXR), MAXR) + MAXR;
                float qr = b2f(qdrl[lq * 36 + rd]);
                float fd = (float)(qg - kg);
                v = (s_[nf][r] + qr) * C1F - fd * fd * iv;
            }
            sc[nf] = v;
            mx = fmaxf(mx, v);
        }
        mx = fmaxf(mx, __shfl_xor(mx, 1, 64));
        mx = fmaxf(mx, __shfl_xor(mx, 2, 64));
        mx = fmaxf(mx, __shfl_xor(mx, 4, 64));
        mx = fmaxf(mx, __shfl_xor(mx, 8, 64));
        float rsum = 0.f, ls = 0.f, rs = 0.f;
        #pragma unroll
        for (int nf = 0; nf < 8; ++nf) {
            const int kg = w0 + nf * 16 + fr;
            float pv = exp2_fast(sc[nf] - mx);
            s_[nf][r] = pv;
            rsum += pv;
            int d = kg - qg;
            if (d <= -MAXR) ls += pv;
            else if (d >= MAXR) rs += pv;
            else {
                int bkt = d + MAXR;
                wA16[(lq * 8 + ((bkt >> 3) ^ (lq & 7))) * 8 + (bkt & 7)] = f2b(pv);
            }
        }
        rsum += __shfl_xor(rsum, 1, 64); rsum += __shfl_xor(rsum, 2, 64);
        rsum += __shfl_xor(rsum, 4, 64); rsum += __shfl_xor(rsum, 8, 64);
        ls += __shfl_xor(ls, 1, 64); ls += __shfl_xor(ls, 2, 64);
        ls += __shfl_xor(ls, 4, 64); ls += __shfl_xor(ls, 8, 64);
        rs += __shfl_xor(rs, 1, 64); rs += __shfl_xor(rs, 2, 64);
        rs += __shfl_xor(rs, 4, 64); rs += __shfl_xor(rs, 8, 64);
        li[r] = rsum;
        if (fr == 0) {
            wA16[(lq * 8 + (0 ^ (lq & 7))) * 8 + 0] = f2b(ls);
            wA16[(lq * 8 + (4 ^ (lq & 7))) * 8 + 0] = f2b(rs);
        }
    }

    #pragma unroll
    for (int r = 0; r < 4; ++r) {
        int lq = wq0 + fq * 4 + r;
        #pragma unroll
        for (int nf = 0; nf < 8; ++nf) {
            int k = nf * 16 + fr;
            int cc = k >> 3;
            Pl[(lq * 16 + (cc ^ (lq & 7))) * 8 + (k & 7)] = f2b(s_[nf][r]);
        }
    }

    f32x4 O[4] = {};
    #pragma unroll
    for (int ks = 0; ks < 4; ++ks) {
        bf16x8 ap = *(const bf16x8*)(Pl + ((wq0 + fr) * 16 + ((ks * 4 + fq) ^ (fr & 7))) * 8);
        #pragma unroll
        for (int nf = 0; nf < 4; ++nf) {
            bf16x8 vf = *(const bf16x8*)(Vl + ((nf * 16 + fr) * 16 + ((ks * 4 + fq) ^ (fr & 7))) * 8);
            O[nf] = __builtin_amdgcn_mfma_f32_16x16x32_bf16(ap, vf, O[nf], 0, 0, 0);
        }
    }
    __syncthreads();   // (E1)

    #pragma unroll
    for (int p = 0; p < 2; ++p) {
        int s = tid + p * 256;
        int d = s >> 3, cs = s & 7;
        u16x8 vv;
        #pragma unroll
        for (int j = 0; j < 8; ++j) {
            int rd = cs * 8 + j;
            vv[j] = (rd < 33) ? f2b(rpe[rd * 128 + 64 + d]) : (u16)0;
        }
        *(u16x8*)(Vl + SWU(d, cs)) = vv;
    }
    __syncthreads();   // (E2)

    {
        bf16x8 aw0 = *(const bf16x8*)(wA16 + SWU(wq0 + fr, fq));
        bf16x8 aw1 = *(const bf16x8*)(wA16 + SWU(wq0 + fr, 4 + fq));
        #pragma unroll
        for (int nf = 0; nf < 4; ++nf) {
            bf16x8 b0 = *(const bf16x8*)(Vl + SWU(nf * 16 + fr, fq));
            bf16x8 b1 = *(const bf16x8*)(Vl + SWU(nf * 16 + fr, 4 + fq));
            O[nf] = __builtin_amdgcn_mfma_f32_16x16x32_bf16(aw0, b0, O[nf], 0, 0, 0);
            O[nf] = __builtin_amdgcn_mfma_f32_16x16x32_bf16(aw1, b1, O[nf], 0, 0, 0);
        }
    }
    float invl[4];
    #pragma unroll
    for (int r = 0; r < 4; ++r) invl[r] = 1.f / li[r];
    #pragma unroll
    for (int r = 0; r < 4; ++r) {
        int lq = wq0 + fq * 4 + r;
        #pragma unroll
        for (int nf = 0; nf < 4; ++nf)
            Pl[lq * 64 + nf * 16 + fr] = f2b(O[nf][r] * invl[r]);
    }
    __syncthreads();   // (E3)
    #pragma unroll
    for (int j = 0; j < 2; ++j) {
        int s = w * 128 + j * 64 + lane;
        int rr = s >> 3, c8 = s & 7;
        u16x8 vv = *(const u16x8*)(Pl + rr * 64 + c8 * 8);
        *(u16x8*)&cxh[((size_t)(b*NT + q0 + rr)) * 512 + h * NHD + c8 * 8] = vv;
    }
}

// ---------------------------------------------------------------------------
extern "C" void kernel_launch(void* const* d_in, const int* in_sizes, int n_in,
                              void* d_out, int out_size, void* d_ws, size_t ws_size,
                              hipStream_t stream) {
    const float* key   = (const float*)d_in[0];
    const float* value = (const float*)d_in[1];
    const float* query = (const float*)d_in[2];
    const int*   mask  = (const int*)d_in[3];
    const float* Wq  = (const float*)d_in[4];
    const float* bq  = (const float*)d_in[5];
    const float* Wk  = (const float*)d_in[6];
    const float* bk  = (const float*)d_in[7];
    const float* Wv  = (const float*)d_in[8];
    const float* bv  = (const float*)d_in[9];
    const float* Wcq = (const float*)d_in[10];
    const float* Wck = (const float*)d_in[11];
    const float* Wcv = (const float*)d_in[12];
    const float* Wgq = (const float*)d_in[13];
    const float* bgq = (const float*)d_in[14];
    const float* Wgk = (const float*)d_in[15];
    const float* bgk = (const float*)d_in[16];
    const float* Wgv = (const float*)d_in[17];
    const float* bgv = (const float*)d_in[18];
    const float* WmD = (const float*)d_in[19];
    const float* bmD = (const float*)d_in[20];
    const float* rpe = (const float*)d_in[21];
    const float* Wo  = (const float*)d_in[22];
    const float* bo  = (const float*)d_in[23];
    float* out = (float*)d_out;

    const size_t NTOK = (size_t)NB * NT;            // 8192
    const size_t NE   = NTOK * NSZ;                 // 4,194,304
    const size_t NW   = (size_t)NSZ * NSZ;          // 262,144

    u16* ws16 = (u16*)d_ws;
    u16* pkv  = ws16;                // (8192, 1536) q|k|v
    u16* wcat = pkv + NTOK * 1536;   // 3 x (512,512)
    u16* woh  = wcat + 3 * NW;
    u16* vpT  = woh + NW;            // (16*8*64, 512)
    u16* cxh  = vpT + NE;            // (8192, 512)
    float* mDb = (float*)(cxh + NE);
    float* WcT = mDb + NTOK;         // 3 x (5,512) fp32

    cvt4_bf16<<<dim3((unsigned)(NW/8/256), 4), 256, 0, stream>>>(
        Wq, Wk, Wv, Wo, wcat, wcat + NW, wcat + 2*NW, woh, (int)NW);
    wprep<<<dim3(10, 3), 256, 0, stream>>>(Wcq, Wck, Wcv, WcT);

    gemm_qkv<<<dim3(128, 4, 3), 256, 0, stream>>>(
        query, key, value, wcat, bq, bk, bv, pkv);

    conv_gate_all<<<(int)(NTOK / 4), 256, 0, stream>>>(
        key, pkv, WcT, Wgq, bgq, Wgk, bgk, Wgv, bgv, WmD, bmD, mDb);

    vtrans<<<dim3(8, 8, 16), 256, 0, stream>>>(pkv, vpT);

    attn_mfma<<<dim3(128, 8), 256, 0, stream>>>(pkv, vpT, mDb, mask, rpe, cxh);

    gemm_out<<<dim3(128, 4), 256, 0, stream>>>(cxh, woh, bo, out, (int)NTOK, NSZ, NSZ);
}

// Round 16
// 108.637 us; speedup vs baseline: 2.0553x; 1.0566x over previous
//
#include <hip/hip_runtime.h>
#include <math.h>

#define NB 16
#define NT 512
#define NSZ 512
#define NH 8
#define NHD 64
#define MAXR 16

#define C_D0 6.3f
#define C_STD 1.4f
#define C_GAMMA 2.0f

#define NEGINF (-1e30f)
#define LOG2E 1.4426950408889634f
#define C1F   0.18033688011112042f   // 0.125 * log2(e)

typedef unsigned short u16;
typedef __attribute__((ext_vector_type(8))) short bf16x8;
typedef __attribute__((ext_vector_type(4))) float f32x4;
typedef __attribute__((ext_vector_type(8))) unsigned short u16x8;
typedef __attribute__((ext_vector_type(4))) unsigned short u16x4;

__device__ __forceinline__ u16 f2b(float f) {
    union { float f; unsigned int u; } c; c.f = f;
    unsigned int u = c.u + 0x7FFFu + ((c.u >> 16) & 1u);
    return (u16)(u >> 16);
}
__device__ __forceinline__ float b2f(u16 h) {
    union { unsigned int u; float f; } c; c.u = ((unsigned int)h) << 16;
    return c.f;
}

#if __has_builtin(__builtin_amdgcn_exp2f)
__device__ __forceinline__ float exp2_fast(float x) { return __builtin_amdgcn_exp2f(x); }
#else
__device__ __forceinline__ float exp2_fast(float x) { return exp2f(x); }
#endif

#define GL2LDS(gp, lp) __builtin_amdgcn_global_load_lds( \
    (const __attribute__((address_space(1))) void*)(gp), \
    (__attribute__((address_space(3))) void*)(lp), 16, 0, 0)

// swizzled u16-index of 16B chunk c in row r (8-chunk rows = 64 bf16)
#define SWU(r, c) ((((r) * 8) + ((c) ^ ((r) & 7))) * 8)
// swizzled u16-index for 16-chunk rows (128 bf16 per row)
#define SWU16(r, c) ((((r) * 16) + ((c) ^ ((r) & 7))) * 8)

// ---------------------------------------------------------------------------
// fp32 -> bf16 convert (weights only)
// ---------------------------------------------------------------------------
__global__ __launch_bounds__(256) void cvt4_bf16(
    const float* __restrict__ s0, const float* __restrict__ s1,
    const float* __restrict__ s2, const float* __restrict__ s3,
    u16* __restrict__ d0, u16* __restrict__ d1,
    u16* __restrict__ d2, u16* __restrict__ d3, int n)
{
    const float* s; u16* d;
    switch (blockIdx.y) {
        case 0: s = s0; d = d0; break;
        case 1: s = s1; d = d1; break;
        case 2: s = s2; d = d2; break;
        default: s = s3; d = d3; break;
    }
    int i = (blockIdx.x * 256 + threadIdx.x) * 8;
    if (i >= n) return;
    float4 a = *(const float4*)&s[i];
    float4 b = *(const float4*)&s[i + 4];
    u16x8 v;
    v[0]=f2b(a.x); v[1]=f2b(a.y); v[2]=f2b(a.z); v[3]=f2b(a.w);
    v[4]=f2b(b.x); v[5]=f2b(b.y); v[6]=f2b(b.z); v[7]=f2b(b.w);
    *(u16x8*)&d[i] = v;
}

// ---------------------------------------------------------------------------
// Conv-weight transpose: Wc_z[512][5] -> WcT[z][5][512]  (fp32, one-time)
// ---------------------------------------------------------------------------
__global__ __launch_bounds__(256) void wprep(
    const float* __restrict__ Wcq, const float* __restrict__ Wck,
    const float* __restrict__ Wcv, float* __restrict__ WcT)
{
    const int z = blockIdx.y;
    const float* src = z == 0 ? Wcq : (z == 1 ? Wck : Wcv);
    int idx = blockIdx.x * 256 + threadIdx.x;
    if (idx >= 2560) return;
    int c = idx / 5, j = idx % 5;
    WcT[(size_t)z * 2560 + j * 512 + c] = src[idx];
}

// ---------------------------------------------------------------------------
// QKV projections, z-batched. R16: 64x256 tile (2x MFMA per barrier vs R15,
// half the A re-reads). 2-phase dbuf (40 KB LDS), one barrier/K-step.
// ---------------------------------------------------------------------------
__global__ __launch_bounds__(256) void gemm_qkv(
    const float* __restrict__ A0, const float* __restrict__ A1, const float* __restrict__ A2,
    const u16* __restrict__ Wc,
    const float* __restrict__ bq, const float* __restrict__ bk, const float* __restrict__ bv,
    u16* __restrict__ pkv)
{
    __shared__ u16 Al[2][64 * 32];
    __shared__ u16 Bl[2][256 * 32];
    const int z = blockIdx.z;
    const float* A = z == 0 ? A0 : (z == 1 ? A1 : A2);
    const u16* W = Wc + (size_t)z * NSZ * NSZ;
    const float* bias = z == 0 ? bq : (z == 1 ? bk : bv);
    const int tid = threadIdx.x;
    const int m0 = blockIdx.x * 64;
    const int n0 = blockIdx.y * 256;
    const int w = tid >> 6, lane = tid & 63;
    const int wm = (w >> 1) * 32, wn = (w & 1) * 128;
    const int fr = lane & 15, fk = lane >> 4;

    const int arow = tid >> 2, acb = tid & 3;   // A: 256 chunks

    f32x4 acc[2][8] = {};

    // ---- prologue: stage t=0 into buf 0 ----
    {
        const float* ga = &A[(size_t)(m0 + arow) * NSZ + acb * 8];
        float4 a0 = *(const float4*)ga, a1 = *(const float4*)(ga + 4);
        #pragma unroll
        for (int p = 0; p < 4; ++p) {
            int s = tid + p * 256;
            int row = s >> 2, cb = s & 3;
            GL2LDS(&W[(size_t)(n0 + row) * NSZ + cb * 8], &Bl[0][s * 8]);
        }
        u16x8 v;
        v[0]=f2b(a0.x); v[1]=f2b(a0.y); v[2]=f2b(a0.z); v[3]=f2b(a0.w);
        v[4]=f2b(a1.x); v[5]=f2b(a1.y); v[6]=f2b(a1.z); v[7]=f2b(a1.w);
        *(u16x8*)&Al[0][tid * 8] = v;
    }
    __syncthreads();

    for (int t = 0; t < 16; ++t) {
        const int cur = t & 1, nxt = cur ^ 1;
        float4 a0n, a1n;
        const bool pre = (t < 15);
        if (pre) {
            const int k0 = (t + 1) * 32;
            const float* ga = &A[(size_t)(m0 + arow) * NSZ + k0 + acb * 8];
            a0n = *(const float4*)ga;
            a1n = *(const float4*)(ga + 4);
            #pragma unroll
            for (int p = 0; p < 4; ++p) {
                int s = tid + p * 256;
                int row = s >> 2, cb = s & 3;
                GL2LDS(&W[(size_t)(n0 + row) * NSZ + k0 + cb * 8], &Bl[nxt][s * 8]);
            }
        }
        bf16x8 af[2], bfr[8];
        #pragma unroll
        for (int mf = 0; mf < 2; ++mf)
            af[mf] = *(const bf16x8*)&Al[cur][(wm + mf * 16 + fr) * 32 + fk * 8];
        #pragma unroll
        for (int nf = 0; nf < 8; ++nf)
            bfr[nf] = *(const bf16x8*)&Bl[cur][(wn + nf * 16 + fr) * 32 + fk * 8];
        #pragma unroll
        for (int mf = 0; mf < 2; ++mf)
            #pragma unroll
            for (int nf = 0; nf < 8; ++nf)
                acc[mf][nf] = __builtin_amdgcn_mfma_f32_16x16x32_bf16(
                    af[mf], bfr[nf], acc[mf][nf], 0, 0, 0);
        if (pre) {
            u16x8 v;
            v[0]=f2b(a0n.x); v[1]=f2b(a0n.y); v[2]=f2b(a0n.z); v[3]=f2b(a0n.w);
            v[4]=f2b(a1n.x); v[5]=f2b(a1n.y); v[6]=f2b(a1n.z); v[7]=f2b(a1n.w);
            *(u16x8*)&Al[nxt][tid * 8] = v;
        }
        __syncthreads();
    }
    #pragma unroll
    for (int mf = 0; mf < 2; ++mf) {
        #pragma unroll
        for (int nf = 0; nf < 8; ++nf) {
            int col = n0 + wn + nf * 16 + fr;
            float bvv = bias[col];
            #pragma unroll
            for (int r = 0; r < 4; ++r) {
                int rowg = m0 + wm + mf * 16 + fk * 4 + r;
                pkv[(size_t)rowg * 1536 + z * 512 + col] = f2b(acc[mf][nf][r] + bvv);
            }
        }
    }
}

// ---------------------------------------------------------------------------
// Output projection (fp32 out). 64x128 tile, 2-phase pipeline (R15 proven).
// ---------------------------------------------------------------------------
__global__ __launch_bounds__(256) void gemm_out(
    const u16* __restrict__ A, const u16* __restrict__ W,
    const float* __restrict__ bias, float* __restrict__ Cout, int M, int N, int K)
{
    __shared__ u16 Al[2][64 * 32];
    __shared__ u16 Bl[2][128 * 32];
    const int tid = threadIdx.x;
    const int m0 = blockIdx.x * 64;
    const int n0 = blockIdx.y * 128;
    const int w = tid >> 6, lane = tid & 63;
    const int wm = (w >> 1) * 32, wn = (w & 1) * 64;
    const int fr = lane & 15, fk = lane >> 4;

    f32x4 acc[2][4] = {};

    {
        int row = tid >> 2, cb = tid & 3;
        GL2LDS(&A[(size_t)(m0 + row) * K + cb * 8], &Al[0][tid * 8]);
        #pragma unroll
        for (int p = 0; p < 2; ++p) {
            int s = tid + p * 256;
            int r2 = s >> 2, c2 = s & 3;
            GL2LDS(&W[(size_t)(n0 + r2) * K + c2 * 8], &Bl[0][s * 8]);
        }
    }
    __syncthreads();

    const int nsteps = K / 32;
    for (int t = 0; t < nsteps; ++t) {
        const int cur = t & 1, nxt = cur ^ 1;
        if (t + 1 < nsteps) {
            const int k0 = (t + 1) * 32;
            int row = tid >> 2, cb = tid & 3;
            GL2LDS(&A[(size_t)(m0 + row) * K + k0 + cb * 8], &Al[nxt][tid * 8]);
            #pragma unroll
            for (int p = 0; p < 2; ++p) {
                int s = tid + p * 256;
                int r2 = s >> 2, c2 = s & 3;
                GL2LDS(&W[(size_t)(n0 + r2) * K + k0 + c2 * 8], &Bl[nxt][s * 8]);
            }
        }
        bf16x8 af[2], bfr[4];
        #pragma unroll
        for (int mf = 0; mf < 2; ++mf)
            af[mf] = *(const bf16x8*)&Al[cur][(wm + mf * 16 + fr) * 32 + fk * 8];
        #pragma unroll
        for (int nf = 0; nf < 4; ++nf)
            bfr[nf] = *(const bf16x8*)&Bl[cur][(wn + nf * 16 + fr) * 32 + fk * 8];
        #pragma unroll
        for (int mf = 0; mf < 2; ++mf)
            #pragma unroll
            for (int nf = 0; nf < 4; ++nf)
                acc[mf][nf] = __builtin_amdgcn_mfma_f32_16x16x32_bf16(
                    af[mf], bfr[nf], acc[mf][nf], 0, 0, 0);
        __syncthreads();
    }
    #pragma unroll
    for (int mf = 0; mf < 2; ++mf) {
        #pragma unroll
        for (int nf = 0; nf < 4; ++nf) {
            int col = n0 + wn + nf * 16 + fr;
            float bv = bias[col];
            #pragma unroll
            for (int r = 0; r < 4; ++r) {
                int rowg = m0 + wm + mf * 16 + fk * 4 + r;
                Cout[(size_t)rowg * N + col] = acc[mf][nf][r] + bv;
            }
        }
    }
}

// ---------------------------------------------------------------------------
// Fused 3x depthwise conv1d(k=5) + 3 scalar gates + mD + V-TRANSPOSE.
// R16: gated V goes straight to vpT via a 4 KB LDS transpose (vtrans kernel
// deleted; dead pkv v-write removed). q/k still written to pkv.
// ---------------------------------------------------------------------------
__global__ void conv_gate_all(
    const float* __restrict__ xn, u16* __restrict__ pkv,
    u16* __restrict__ vpT,
    const float* __restrict__ WcT,
    const float* __restrict__ Wgq, const float* __restrict__ bgq,
    const float* __restrict__ Wgk, const float* __restrict__ bgk,
    const float* __restrict__ Wgv, const float* __restrict__ bgv,
    const float* __restrict__ WmD, const float* __restrict__ bmD,
    float* __restrict__ mD)
{
    __shared__ u16 lt[4][512];   // [t][c] gated V bounce
    const int w = threadIdx.x >> 6, lane = threadIdx.x & 63;
    const int bt = blockIdx.x * 4 + w;
    const int b = bt >> 9, tpos = bt & (NT - 1);
    const int c0 = lane * 8;

    float x[5][8];
    #pragma unroll
    for (int j = 0; j < 5; ++j) {
        int tt = tpos + j - 2;
        if (tt >= 0 && tt < NT) {
            const float4* xp = (const float4*)&xn[((size_t)(b*NT + tt))*NSZ + c0];
            float4 u0 = xp[0], u1 = xp[1];
            x[j][0]=u0.x; x[j][1]=u0.y; x[j][2]=u0.z; x[j][3]=u0.w;
            x[j][4]=u1.x; x[j][5]=u1.y; x[j][6]=u1.z; x[j][7]=u1.w;
        } else {
            #pragma unroll
            for (int i = 0; i < 8; ++i) x[j][i] = 0.f;
        }
    }
    float aq[8] = {}, ak[8] = {}, av[8] = {};
    #pragma unroll
    for (int j = 0; j < 5; ++j) {
        const float* wq = &WcT[j * 512 + c0];
        const float* wk = &WcT[2560 + j * 512 + c0];
        const float* wv = &WcT[5120 + j * 512 + c0];
        float4 q0 = *(const float4*)wq, q1 = *(const float4*)(wq + 4);
        float4 k0 = *(const float4*)wk, k1 = *(const float4*)(wk + 4);
        float4 v0 = *(const float4*)wv, v1 = *(const float4*)(wv + 4);
        float wq8[8] = {q0.x,q0.y,q0.z,q0.w,q1.x,q1.y,q1.z,q1.w};
        float wk8[8] = {k0.x,k0.y,k0.z,k0.w,k1.x,k1.y,k1.z,k1.w};
        float wv8[8] = {v0.x,v0.y,v0.z,v0.w,v1.x,v1.y,v1.z,v1.w};
        #pragma unroll
        for (int i = 0; i < 8; ++i) {
            aq[i] += x[j][i] * wq8[i];
            ak[i] += x[j][i] * wk8[i];
            av[i] += x[j][i] * wv8[i];
        }
    }
    const size_t rb = (size_t)bt * 1536;
    u16x8 q8 = *(const u16x8*)&pkv[rb + c0];
    u16x8 k8 = *(const u16x8*)&pkv[rb + 512 + c0];
    u16x8 v8 = *(const u16x8*)&pkv[rb + 1024 + c0];

    float gql[8], gqh[8], gkl[8], gkh[8], gvl[8], gvh[8];
    {
        float4 a0 = *(const float4*)&Wgq[c0],      a1 = *(const float4*)&Wgq[c0 + 4];
        float4 a2 = *(const float4*)&Wgq[512 + c0], a3 = *(const float4*)&Wgq[512 + c0 + 4];
        gql[0]=a0.x;gql[1]=a0.y;gql[2]=a0.z;gql[3]=a0.w;gql[4]=a1.x;gql[5]=a1.y;gql[6]=a1.z;gql[7]=a1.w;
        gqh[0]=a2.x;gqh[1]=a2.y;gqh[2]=a2.z;gqh[3]=a2.w;gqh[4]=a3.x;gqh[5]=a3.y;gqh[6]=a3.z;gqh[7]=a3.w;
        float4 b0 = *(const float4*)&Wgk[c0],      b1 = *(const float4*)&Wgk[c0 + 4];
        float4 b2 = *(const float4*)&Wgk[512 + c0], b3 = *(const float4*)&Wgk[512 + c0 + 4];
        gkl[0]=b0.x;gkl[1]=b0.y;gkl[2]=b0.z;gkl[3]=b0.w;gkl[4]=b1.x;gkl[5]=b1.y;gkl[6]=b1.z;gkl[7]=b1.w;
        gkh[0]=b2.x;gkh[1]=b2.y;gkh[2]=b2.z;gkh[3]=b2.w;gkh[4]=b3.x;gkh[5]=b3.y;gkh[6]=b3.z;gkh[7]=b3.w;
        float4 c0v = *(const float4*)&Wgv[c0],      c1v = *(const float4*)&Wgv[c0 + 4];
        float4 c2v = *(const float4*)&Wgv[512 + c0], c3v = *(const float4*)&Wgv[512 + c0 + 4];
        gvl[0]=c0v.x;gvl[1]=c0v.y;gvl[2]=c0v.z;gvl[3]=c0v.w;gvl[4]=c1v.x;gvl[5]=c1v.y;gvl[6]=c1v.z;gvl[7]=c1v.w;
        gvh[0]=c2v.x;gvh[1]=c2v.y;gvh[2]=c2v.z;gvh[3]=c2v.w;gvh[4]=c3v.x;gvh[5]=c3v.y;gvh[6]=c3v.z;gvh[7]=c3v.w;
    }
    float sq = 0.f, sk = 0.f, sv = 0.f;
    #pragma unroll
    for (int i = 0; i < 8; ++i) {
        sq += b2f(q8[i]) * gql[i] + aq[i] * gqh[i];
        sk += b2f(k8[i]) * gkl[i] + ak[i] * gkh[i];
        sv += b2f(v8[i]) * gvl[i] + av[i] * gvh[i];
    }
    #pragma unroll
    for (int o = 1; o < 64; o <<= 1) {
        sq += __shfl_xor(sq, o, 64);
        sk += __shfl_xor(sk, o, 64);
        sv += __shfl_xor(sv, o, 64);
    }
    float gq = 1.f / (1.f + expf(-(sq + bgq[0])));
    float gk = 1.f / (1.f + expf(-(sk + bgk[0])));
    float gv = 1.f / (1.f + expf(-(sv + bgv[0])));

    float wm8[8];
    {
        float4 m0 = *(const float4*)&WmD[c0], m1 = *(const float4*)&WmD[c0 + 4];
        wm8[0]=m0.x;wm8[1]=m0.y;wm8[2]=m0.z;wm8[3]=m0.w;wm8[4]=m1.x;wm8[5]=m1.y;wm8[6]=m1.z;wm8[7]=m1.w;
    }
    u16x8 oq8, ok8, ov8;
    float smd = 0.f;
    #pragma unroll
    for (int i = 0; i < 8; ++i) {
        float oq = (1.f - gq) * b2f(q8[i]) + gq * aq[i];
        oq8[i] = f2b(oq);
        ok8[i] = f2b((1.f - gk) * b2f(k8[i]) + gk * ak[i]);
        ov8[i] = f2b((1.f - gv) * b2f(v8[i]) + gv * av[i]);
        smd += oq * wm8[i];
    }
    *(u16x8*)&pkv[rb + c0]       = oq8;
    *(u16x8*)&pkv[rb + 512 + c0] = ok8;
    *(u16x8*)&lt[w][c0] = ov8;            // gated V -> LDS (pkv v-write dead)
    #pragma unroll
    for (int o = 1; o < 64; o <<= 1) smd += __shfl_xor(smd, o, 64);
    if (lane == 0)
        mD[bt] = C_D0 + 2.f * C_STD * tanhf((smd + bmD[0]) / C_GAMMA);

    __syncthreads();
    // transposed write: vpT row (b*512 + c) gets t0..t0+3
    const int t0g = (blockIdx.x * 4) & (NT - 1);
    const int b0g = (blockIdx.x * 4) >> 9;
    #pragma unroll
    for (int p2 = 0; p2 < 2; ++p2) {
        int c = threadIdx.x + p2 * 256;
        u16x4 o4;
        o4[0] = lt[0][c]; o4[1] = lt[1][c]; o4[2] = lt[2][c]; o4[3] = lt[3][c];
        *(u16x4*)&vpT[((size_t)(b0g * 512 + c)) * NT + t0g] = o4;
    }
}

// ---------------------------------------------------------------------------
// MFMA flash attention — R14 single-pass version (unchanged).
// ---------------------------------------------------------------------------
__global__ __launch_bounds__(256) void attn_mfma(
    const u16* __restrict__ pkv, const u16* __restrict__ vpT,
    const float* __restrict__ mD, const int* __restrict__ mask,
    const float* __restrict__ rpe, u16* __restrict__ cxh)
{
    __shared__ __align__(16) char smem[70400];
    u16*  Ql    = (u16*)(smem);
    u16*  Kl    = (u16*)(smem + 8192);
    u16*  Vl    = (u16*)(smem + 24576);
    u16*  Pl    = (u16*)(smem + 40960);
    u16*  rpk   = (u16*)(smem + 40960);
    u16*  wA16  = (u16*)(smem + 57344);
    u16*  qdrl  = (u16*)(smem + 65536);
    float* inv2s= (float*)(smem + 70144);

    const int tid  = threadIdx.x;
    const int lane = tid & 63;
    const int w    = tid >> 6;
    const int wq0  = w * 16;
    const int fr   = lane & 15;
    const int fq   = lane >> 4;
    const int b    = blockIdx.x >> 3;
    const int h    = blockIdx.x & 7;
    const int q0   = blockIdx.y * 64;

    const size_t qbase  = ((size_t)(b*NT + q0)) * 1536 + h * NHD;
    const size_t kbaseg = ((size_t)b * NT) * 1536 + 512 + h * NHD;
    const size_t vbaseg = ((size_t)((b*NH + h) * NHD)) * NT;

    int Lm = 512;
    #pragma unroll
    for (int j = 0; j < 8; ++j) {
        if (mask[b * NT + lane + 64 * j]) Lm = min(Lm, lane + 64 * j);
    }
    #pragma unroll
    for (int o = 1; o < 64; o <<= 1) Lm = min(Lm, __shfl_xor(Lm, o, 64));
    const int L = Lm;
    const int w0 = max(0, min(q0 - 32, L - 128));

    #pragma unroll
    for (int p = 0; p < 2; ++p) {
        int s = tid + p * 256;
        int r = s >> 3, c = s & 7;
        u16x8 v = *(const u16x8*)(pkv + qbase + (size_t)r * 1536 + c * 8);
        *(u16x8*)(Ql + SWU(r, c)) = v;
    }
    #pragma unroll
    for (int p = 0; p < 4; ++p) {
        int s = tid + p * 256;
        int r = s >> 3, c = s & 7;
        u16x8 v = *(const u16x8*)(pkv + kbaseg + (size_t)(w0 + r) * 1536 + c * 8);
        *(u16x8*)(Kl + SWU(r, c)) = v;
    }
    #pragma unroll
    for (int p = 0; p < 4; ++p) {
        int s = tid + p * 256;
        int d = s >> 4, cc = s & 15;
        u16x8 v = *(const u16x8*)(vpT + vbaseg + (size_t)d * NT + w0 + cc * 8);
        *(u16x8*)(Vl + SWU16(d, cc)) = v;
    }
    for (int idx = tid; idx < 264; idx += 256) {
        int r = idx >> 3, c = idx & 7;
        float4 f0 = *(const float4*)&rpe[r * 128 + c * 8];
        float4 f1 = *(const float4*)&rpe[r * 128 + c * 8 + 4];
        u16x8 vv;
        vv[0]=f2b(f0.x); vv[1]=f2b(f0.y); vv[2]=f2b(f0.z); vv[3]=f2b(f0.w);
        vv[4]=f2b(f1.x); vv[5]=f2b(f1.y); vv[6]=f2b(f1.z); vv[7]=f2b(f1.w);
        *(u16x8*)(rpk + SWU(r, c)) = vv;
    }
    if (tid < 120) {
        u16x8 vv = {0,0,0,0,0,0,0,0};
        *(u16x8*)(rpk + (((33 + (tid >> 3)) * 8) + (tid & 7)) * 8) = vv;
    }
    {
        u16x8 z = {0,0,0,0,0,0,0,0};
        #pragma unroll
        for (int p = 0; p < 2; ++p) *(u16x8*)(wA16 + (tid + p * 256) * 8) = z;
    }
    if (tid < 64) {
        float md = mD[b * NT + q0 + tid];
        inv2s[tid] = 2.f * LOG2E / (md * md);
    }
    __syncthreads();                        // (P0)

    bf16x8 aq0 = *(const bf16x8*)(Ql + SWU(wq0 + fr, fq));
    bf16x8 aq1 = *(const bf16x8*)(Ql + SWU(wq0 + fr, 4 + fq));

    {
        f32x4 qd[3] = {};
        #pragma unroll
        for (int nf = 0; nf < 3; ++nf) {
            bf16x8 b0 = *(const bf16x8*)(rpk + SWU(nf * 16 + fr, fq));
            bf16x8 b1 = *(const bf16x8*)(rpk + SWU(nf * 16 + fr, 4 + fq));
            qd[nf] = __builtin_amdgcn_mfma_f32_16x16x32_bf16(aq0, b0, qd[nf], 0, 0, 0);
            qd[nf] = __builtin_amdgcn_mfma_f32_16x16x32_bf16(aq1, b1, qd[nf], 0, 0, 0);
        }
        #pragma unroll
        for (int nf = 0; nf < 3; ++nf) {
            int rd = nf * 16 + fr;
            if (rd < 33) {
                #pragma unroll
                for (int r = 0; r < 4; ++r)
                    qdrl[(wq0 + fq * 4 + r) * 36 + rd] = f2b(qd[nf][r]);
            }
        }
    }
    __syncthreads();                        // (P1)

    f32x4 s_[8] = {};
    #pragma unroll
    for (int nf = 0; nf < 8; ++nf) {
        bf16x8 b0 = *(const bf16x8*)(Kl + SWU(nf * 16 + fr, fq));
        bf16x8 b1 = *(const bf16x8*)(Kl + SWU(nf * 16 + fr, 4 + fq));
        s_[nf] = __builtin_amdgcn_mfma_f32_16x16x32_bf16(aq0, b0, s_[nf], 0, 0, 0);
        s_[nf] = __builtin_amdgcn_mfma_f32_16x16x32_bf16(aq1, b1, s_[nf], 0, 0, 0);
    }

    float li[4];
    #pragma unroll
    for (int r = 0; r < 4; ++r) {
        const int lq = wq0 + fq * 4 + r;
        const int qg = q0 + lq;
        const float iv = inv2s[lq];
        float sc[8];
        float mx = NEGINF;
        #pragma unroll
        for (int nf = 0; nf < 8; ++nf) {
            const int kg = w0 + nf * 16 + fr;
            float v;
            if (kg >= L) v = NEGINF;
            else {
                int rd = min(max(kg - qg, -MAXR), MAXR) + MAXR;
                float qr = b2f(qdrl[lq * 36 + rd]);
                float fd = (float)(qg - kg);
                v = (s_[nf][r] + qr) * C1F - fd * fd * iv;
            }
            sc[nf] = v;
            mx = fmaxf(mx, v);
        }
        mx = fmaxf(mx, __shfl_xor(mx, 1, 64));
        mx = fmaxf(mx, __shfl_xor(mx, 2, 64));
        mx = fmaxf(mx, __shfl_xor(mx, 4, 64));
        mx = fmaxf(mx, __shfl_xor(mx, 8, 64));
        float rsum = 0.f, ls = 0.f, rs = 0.f;
        #pragma unroll
        for (int nf = 0; nf < 8; ++nf) {
            const int kg = w0 + nf * 16 + fr;
            float pv = exp2_fast(sc[nf] - mx);
            s_[nf][r] = pv;
            rsum += pv;
            int d = kg - qg;
            if (d <= -MAXR) ls += pv;
            else if (d >= MAXR) rs += pv;
            else {
                int bkt = d + MAXR;
                wA16[(lq * 8 + ((bkt >> 3) ^ (lq & 7))) * 8 + (bkt & 7)] = f2b(pv);
            }
        }
        rsum += __shfl_xor(rsum, 1, 64); rsum += __shfl_xor(rsum, 2, 64);
        rsum += __shfl_xor(rsum, 4, 64); rsum += __shfl_xor(rsum, 8, 64);
        ls += __shfl_xor(ls, 1, 64); ls += __shfl_xor(ls, 2, 64);
        ls += __shfl_xor(ls, 4, 64); ls += __shfl_xor(ls, 8, 64);
        rs += __shfl_xor(rs, 1, 64); rs += __shfl_xor(rs, 2, 64);
        rs += __shfl_xor(rs, 4, 64); rs += __shfl_xor(rs, 8, 64);
        li[r] = rsum;
        if (fr == 0) {
            wA16[(lq * 8 + (0 ^ (lq & 7))) * 8 + 0] = f2b(ls);
            wA16[(lq * 8 + (4 ^ (lq & 7))) * 8 + 0] = f2b(rs);
        }
    }

    #pragma unroll
    for (int r = 0; r < 4; ++r) {
        int lq = wq0 + fq * 4 + r;
        #pragma unroll
        for (int nf = 0; nf < 8; ++nf) {
            int k = nf * 16 + fr;
            int cc = k >> 3;
            Pl[(lq * 16 + (cc ^ (lq & 7))) * 8 + (k & 7)] = f2b(s_[nf][r]);
        }
    }

    f32x4 O[4] = {};
    #pragma unroll
    for (int ks = 0; ks < 4; ++ks) {
        bf16x8 ap = *(const bf16x8*)(Pl + ((wq0 + fr) * 16 + ((ks * 4 + fq) ^ (fr & 7))) * 8);
        #pragma unroll
        for (int nf = 0; nf < 4; ++nf) {
            bf16x8 vf = *(const bf16x8*)(Vl + ((nf * 16 + fr) * 16 + ((ks * 4 + fq) ^ (fr & 7))) * 8);
            O[nf] = __builtin_amdgcn_mfma_f32_16x16x32_bf16(ap, vf, O[nf], 0, 0, 0);
        }
    }
    __syncthreads();   // (E1)

    #pragma unroll
    for (int p = 0; p < 2; ++p) {
        int s = tid + p * 256;
        int d = s >> 3, cs = s & 7;
        u16x8 vv;
        #pragma unroll
        for (int j = 0; j < 8; ++j) {
            int rd = cs * 8 + j;
            vv[j] = (rd < 33) ? f2b(rpe[rd * 128 + 64 + d]) : (u16)0;
        }
        *(u16x8*)(Vl + SWU(d, cs)) = vv;
    }
    __syncthreads();   // (E2)

    {
        bf16x8 aw0 = *(const bf16x8*)(wA16 + SWU(wq0 + fr, fq));
        bf16x8 aw1 = *(const bf16x8*)(wA16 + SWU(wq0 + fr, 4 + fq));
        #pragma unroll
        for (int nf = 0; nf < 4; ++nf) {
            bf16x8 b0 = *(const bf16x8*)(Vl + SWU(nf * 16 + fr, fq));
            bf16x8 b1 = *(const bf16x8*)(Vl + SWU(nf * 16 + fr, 4 + fq));
            O[nf] = __builtin_amdgcn_mfma_f32_16x16x32_bf16(aw0, b0, O[nf], 0, 0, 0);
            O[nf] = __builtin_amdgcn_mfma_f32_16x16x32_bf16(aw1, b1, O[nf], 0, 0, 0);
        }
    }
    float invl[4];
    #pragma unroll
    for (int r = 0; r < 4; ++r) invl[r] = 1.f / li[r];
    #pragma unroll
    for (int r = 0; r < 4; ++r) {
        int lq = wq0 + fq * 4 + r;
        #pragma unroll
        for (int nf = 0; nf < 4; ++nf)
            Pl[lq * 64 + nf * 16 + fr] = f2b(O[nf][r] * invl[r]);
    }
    __syncthreads();   // (E3)
    #pragma unroll
    for (int j = 0; j < 2; ++j) {
        int s = w * 128 + j * 64 + lane;
        int rr = s >> 3, c8 = s & 7;
        u16x8 vv = *(const u16x8*)(Pl + rr * 64 + c8 * 8);
        *(u16x8*)&cxh[((size_t)(b*NT + q0 + rr)) * 512 + h * NHD + c8 * 8] = vv;
    }
}

// ---------------------------------------------------------------------------
extern "C" void kernel_launch(void* const* d_in, const int* in_sizes, int n_in,
                              void* d_out, int out_size, void* d_ws, size_t ws_size,
                              hipStream_t stream) {
    const float* key   = (const float*)d_in[0];
    const float* value = (const float*)d_in[1];
    const float* query = (const float*)d_in[2];
    const int*   mask  = (const int*)d_in[3];
    const float* Wq  = (const float*)d_in[4];
    const float* bq  = (const float*)d_in[5];
    const float* Wk  = (const float*)d_in[6];
    const float* bk  = (const float*)d_in[7];
    const float* Wv  = (const float*)d_in[8];
    const float* bv  = (const float*)d_in[9];
    const float* Wcq = (const float*)d_in[10];
    const float* Wck = (const float*)d_in[11];
    const float* Wcv = (const float*)d_in[12];
    const float* Wgq = (const float*)d_in[13];
    const float* bgq = (const float*)d_in[14];
    const float* Wgk = (const float*)d_in[15];
    const float* bgk = (const float*)d_in[16];
    const float* Wgv = (const float*)d_in[17];
    const float* bgv = (const float*)d_in[18];
    const float* WmD = (const float*)d_in[19];
    const float* bmD = (const float*)d_in[20];
    const float* rpe = (const float*)d_in[21];
    const float* Wo  = (const float*)d_in[22];
    const float* bo  = (const float*)d_in[23];
    float* out = (float*)d_out;

    const size_t NTOK = (size_t)NB * NT;            // 8192
    const size_t NE   = NTOK * NSZ;                 // 4,194,304
    const size_t NW   = (size_t)NSZ * NSZ;          // 262,144

    u16* ws16 = (u16*)d_ws;
    u16* pkv  = ws16;                // (8192, 1536) q|k|v
    u16* wcat = pkv + NTOK * 1536;   // 3 x (512,512)
    u16* woh  = wcat + 3 * NW;
    u16* vpT  = woh + NW;            // (16*8*64, 512)
    u16* cxh  = vpT + NE;            // (8192, 512)
    float* mDb = (float*)(cxh + NE);
    float* WcT = mDb + NTOK;         // 3 x (5,512) fp32

    cvt4_bf16<<<dim3((unsigned)(NW/8/256), 4), 256, 0, stream>>>(
        Wq, Wk, Wv, Wo, wcat, wcat + NW, wcat + 2*NW, woh, (int)NW);
    wprep<<<dim3(10, 3), 256, 0, stream>>>(Wcq, Wck, Wcv, WcT);

    gemm_qkv<<<dim3(128, 2, 3), 256, 0, stream>>>(
        query, key, value, wcat, bq, bk, bv, pkv);

    conv_gate_all<<<(int)(NTOK / 4), 256, 0, stream>>>(
        key, pkv, vpT, WcT, Wgq, bgq, Wgk, bgk, Wgv, bgv, WmD, bmD, mDb);

    attn_mfma<<<dim3(128, 8), 256, 0, stream>>>(pkv, vpT, mDb, mask, rpe, cxh);

    gemm_out<<<dim3(128, 4), 256, 0, stream>>>(cxh, woh, bo, out, (int)NTOK, NSZ, NSZ);
}

// Round 17
// 108.056 us; speedup vs baseline: 2.0663x; 1.0054x over previous
//
#include <hip/hip_runtime.h>
#include <math.h>

#define NB 16
#define NT 512
#define NSZ 512
#define NH 8
#define NHD 64
#define MAXR 16

#define C_D0 6.3f
#define C_STD 1.4f
#define C_GAMMA 2.0f

#define NEGINF (-1e30f)
#define LOG2E 1.4426950408889634f
#define C1F   0.18033688011112042f   // 0.125 * log2(e)

typedef unsigned short u16;
typedef __attribute__((ext_vector_type(8))) short bf16x8;
typedef __attribute__((ext_vector_type(4))) float f32x4;
typedef __attribute__((ext_vector_type(8))) unsigned short u16x8;
typedef __attribute__((ext_vector_type(4))) unsigned short u16x4;

__device__ __forceinline__ u16 f2b(float f) {
    union { float f; unsigned int u; } c; c.f = f;
    unsigned int u = c.u + 0x7FFFu + ((c.u >> 16) & 1u);
    return (u16)(u >> 16);
}
__device__ __forceinline__ float b2f(u16 h) {
    union { unsigned int u; float f; } c; c.u = ((unsigned int)h) << 16;
    return c.f;
}

#if __has_builtin(__builtin_amdgcn_exp2f)
__device__ __forceinline__ float exp2_fast(float x) { return __builtin_amdgcn_exp2f(x); }
#else
__device__ __forceinline__ float exp2_fast(float x) { return exp2f(x); }
#endif

#define GL2LDS(gp, lp) __builtin_amdgcn_global_load_lds( \
    (const __attribute__((address_space(1))) void*)(gp), \
    (__attribute__((address_space(3))) void*)(lp), 16, 0, 0)

// swizzled u16-index of 16B chunk c in row r (8-chunk rows = 64 bf16)
#define SWU(r, c) ((((r) * 8) + ((c) ^ ((r) & 7))) * 8)
// swizzled u16-index for 16-chunk rows (128 bf16 per row)
#define SWU16(r, c) ((((r) * 16) + ((c) ^ ((r) & 7))) * 8)

// ---------------------------------------------------------------------------
// fp32 -> bf16 convert (weights only)
// ---------------------------------------------------------------------------
__global__ __launch_bounds__(256) void cvt4_bf16(
    const float* __restrict__ s0, const float* __restrict__ s1,
    const float* __restrict__ s2, const float* __restrict__ s3,
    u16* __restrict__ d0, u16* __restrict__ d1,
    u16* __restrict__ d2, u16* __restrict__ d3, int n)
{
    const float* s; u16* d;
    switch (blockIdx.y) {
        case 0: s = s0; d = d0; break;
        case 1: s = s1; d = d1; break;
        case 2: s = s2; d = d2; break;
        default: s = s3; d = d3; break;
    }
    int i = (blockIdx.x * 256 + threadIdx.x) * 8;
    if (i >= n) return;
    float4 a = *(const float4*)&s[i];
    float4 b = *(const float4*)&s[i + 4];
    u16x8 v;
    v[0]=f2b(a.x); v[1]=f2b(a.y); v[2]=f2b(a.z); v[3]=f2b(a.w);
    v[4]=f2b(b.x); v[5]=f2b(b.y); v[6]=f2b(b.z); v[7]=f2b(b.w);
    *(u16x8*)&d[i] = v;
}

// ---------------------------------------------------------------------------
// Conv-weight transpose: Wc_z[512][5] -> WcT[z][5][512]  (fp32, one-time)
// ---------------------------------------------------------------------------
__global__ __launch_bounds__(256) void wprep(
    const float* __restrict__ Wcq, const float* __restrict__ Wck,
    const float* __restrict__ Wcv, float* __restrict__ WcT)
{
    const int z = blockIdx.y;
    const float* src = z == 0 ? Wcq : (z == 1 ? Wck : Wcv);
    int idx = blockIdx.x * 256 + threadIdx.x;
    if (idx >= 2560) return;
    int c = idx / 5, j = idx % 5;
    WcT[(size_t)z * 2560 + j * 512 + c] = src[idx];
}

// ---------------------------------------------------------------------------
// QKV projections, z-batched, 64x128 tile.
// R17: counted-wait pipeline. W via 3-buffer GL2LDS rotation; A via 2-deep
// register pipeline (even/odd reg banks, 2x-unrolled loop, no reg copies).
// The cvt of A(t+1) forces the COMPILER's counted vmcnt to retire exactly
// {W(t+1),A(t+1)} while keeping {W(t+2),A(t+2)} in flight. Raw s_barrier
// (no implicit vmcnt(0) drain) + manual lgkmcnt(0) for the A ds_write.
// ---------------------------------------------------------------------------
__global__ __launch_bounds__(256) void gemm_qkv(
    const float* __restrict__ A0, const float* __restrict__ A1, const float* __restrict__ A2,
    const u16* __restrict__ Wc,
    const float* __restrict__ bq, const float* __restrict__ bk, const float* __restrict__ bv,
    u16* __restrict__ pkv)
{
    __shared__ u16 Al[2][64 * 32];     // 8 KB
    __shared__ u16 Wl[3][128 * 32];    // 24 KB
    const int z = blockIdx.z;
    const float* A = z == 0 ? A0 : (z == 1 ? A1 : A2);
    const u16* W = Wc + (size_t)z * NSZ * NSZ;
    const float* bias = z == 0 ? bq : (z == 1 ? bk : bv);
    const int tid = threadIdx.x;
    const int m0 = blockIdx.x * 64;
    const int n0 = blockIdx.y * 128;
    const int w = tid >> 6, lane = tid & 63;
    const int wm = (w >> 1) * 32, wn = (w & 1) * 64;
    const int fr = lane & 15, fk = lane >> 4;

    const int arow = tid >> 2, acb = tid & 3;
    const float* gA = &A[(size_t)(m0 + arow) * NSZ + acb * 8];
    const int wrow = tid >> 2, wcb = tid & 3;

    f32x4 acc[2][4] = {};

    // ---- prologue: A(0) cvt'd now; A(1) -> regs a; W(0),W(1) in flight ----
    float4 t0a = *(const float4*)(gA);
    float4 t0b = *(const float4*)(gA + 4);
    #pragma unroll
    for (int p = 0; p < 2; ++p) {
        int s = tid + p * 256;
        int row = s >> 2, cb = s & 3;
        GL2LDS(&W[(size_t)(n0 + row) * NSZ + cb * 8], &Wl[0][s * 8]);
    }
    #pragma unroll
    for (int p = 0; p < 2; ++p) {
        int s = tid + p * 256;
        int row = s >> 2, cb = s & 3;
        GL2LDS(&W[(size_t)(n0 + row) * NSZ + 32 + cb * 8], &Wl[1][s * 8]);
    }
    float4 a0 = *(const float4*)(gA + 32);
    float4 a1 = *(const float4*)(gA + 36);
    {
        u16x8 v;
        v[0]=f2b(t0a.x); v[1]=f2b(t0a.y); v[2]=f2b(t0a.z); v[3]=f2b(t0a.w);
        v[4]=f2b(t0b.x); v[5]=f2b(t0b.y); v[6]=f2b(t0b.z); v[7]=f2b(t0b.w);
        *(u16x8*)&Al[0][tid * 8] = v;
    }
    asm volatile("s_waitcnt lgkmcnt(0)" ::: "memory");
    __builtin_amdgcn_sched_barrier(0);
    __builtin_amdgcn_s_barrier();

    float4 b0, b1;
    int wiC = 0;                        // t % 3
    #pragma unroll 1
    for (int tt = 0; tt < 8; ++tt) {
        // ================= even t = 2*tt : cvt a (A(t+1)), load -> b =====
        {
            const int t = 2 * tt;
            const int wiS = (wiC + 2 >= 3) ? wiC - 1 : wiC + 2;
            bf16x8 af[2], bfr[4];
            #pragma unroll
            for (int mf = 0; mf < 2; ++mf)
                af[mf] = *(const bf16x8*)&Al[t & 1][(wm + mf * 16 + fr) * 32 + fk * 8];
            #pragma unroll
            for (int nf = 0; nf < 4; ++nf)
                bfr[nf] = *(const bf16x8*)&Wl[wiC][(wn + nf * 16 + fr) * 32 + fk * 8];
            if (t < 14) {
                const int k0 = (t + 2) * 32;
                #pragma unroll
                for (int p = 0; p < 2; ++p) {
                    int s = tid + p * 256;
                    int row = s >> 2, cb = s & 3;
                    GL2LDS(&W[(size_t)(n0 + row) * NSZ + k0 + cb * 8], &Wl[wiS][s * 8]);
                }
                b0 = *(const float4*)(gA + k0);
                b1 = *(const float4*)(gA + k0 + 4);
            }
            if (t < 15) {
                u16x8 v;
                v[0]=f2b(a0.x); v[1]=f2b(a0.y); v[2]=f2b(a0.z); v[3]=f2b(a0.w);
                v[4]=f2b(a1.x); v[5]=f2b(a1.y); v[6]=f2b(a1.z); v[7]=f2b(a1.w);
                *(u16x8*)&Al[(t + 1) & 1][tid * 8] = v;
            }
            #pragma unroll
            for (int mf = 0; mf < 2; ++mf)
                #pragma unroll
                for (int nf = 0; nf < 4; ++nf)
                    acc[mf][nf] = __builtin_amdgcn_mfma_f32_16x16x32_bf16(
                        af[mf], bfr[nf], acc[mf][nf], 0, 0, 0);
            asm volatile("s_waitcnt lgkmcnt(0)" ::: "memory");
            __builtin_amdgcn_sched_barrier(0);
            __builtin_amdgcn_s_barrier();
            wiC = (wiC + 1 >= 3) ? 0 : wiC + 1;
        }
        // ================= odd t = 2*tt+1 : cvt b (A(t+1)), load -> a =====
        {
            const int t = 2 * tt + 1;
            const int wiS = (wiC + 2 >= 3) ? wiC - 1 : wiC + 2;
            bf16x8 af[2], bfr[4];
            #pragma unroll
            for (int mf = 0; mf < 2; ++mf)
                af[mf] = *(const bf16x8*)&Al[t & 1][(wm + mf * 16 + fr) * 32 + fk * 8];
            #pragma unroll
            for (int nf = 0; nf < 4; ++nf)
                bfr[nf] = *(const bf16x8*)&Wl[wiC][(wn + nf * 16 + fr) * 32 + fk * 8];
            if (t < 14) {
                const int k0 = (t + 2) * 32;
                #pragma unroll
                for (int p = 0; p < 2; ++p) {
                    int s = tid + p * 256;
                    int row = s >> 2, cb = s & 3;
                    GL2LDS(&W[(size_t)(n0 + row) * NSZ + k0 + cb * 8], &Wl[wiS][s * 8]);
                }
                a0 = *(const float4*)(gA + k0);
                a1 = *(const float4*)(gA + k0 + 4);
            }
            if (t < 15) {
                u16x8 v;
                v[0]=f2b(b0.x); v[1]=f2b(b0.y); v[2]=f2b(b0.z); v[3]=f2b(b0.w);
                v[4]=f2b(b1.x); v[5]=f2b(b1.y); v[6]=f2b(b1.z); v[7]=f2b(b1.w);
                *(u16x8*)&Al[(t + 1) & 1][tid * 8] = v;
            }
            #pragma unroll
            for (int mf = 0; mf < 2; ++mf)
                #pragma unroll
                for (int nf = 0; nf < 4; ++nf)
                    acc[mf][nf] = __builtin_amdgcn_mfma_f32_16x16x32_bf16(
                        af[mf], bfr[nf], acc[mf][nf], 0, 0, 0);
            asm volatile("s_waitcnt lgkmcnt(0)" ::: "memory");
            __builtin_amdgcn_sched_barrier(0);
            __builtin_amdgcn_s_barrier();
            wiC = (wiC + 1 >= 3) ? 0 : wiC + 1;
        }
    }
    #pragma unroll
    for (int mf = 0; mf < 2; ++mf) {
        #pragma unroll
        for (int nf = 0; nf < 4; ++nf) {
            int col = n0 + wn + nf * 16 + fr;
            float bvv = bias[col];
            #pragma unroll
            for (int r = 0; r < 4; ++r) {
                int rowg = m0 + wm + mf * 16 + fk * 4 + r;
                pkv[(size_t)rowg * 1536 + z * 512 + col] = f2b(acc[mf][nf][r] + bvv);
            }
        }
    }
}

// ---------------------------------------------------------------------------
// Output projection (fp32 out). R17: 3-buffer GL2LDS rotation for BOTH
// operands; one manual counted vmcnt(3) per iter (retire set t, keep t+1);
// raw s_barrier (no drain).
// ---------------------------------------------------------------------------
__global__ __launch_bounds__(256) void gemm_out(
    const u16* __restrict__ A, const u16* __restrict__ W,
    const float* __restrict__ bias, float* __restrict__ Cout, int M, int N, int K)
{
    __shared__ u16 Al[3][64 * 32];     // 12 KB
    __shared__ u16 Bl[3][128 * 32];    // 24 KB
    const int tid = threadIdx.x;
    const int m0 = blockIdx.x * 64;
    const int n0 = blockIdx.y * 128;
    const int w = tid >> 6, lane = tid & 63;
    const int wm = (w >> 1) * 32, wn = (w & 1) * 64;
    const int fr = lane & 15, fk = lane >> 4;

    f32x4 acc[2][4] = {};

    // prologue: issue sets 0 and 1 (3 GL2LDS each per thread)
    #pragma unroll
    for (int t0 = 0; t0 < 2; ++t0) {
        int k0 = t0 * 32;
        {
            int row = tid >> 2, cb = tid & 3;
            GL2LDS(&A[(size_t)(m0 + row) * K + k0 + cb * 8], &Al[t0][tid * 8]);
        }
        #pragma unroll
        for (int p = 0; p < 2; ++p) {
            int s = tid + p * 256;
            int r2 = s >> 2, c2 = s & 3;
            GL2LDS(&W[(size_t)(n0 + r2) * K + k0 + c2 * 8], &Bl[t0][s * 8]);
        }
    }

    int cur = 0;
    #pragma unroll 1
    for (int t = 0; t < 16; ++t) {
        if (t < 15) asm volatile("s_waitcnt vmcnt(3)" ::: "memory");
        else        asm volatile("s_waitcnt vmcnt(0)" ::: "memory");
        __builtin_amdgcn_sched_barrier(0);
        __builtin_amdgcn_s_barrier();

        bf16x8 af[2], bfr[4];
        #pragma unroll
        for (int mf = 0; mf < 2; ++mf)
            af[mf] = *(const bf16x8*)&Al[cur][(wm + mf * 16 + fr) * 32 + fk * 8];
        #pragma unroll
        for (int nf = 0; nf < 4; ++nf)
            bfr[nf] = *(const bf16x8*)&Bl[cur][(wn + nf * 16 + fr) * 32 + fk * 8];

        if (t < 14) {
            const int k0 = (t + 2) * 32;
            const int stg = (cur + 2 >= 3) ? cur - 1 : cur + 2;
            {
                int row = tid >> 2, cb = tid & 3;
                GL2LDS(&A[(size_t)(m0 + row) * K + k0 + cb * 8], &Al[stg][tid * 8]);
            }
            #pragma unroll
            for (int p = 0; p < 2; ++p) {
                int s = tid + p * 256;
                int r2 = s >> 2, c2 = s & 3;
                GL2LDS(&W[(size_t)(n0 + r2) * K + k0 + c2 * 8], &Bl[stg][s * 8]);
            }
        }
        #pragma unroll
        for (int mf = 0; mf < 2; ++mf)
            #pragma unroll
            for (int nf = 0; nf < 4; ++nf)
                acc[mf][nf] = __builtin_amdgcn_mfma_f32_16x16x32_bf16(
                    af[mf], bfr[nf], acc[mf][nf], 0, 0, 0);
        cur = (cur + 1 >= 3) ? 0 : cur + 1;
    }
    #pragma unroll
    for (int mf = 0; mf < 2; ++mf) {
        #pragma unroll
        for (int nf = 0; nf < 4; ++nf) {
            int col = n0 + wn + nf * 16 + fr;
            float bv = bias[col];
            #pragma unroll
            for (int r = 0; r < 4; ++r) {
                int rowg = m0 + wm + mf * 16 + fk * 4 + r;
                Cout[(size_t)rowg * N + col] = acc[mf][nf][r] + bv;
            }
        }
    }
}

// ---------------------------------------------------------------------------
// Fused 3x depthwise conv1d(k=5) + 3 scalar gates + mD + V-transpose
// (R16 proven version).
// ---------------------------------------------------------------------------
__global__ void conv_gate_all(
    const float* __restrict__ xn, u16* __restrict__ pkv,
    u16* __restrict__ vpT,
    const float* __restrict__ WcT,
    const float* __restrict__ Wgq, const float* __restrict__ bgq,
    const float* __restrict__ Wgk, const float* __restrict__ bgk,
    const float* __restrict__ Wgv, const float* __restrict__ bgv,
    const float* __restrict__ WmD, const float* __restrict__ bmD,
    float* __restrict__ mD)
{
    __shared__ u16 lt[4][512];
    const int w = threadIdx.x >> 6, lane = threadIdx.x & 63;
    const int bt = blockIdx.x * 4 + w;
    const int b = bt >> 9, tpos = bt & (NT - 1);
    const int c0 = lane * 8;

    float x[5][8];
    #pragma unroll
    for (int j = 0; j < 5; ++j) {
        int tt = tpos + j - 2;
        if (tt >= 0 && tt < NT) {
            const float4* xp = (const float4*)&xn[((size_t)(b*NT + tt))*NSZ + c0];
            float4 u0 = xp[0], u1 = xp[1];
            x[j][0]=u0.x; x[j][1]=u0.y; x[j][2]=u0.z; x[j][3]=u0.w;
            x[j][4]=u1.x; x[j][5]=u1.y; x[j][6]=u1.z; x[j][7]=u1.w;
        } else {
            #pragma unroll
            for (int i = 0; i < 8; ++i) x[j][i] = 0.f;
        }
    }
    float aq[8] = {}, ak[8] = {}, av[8] = {};
    #pragma unroll
    for (int j = 0; j < 5; ++j) {
        const float* wq = &WcT[j * 512 + c0];
        const float* wk = &WcT[2560 + j * 512 + c0];
        const float* wv = &WcT[5120 + j * 512 + c0];
        float4 q0 = *(const float4*)wq, q1 = *(const float4*)(wq + 4);
        float4 k0 = *(const float4*)wk, k1 = *(const float4*)(wk + 4);
        float4 v0 = *(const float4*)wv, v1 = *(const float4*)(wv + 4);
        float wq8[8] = {q0.x,q0.y,q0.z,q0.w,q1.x,q1.y,q1.z,q1.w};
        float wk8[8] = {k0.x,k0.y,k0.z,k0.w,k1.x,k1.y,k1.z,k1.w};
        float wv8[8] = {v0.x,v0.y,v0.z,v0.w,v1.x,v1.y,v1.z,v1.w};
        #pragma unroll
        for (int i = 0; i < 8; ++i) {
            aq[i] += x[j][i] * wq8[i];
            ak[i] += x[j][i] * wk8[i];
            av[i] += x[j][i] * wv8[i];
        }
    }
    const size_t rb = (size_t)bt * 1536;
    u16x8 q8 = *(const u16x8*)&pkv[rb + c0];
    u16x8 k8 = *(const u16x8*)&pkv[rb + 512 + c0];
    u16x8 v8 = *(const u16x8*)&pkv[rb + 1024 + c0];

    float gql[8], gqh[8], gkl[8], gkh[8], gvl[8], gvh[8];
    {
        float4 a0 = *(const float4*)&Wgq[c0],      a1 = *(const float4*)&Wgq[c0 + 4];
        float4 a2 = *(const float4*)&Wgq[512 + c0], a3 = *(const float4*)&Wgq[512 + c0 + 4];
        gql[0]=a0.x;gql[1]=a0.y;gql[2]=a0.z;gql[3]=a0.w;gql[4]=a1.x;gql[5]=a1.y;gql[6]=a1.z;gql[7]=a1.w;
        gqh[0]=a2.x;gqh[1]=a2.y;gqh[2]=a2.z;gqh[3]=a2.w;gqh[4]=a3.x;gqh[5]=a3.y;gqh[6]=a3.z;gqh[7]=a3.w;
        float4 b0 = *(const float4*)&Wgk[c0],      b1 = *(const float4*)&Wgk[c0 + 4];
        float4 b2 = *(const float4*)&Wgk[512 + c0], b3 = *(const float4*)&Wgk[512 + c0 + 4];
        gkl[0]=b0.x;gkl[1]=b0.y;gkl[2]=b0.z;gkl[3]=b0.w;gkl[4]=b1.x;gkl[5]=b1.y;gkl[6]=b1.z;gkl[7]=b1.w;
        gkh[0]=b2.x;gkh[1]=b2.y;gkh[2]=b2.z;gkh[3]=b2.w;gkh[4]=b3.x;gkh[5]=b3.y;gkh[6]=b3.z;gkh[7]=b3.w;
        float4 c0v = *(const float4*)&Wgv[c0],      c1v = *(const float4*)&Wgv[c0 + 4];
        float4 c2v = *(const float4*)&Wgv[512 + c0], c3v = *(const float4*)&Wgv[512 + c0 + 4];
        gvl[0]=c0v.x;gvl[1]=c0v.y;gvl[2]=c0v.z;gvl[3]=c0v.w;gvl[4]=c1v.x;gvl[5]=c1v.y;gvl[6]=c1v.z;gvl[7]=c1v.w;
        gvh[0]=c2v.x;gvh[1]=c2v.y;gvh[2]=c2v.z;gvh[3]=c2v.w;gvh[4]=c3v.x;gvh[5]=c3v.y;gvh[6]=c3v.z;gvh[7]=c3v.w;
    }
    float sq = 0.f, sk = 0.f, sv = 0.f;
    #pragma unroll
    for (int i = 0; i < 8; ++i) {
        sq += b2f(q8[i]) * gql[i] + aq[i] * gqh[i];
        sk += b2f(k8[i]) * gkl[i] + ak[i] * gkh[i];
        sv += b2f(v8[i]) * gvl[i] + av[i] * gvh[i];
    }
    #pragma unroll
    for (int o = 1; o < 64; o <<= 1) {
        sq += __shfl_xor(sq, o, 64);
        sk += __shfl_xor(sk, o, 64);
        sv += __shfl_xor(sv, o, 64);
    }
    float gq = 1.f / (1.f + expf(-(sq + bgq[0])));
    float gk = 1.f / (1.f + expf(-(sk + bgk[0])));
    float gv = 1.f / (1.f + expf(-(sv + bgv[0])));

    float wm8[8];
    {
        float4 m0 = *(const float4*)&WmD[c0], m1 = *(const float4*)&WmD[c0 + 4];
        wm8[0]=m0.x;wm8[1]=m0.y;wm8[2]=m0.z;wm8[3]=m0.w;wm8[4]=m1.x;wm8[5]=m1.y;wm8[6]=m1.z;wm8[7]=m1.w;
    }
    u16x8 oq8, ok8, ov8;
    float smd = 0.f;
    #pragma unroll
    for (int i = 0; i < 8; ++i) {
        float oq = (1.f - gq) * b2f(q8[i]) + gq * aq[i];
        oq8[i] = f2b(oq);
        ok8[i] = f2b((1.f - gk) * b2f(k8[i]) + gk * ak[i]);
        ov8[i] = f2b((1.f - gv) * b2f(v8[i]) + gv * av[i]);
        smd += oq * wm8[i];
    }
    *(u16x8*)&pkv[rb + c0]       = oq8;
    *(u16x8*)&pkv[rb + 512 + c0] = ok8;
    *(u16x8*)&lt[w][c0] = ov8;
    #pragma unroll
    for (int o = 1; o < 64; o <<= 1) smd += __shfl_xor(smd, o, 64);
    if (lane == 0)
        mD[bt] = C_D0 + 2.f * C_STD * tanhf((smd + bmD[0]) / C_GAMMA);

    __syncthreads();
    const int t0g = (blockIdx.x * 4) & (NT - 1);
    const int b0g = (blockIdx.x * 4) >> 9;
    #pragma unroll
    for (int p2 = 0; p2 < 2; ++p2) {
        int c = threadIdx.x + p2 * 256;
        u16x4 o4;
        o4[0] = lt[0][c]; o4[1] = lt[1][c]; o4[2] = lt[2][c]; o4[3] = lt[3][c];
        *(u16x4*)&vpT[((size_t)(b0g * 512 + c)) * NT + t0g] = o4;
    }
}

// ---------------------------------------------------------------------------
// MFMA flash attention — R14 single-pass version (unchanged).
// ---------------------------------------------------------------------------
__global__ __launch_bounds__(256) void attn_mfma(
    const u16* __restrict__ pkv, const u16* __restrict__ vpT,
    const float* __restrict__ mD, const int* __restrict__ mask,
    const float* __restrict__ rpe, u16* __restrict__ cxh)
{
    __shared__ __align__(16) char smem[70400];
    u16*  Ql    = (u16*)(smem);
    u16*  Kl    = (u16*)(smem + 8192);
    u16*  Vl    = (u16*)(smem + 24576);
    u16*  Pl    = (u16*)(smem + 40960);
    u16*  rpk   = (u16*)(smem + 40960);
    u16*  wA16  = (u16*)(smem + 57344);
    u16*  qdrl  = (u16*)(smem + 65536);
    float* inv2s= (float*)(smem + 70144);

    const int tid  = threadIdx.x;
    const int lane = tid & 63;
    const int w    = tid >> 6;
    const int wq0  = w * 16;
    const int fr   = lane & 15;
    const int fq   = lane >> 4;
    const int b    = blockIdx.x >> 3;
    const int h    = blockIdx.x & 7;
    const int q0   = blockIdx.y * 64;

    const size_t qbase  = ((size_t)(b*NT + q0)) * 1536 + h * NHD;
    const size_t kbaseg = ((size_t)b * NT) * 1536 + 512 + h * NHD;
    const size_t vbaseg = ((size_t)((b*NH + h) * NHD)) * NT;

    int Lm = 512;
    #pragma unroll
    for (int j = 0; j < 8; ++j) {
        if (mask[b * NT + lane + 64 * j]) Lm = min(Lm, lane + 64 * j);
    }
    #pragma unroll
    for (int o = 1; o < 64; o <<= 1) Lm = min(Lm, __shfl_xor(Lm, o, 64));
    const int L = Lm;
    const int w0 = max(0, min(q0 - 32, L - 128));

    #pragma unroll
    for (int p = 0; p < 2; ++p) {
        int s = tid + p * 256;
        int r = s >> 3, c = s & 7;
        u16x8 v = *(const u16x8*)(pkv + qbase + (size_t)r * 1536 + c * 8);
        *(u16x8*)(Ql + SWU(r, c)) = v;
    }
    #pragma unroll
    for (int p = 0; p < 4; ++p) {
        int s = tid + p * 256;
        int r = s >> 3, c = s & 7;
        u16x8 v = *(const u16x8*)(pkv + kbaseg + (size_t)(w0 + r) * 1536 + c * 8);
        *(u16x8*)(Kl + SWU(r, c)) = v;
    }
    #pragma unroll
    for (int p = 0; p < 4; ++p) {
        int s = tid + p * 256;
        int d = s >> 4, cc = s & 15;
        u16x8 v = *(const u16x8*)(vpT + vbaseg + (size_t)d * NT + w0 + cc * 8);
        *(u16x8*)(Vl + SWU16(d, cc)) = v;
    }
    for (int idx = tid; idx < 264; idx += 256) {
        int r = idx >> 3, c = idx & 7;
        float4 f0 = *(const float4*)&rpe[r * 128 + c * 8];
        float4 f1 = *(const float4*)&rpe[r * 128 + c * 8 + 4];
        u16x8 vv;
        vv[0]=f2b(f0.x); vv[1]=f2b(f0.y); vv[2]=f2b(f0.z); vv[3]=f2b(f0.w);
        vv[4]=f2b(f1.x); vv[5]=f2b(f1.y); vv[6]=f2b(f1.z); vv[7]=f2b(f1.w);
        *(u16x8*)(rpk + SWU(r, c)) = vv;
    }
    if (tid < 120) {
        u16x8 vv = {0,0,0,0,0,0,0,0};
        *(u16x8*)(rpk + (((33 + (tid >> 3)) * 8) + (tid & 7)) * 8) = vv;
    }
    {
        u16x8 z = {0,0,0,0,0,0,0,0};
        #pragma unroll
        for (int p = 0; p < 2; ++p) *(u16x8*)(wA16 + (tid + p * 256) * 8) = z;
    }
    if (tid < 64) {
        float md = mD[b * NT + q0 + tid];
        inv2s[tid] = 2.f * LOG2E / (md * md);
    }
    __syncthreads();                        // (P0)

    bf16x8 aq0 = *(const bf16x8*)(Ql + SWU(wq0 + fr, fq));
    bf16x8 aq1 = *(const bf16x8*)(Ql + SWU(wq0 + fr, 4 + fq));

    {
        f32x4 qd[3] = {};
        #pragma unroll
        for (int nf = 0; nf < 3; ++nf) {
            bf16x8 b0 = *(const bf16x8*)(rpk + SWU(nf * 16 + fr, fq));
            bf16x8 b1 = *(const bf16x8*)(rpk + SWU(nf * 16 + fr, 4 + fq));
            qd[nf] = __builtin_amdgcn_mfma_f32_16x16x32_bf16(aq0, b0, qd[nf], 0, 0, 0);
            qd[nf] = __builtin_amdgcn_mfma_f32_16x16x32_bf16(aq1, b1, qd[nf], 0, 0, 0);
        }
        #pragma unroll
        for (int nf = 0; nf < 3; ++nf) {
            int rd = nf * 16 + fr;
            if (rd < 33) {
                #pragma unroll
                for (int r = 0; r < 4; ++r)
                    qdrl[(wq0 + fq * 4 + r) * 36 + rd] = f2b(qd[nf][r]);
            }
        }
    }
    __syncthreads();                        // (P1)

    f32x4 s_[8] = {};
    #pragma unroll
    for (int nf = 0; nf < 8; ++nf) {
        bf16x8 b0 = *(const bf16x8*)(Kl + SWU(nf * 16 + fr, fq));
        bf16x8 b1 = *(const bf16x8*)(Kl + SWU(nf * 16 + fr, 4 + fq));
        s_[nf] = __builtin_amdgcn_mfma_f32_16x16x32_bf16(aq0, b0, s_[nf], 0, 0, 0);
        s_[nf] = __builtin_amdgcn_mfma_f32_16x16x32_bf16(aq1, b1, s_[nf], 0, 0, 0);
    }

    float li[4];
    #pragma unroll
    for (int r = 0; r < 4; ++r) {
        const int lq = wq0 + fq * 4 + r;
        const int qg = q0 + lq;
        const float iv = inv2s[lq];
        float sc[8];
        float mx = NEGINF;
        #pragma unroll
        for (int nf = 0; nf < 8; ++nf) {
            const int kg = w0 + nf * 16 + fr;
            float v;
            if (kg >= L) v = NEGINF;
            else {
                int rd = min(max(kg - qg, -MAXR), MAXR) + MAXR;
                float qr = b2f(qdrl[lq * 36 + rd]);
                float fd = (float)(qg - kg);
                v = (s_[nf][r] + qr) * C1F - fd * fd * iv;
            }
            sc[nf] = v;
            mx = fmaxf(mx, v);
        }
        mx = fmaxf(mx, __shfl_xor(mx, 1, 64));
        mx = fmaxf(mx, __shfl_xor(mx, 2, 64));
        mx = fmaxf(mx, __shfl_xor(mx, 4, 64));
        mx = fmaxf(mx, __shfl_xor(mx, 8, 64));
        float rsum = 0.f, ls = 0.f, rs = 0.f;
        #pragma unroll
        for (int nf = 0; nf < 8; ++nf) {
            const int kg = w0 + nf * 16 + fr;
            float pv = exp2_fast(sc[nf] - mx);
            s_[nf][r] = pv;
            rsum += pv;
            int d = kg - qg;
            if (d <= -MAXR) ls += pv;
            else if (d >= MAXR) rs += pv;
            else {
                int bkt = d + MAXR;
                wA16[(lq * 8 + ((bkt >> 3) ^ (lq & 7))) * 8 + (bkt & 7)] = f2b(pv);
            }
        }
        rsum += __shfl_xor(rsum, 1, 64); rsum += __shfl_xor(rsum, 2, 64);
        rsum += __shfl_xor(rsum, 4, 64); rsum += __shfl_xor(rsum, 8, 64);
        ls += __shfl_xor(ls, 1, 64); ls += __shfl_xor(ls, 2, 64);
        ls += __shfl_xor(ls, 4, 64); ls += __shfl_xor(ls, 8, 64);
        rs += __shfl_xor(rs, 1, 64); rs += __shfl_xor(rs, 2, 64);
        rs += __shfl_xor(rs, 4, 64); rs += __shfl_xor(rs, 8, 64);
        li[r] = rsum;
        if (fr == 0) {
            wA16[(lq * 8 + (0 ^ (lq & 7))) * 8 + 0] = f2b(ls);
            wA16[(lq * 8 + (4 ^ (lq & 7))) * 8 + 0] = f2b(rs);
        }
    }

    #pragma unroll
    for (int r = 0; r < 4; ++r) {
        int lq = wq0 + fq * 4 + r;
        #pragma unroll
        for (int nf = 0; nf < 8; ++nf) {
            int k = nf * 16 + fr;
            int cc = k >> 3;
            Pl[(lq * 16 + (cc ^ (lq & 7))) * 8 + (k & 7)] = f2b(s_[nf][r]);
        }
    }

    f32x4 O[4] = {};
    #pragma unroll
    for (int ks = 0; ks < 4; ++ks) {
        bf16x8 ap = *(const bf16x8*)(Pl + ((wq0 + fr) * 16 + ((ks * 4 + fq) ^ (fr & 7))) * 8);
        #pragma unroll
        for (int nf = 0; nf < 4; ++nf) {
            bf16x8 vf = *(const bf16x8*)(Vl + ((nf * 16 + fr) * 16 + ((ks * 4 + fq) ^ (fr & 7))) * 8);
            O[nf] = __builtin_amdgcn_mfma_f32_16x16x32_bf16(ap, vf, O[nf], 0, 0, 0);
        }
    }
    __syncthreads();   // (E1)

    #pragma unroll
    for (int p = 0; p < 2; ++p) {
        int s = tid + p * 256;
        int d = s >> 3, cs = s & 7;
        u16x8 vv;
        #pragma unroll
        for (int j = 0; j < 8; ++j) {
            int rd = cs * 8 + j;
            vv[j] = (rd < 33) ? f2b(rpe[rd * 128 + 64 + d]) : (u16)0;
        }
        *(u16x8*)(Vl + SWU(d, cs)) = vv;
    }
    __syncthreads();   // (E2)

    {
        bf16x8 aw0 = *(const bf16x8*)(wA16 + SWU(wq0 + fr, fq));
        bf16x8 aw1 = *(const bf16x8*)(wA16 + SWU(wq0 + fr, 4 + fq));
        #pragma unroll
        for (int nf = 0; nf < 4; ++nf) {
            bf16x8 b0 = *(const bf16x8*)(Vl + SWU(nf * 16 + fr, fq));
            bf16x8 b1 = *(const bf16x8*)(Vl + SWU(nf * 16 + fr, 4 + fq));
            O[nf] = __builtin_amdgcn_mfma_f32_16x16x32_bf16(aw0, b0, O[nf], 0, 0, 0);
            O[nf] = __builtin_amdgcn_mfma_f32_16x16x32_bf16(aw1, b1, O[nf], 0, 0, 0);
        }
    }
    float invl[4];
    #pragma unroll
    for (int r = 0; r < 4; ++r) invl[r] = 1.f / li[r];
    #pragma unroll
    for (int r = 0; r < 4; ++r) {
        int lq = wq0 + fq * 4 + r;
        #pragma unroll
        for (int nf = 0; nf < 4; ++nf)
            Pl[lq * 64 + nf * 16 + fr] = f2b(O[nf][r] * invl[r]);
    }
    __syncthreads();   // (E3)
    #pragma unroll
    for (int j = 0; j < 2; ++j) {
        int s = w * 128 + j * 64 + lane;
        int rr = s >> 3, c8 = s & 7;
        u16x8 vv = *(const u16x8*)(Pl + rr * 64 + c8 * 8);
        *(u16x8*)&cxh[((size_t)(b*NT + q0 + rr)) * 512 + h * NHD + c8 * 8] = vv;
    }
}

// ---------------------------------------------------------------------------
extern "C" void kernel_launch(void* const* d_in, const int* in_sizes, int n_in,
                              void* d_out, int out_size, void* d_ws, size_t ws_size,
                              hipStream_t stream) {
    const float* key   = (const float*)d_in[0];
    const float* value = (const float*)d_in[1];
    const float* query = (const float*)d_in[2];
    const int*   mask  = (const int*)d_in[3];
    const float* Wq  = (const float*)d_in[4];
    const float* bq  = (const float*)d_in[5];
    const float* Wk  = (const float*)d_in[6];
    const float* bk  = (const float*)d_in[7];
    const float* Wv  = (const float*)d_in[8];
    const float* bv  = (const float*)d_in[9];
    const float* Wcq = (const float*)d_in[10];
    const float* Wck = (const float*)d_in[11];
    const float* Wcv = (const float*)d_in[12];
    const float* Wgq = (const float*)d_in[13];
    const float* bgq = (const float*)d_in[14];
    const float* Wgk = (const float*)d_in[15];
    const float* bgk = (const float*)d_in[16];
    const float* Wgv = (const float*)d_in[17];
    const float* bgv = (const float*)d_in[18];
    const float* WmD = (const float*)d_in[19];
    const float* bmD = (const float*)d_in[20];
    const float* rpe = (const float*)d_in[21];
    const float* Wo  = (const float*)d_in[22];
    const float* bo  = (const float*)d_in[23];
    float* out = (float*)d_out;

    const size_t NTOK = (size_t)NB * NT;            // 8192
    const size_t NE   = NTOK * NSZ;                 // 4,194,304
    const size_t NW   = (size_t)NSZ * NSZ;          // 262,144

    u16* ws16 = (u16*)d_ws;
    u16* pkv  = ws16;                // (8192, 1536) q|k|v
    u16* wcat = pkv + NTOK * 1536;   // 3 x (512,512)
    u16* woh  = wcat + 3 * NW;
    u16* vpT  = woh + NW;            // (16*8*64, 512)
    u16* cxh  = vpT + NE;            // (8192, 512)
    float* mDb = (float*)(cxh + NE);
    float* WcT = mDb + NTOK;         // 3 x (5,512) fp32

    cvt4_bf16<<<dim3((unsigned)(NW/8/256), 4), 256, 0, stream>>>(
        Wq, Wk, Wv, Wo, wcat, wcat + NW, wcat + 2*NW, woh, (int)NW);
    wprep<<<dim3(10, 3), 256, 0, stream>>>(Wcq, Wck, Wcv, WcT);

    gemm_qkv<<<dim3(128, 4, 3), 256, 0, stream>>>(
        query, key, value, wcat, bq, bk, bv, pkv);

    conv_gate_all<<<(int)(NTOK / 4), 256, 0, stream>>>(
        key, pkv, vpT, WcT, Wgq, bgq, Wgk, bgk, Wgv, bgv, WmD, bmD, mDb);

    attn_mfma<<<dim3(128, 8), 256, 0, stream>>>(pkv, vpT, mDb, mask, rpe, cxh);

    gemm_out<<<dim3(128, 4), 256, 0, stream>>>(cxh, woh, bo, out, (int)NTOK, NSZ, NSZ);
}

// Round 18
// 107.782 us; speedup vs baseline: 2.0716x; 1.0025x over previous
//
#include <hip/hip_runtime.h>
#include <math.h>

#define NB 16
#define NT 512
#define NSZ 512
#define NH 8
#define NHD 64
#define MAXR 16

#define C_D0 6.3f
#define C_STD 1.4f
#define C_GAMMA 2.0f

#define NEGINF (-1e30f)
#define LOG2E 1.4426950408889634f
#define C1F   0.18033688011112042f   // 0.125 * log2(e)

typedef unsigned short u16;
typedef __attribute__((ext_vector_type(8))) short bf16x8;
typedef __attribute__((ext_vector_type(4))) float f32x4;
typedef __attribute__((ext_vector_type(8))) unsigned short u16x8;
typedef __attribute__((ext_vector_type(4))) unsigned short u16x4;

__device__ __forceinline__ u16 f2b(float f) {
    union { float f; unsigned int u; } c; c.f = f;
    unsigned int u = c.u + 0x7FFFu + ((c.u >> 16) & 1u);
    return (u16)(u >> 16);
}
__device__ __forceinline__ float b2f(u16 h) {
    union { unsigned int u; float f; } c; c.u = ((unsigned int)h) << 16;
    return c.f;
}

#if __has_builtin(__builtin_amdgcn_exp2f)
__device__ __forceinline__ float exp2_fast(float x) { return __builtin_amdgcn_exp2f(x); }
#else
__device__ __forceinline__ float exp2_fast(float x) { return exp2f(x); }
#endif

#define GL2LDS(gp, lp) __builtin_amdgcn_global_load_lds( \
    (const __attribute__((address_space(1))) void*)(gp), \
    (__attribute__((address_space(3))) void*)(lp), 16, 0, 0)

// swizzled u16-index of 16B chunk c in row r (8-chunk rows = 64 bf16)
#define SWU(r, c) ((((r) * 8) + ((c) ^ ((r) & 7))) * 8)
// swizzled u16-index for 16-chunk rows (128 bf16 per row)
#define SWU16(r, c) ((((r) * 16) + ((c) ^ ((r) & 7))) * 8)
// R18: GEMM-tile swizzle for 4-chunk rows (32 bf16 = 64 B). Bank period = 8
// rows; chunk ^= (row>>1)&3 spreads 16 consecutive rows over 8 bank-quads
// (2-way aliasing = free) instead of 2 (8-way conflict).
#define GSW(r)      (((r) >> 1) & 3)
#define GIDX(r, c)  ((((r) * 4) + ((c) ^ GSW(r))) * 8)

// ---------------------------------------------------------------------------
// fp32 -> bf16 convert (weights only)
// ---------------------------------------------------------------------------
__global__ __launch_bounds__(256) void cvt4_bf16(
    const float* __restrict__ s0, const float* __restrict__ s1,
    const float* __restrict__ s2, const float* __restrict__ s3,
    u16* __restrict__ d0, u16* __restrict__ d1,
    u16* __restrict__ d2, u16* __restrict__ d3, int n)
{
    const float* s; u16* d;
    switch (blockIdx.y) {
        case 0: s = s0; d = d0; break;
        case 1: s = s1; d = d1; break;
        case 2: s = s2; d = d2; break;
        default: s = s3; d = d3; break;
    }
    int i = (blockIdx.x * 256 + threadIdx.x) * 8;
    if (i >= n) return;
    float4 a = *(const float4*)&s[i];
    float4 b = *(const float4*)&s[i + 4];
    u16x8 v;
    v[0]=f2b(a.x); v[1]=f2b(a.y); v[2]=f2b(a.z); v[3]=f2b(a.w);
    v[4]=f2b(b.x); v[5]=f2b(b.y); v[6]=f2b(b.z); v[7]=f2b(b.w);
    *(u16x8*)&d[i] = v;
}

// ---------------------------------------------------------------------------
// Conv-weight transpose: Wc_z[512][5] -> WcT[z][5][512]  (fp32, one-time)
// ---------------------------------------------------------------------------
__global__ __launch_bounds__(256) void wprep(
    const float* __restrict__ Wcq, const float* __restrict__ Wck,
    const float* __restrict__ Wcv, float* __restrict__ WcT)
{
    const int z = blockIdx.y;
    const float* src = z == 0 ? Wcq : (z == 1 ? Wck : Wcv);
    int idx = blockIdx.x * 256 + threadIdx.x;
    if (idx >= 2560) return;
    int c = idx / 5, j = idx % 5;
    WcT[(size_t)z * 2560 + j * 512 + c] = src[idx];
}

// ---------------------------------------------------------------------------
// QKV projections, z-batched, 64x128 tile. R18: R17 pipeline + GIDX bank
// swizzle on both LDS tiles (A ds_write addr swizzled; W GL2LDS keeps linear
// dest with PRE-SWIZZLED global source chunk; frag reads use the same XOR).
// ---------------------------------------------------------------------------
__global__ __launch_bounds__(256) void gemm_qkv(
    const float* __restrict__ A0, const float* __restrict__ A1, const float* __restrict__ A2,
    const u16* __restrict__ Wc,
    const float* __restrict__ bq, const float* __restrict__ bk, const float* __restrict__ bv,
    u16* __restrict__ pkv)
{
    __shared__ u16 Al[2][64 * 32];     // 8 KB
    __shared__ u16 Wl[3][128 * 32];    // 24 KB
    const int z = blockIdx.z;
    const float* A = z == 0 ? A0 : (z == 1 ? A1 : A2);
    const u16* W = Wc + (size_t)z * NSZ * NSZ;
    const float* bias = z == 0 ? bq : (z == 1 ? bk : bv);
    const int tid = threadIdx.x;
    const int m0 = blockIdx.x * 64;
    const int n0 = blockIdx.y * 128;
    const int w = tid >> 6, lane = tid & 63;
    const int wm = (w >> 1) * 32, wn = (w & 1) * 64;
    const int fr = lane & 15, fk = lane >> 4;

    const int arow = tid >> 2, acb = tid & 3;
    const float* gA = &A[(size_t)(m0 + arow) * NSZ + acb * 8];
    const int aldst = GIDX(arow, acb);              // swizzled A LDS slot

    f32x4 acc[2][4] = {};

    // ---- prologue ----
    float4 t0a = *(const float4*)(gA);
    float4 t0b = *(const float4*)(gA + 4);
    #pragma unroll
    for (int p = 0; p < 2; ++p) {
        int s = tid + p * 256;
        int row = s >> 2, cb = s & 3;
        GL2LDS(&W[(size_t)(n0 + row) * NSZ + (cb ^ GSW(row)) * 8], &Wl[0][s * 8]);
    }
    #pragma unroll
    for (int p = 0; p < 2; ++p) {
        int s = tid + p * 256;
        int row = s >> 2, cb = s & 3;
        GL2LDS(&W[(size_t)(n0 + row) * NSZ + 32 + (cb ^ GSW(row)) * 8], &Wl[1][s * 8]);
    }
    float4 a0 = *(const float4*)(gA + 32);
    float4 a1 = *(const float4*)(gA + 36);
    {
        u16x8 v;
        v[0]=f2b(t0a.x); v[1]=f2b(t0a.y); v[2]=f2b(t0a.z); v[3]=f2b(t0a.w);
        v[4]=f2b(t0b.x); v[5]=f2b(t0b.y); v[6]=f2b(t0b.z); v[7]=f2b(t0b.w);
        *(u16x8*)&Al[0][aldst] = v;
    }
    asm volatile("s_waitcnt lgkmcnt(0)" ::: "memory");
    __builtin_amdgcn_sched_barrier(0);
    __builtin_amdgcn_s_barrier();

    float4 b0, b1;
    int wiC = 0;
    #pragma unroll 1
    for (int tt = 0; tt < 8; ++tt) {
        {   // even t = 2*tt
            const int t = 2 * tt;
            const int wiS = (wiC + 2 >= 3) ? wiC - 1 : wiC + 2;
            bf16x8 af[2], bfr[4];
            #pragma unroll
            for (int mf = 0; mf < 2; ++mf) {
                int row = wm + mf * 16 + fr;
                af[mf] = *(const bf16x8*)&Al[t & 1][GIDX(row, fk)];
            }
            #pragma unroll
            for (int nf = 0; nf < 4; ++nf) {
                int row = wn + nf * 16 + fr;
                bfr[nf] = *(const bf16x8*)&Wl[wiC][GIDX(row, fk)];
            }
            if (t < 14) {
                const int k0 = (t + 2) * 32;
                #pragma unroll
                for (int p = 0; p < 2; ++p) {
                    int s = tid + p * 256;
                    int row = s >> 2, cb = s & 3;
                    GL2LDS(&W[(size_t)(n0 + row) * NSZ + k0 + (cb ^ GSW(row)) * 8], &Wl[wiS][s * 8]);
                }
                b0 = *(const float4*)(gA + k0);
                b1 = *(const float4*)(gA + k0 + 4);
            }
            if (t < 15) {
                u16x8 v;
                v[0]=f2b(a0.x); v[1]=f2b(a0.y); v[2]=f2b(a0.z); v[3]=f2b(a0.w);
                v[4]=f2b(a1.x); v[5]=f2b(a1.y); v[6]=f2b(a1.z); v[7]=f2b(a1.w);
                *(u16x8*)&Al[(t + 1) & 1][aldst] = v;
            }
            #pragma unroll
            for (int mf = 0; mf < 2; ++mf)
                #pragma unroll
                for (int nf = 0; nf < 4; ++nf)
                    acc[mf][nf] = __builtin_amdgcn_mfma_f32_16x16x32_bf16(
                        af[mf], bfr[nf], acc[mf][nf], 0, 0, 0);
            asm volatile("s_waitcnt lgkmcnt(0)" ::: "memory");
            __builtin_amdgcn_sched_barrier(0);
            __builtin_amdgcn_s_barrier();
            wiC = (wiC + 1 >= 3) ? 0 : wiC + 1;
        }
        {   // odd t = 2*tt+1
            const int t = 2 * tt + 1;
            const int wiS = (wiC + 2 >= 3) ? wiC - 1 : wiC + 2;
            bf16x8 af[2], bfr[4];
            #pragma unroll
            for (int mf = 0; mf < 2; ++mf) {
                int row = wm + mf * 16 + fr;
                af[mf] = *(const bf16x8*)&Al[t & 1][GIDX(row, fk)];
            }
            #pragma unroll
            for (int nf = 0; nf < 4; ++nf) {
                int row = wn + nf * 16 + fr;
                bfr[nf] = *(const bf16x8*)&Wl[wiC][GIDX(row, fk)];
            }
            if (t < 14) {
                const int k0 = (t + 2) * 32;
                #pragma unroll
                for (int p = 0; p < 2; ++p) {
                    int s = tid + p * 256;
                    int row = s >> 2, cb = s & 3;
                    GL2LDS(&W[(size_t)(n0 + row) * NSZ + k0 + (cb ^ GSW(row)) * 8], &Wl[wiS][s * 8]);
                }
                a0 = *(const float4*)(gA + k0);
                a1 = *(const float4*)(gA + k0 + 4);
            }
            if (t < 15) {
                u16x8 v;
                v[0]=f2b(b0.x); v[1]=f2b(b0.y); v[2]=f2b(b0.z); v[3]=f2b(b0.w);
                v[4]=f2b(b1.x); v[5]=f2b(b1.y); v[6]=f2b(b1.z); v[7]=f2b(b1.w);
                *(u16x8*)&Al[(t + 1) & 1][aldst] = v;
            }
            #pragma unroll
            for (int mf = 0; mf < 2; ++mf)
                #pragma unroll
                for (int nf = 0; nf < 4; ++nf)
                    acc[mf][nf] = __builtin_amdgcn_mfma_f32_16x16x32_bf16(
                        af[mf], bfr[nf], acc[mf][nf], 0, 0, 0);
            asm volatile("s_waitcnt lgkmcnt(0)" ::: "memory");
            __builtin_amdgcn_sched_barrier(0);
            __builtin_amdgcn_s_barrier();
            wiC = (wiC + 1 >= 3) ? 0 : wiC + 1;
        }
    }
    #pragma unroll
    for (int mf = 0; mf < 2; ++mf) {
        #pragma unroll
        for (int nf = 0; nf < 4; ++nf) {
            int col = n0 + wn + nf * 16 + fr;
            float bvv = bias[col];
            #pragma unroll
            for (int r = 0; r < 4; ++r) {
                int rowg = m0 + wm + mf * 16 + fk * 4 + r;
                pkv[(size_t)rowg * 1536 + z * 512 + col] = f2b(acc[mf][nf][r] + bvv);
            }
        }
    }
}

// ---------------------------------------------------------------------------
// Output projection (fp32 out). R17 3-buffer counted-vmcnt + R18 GIDX swizzle
// (both operands GL2LDS: linear dest, pre-swizzled global source).
// ---------------------------------------------------------------------------
__global__ __launch_bounds__(256) void gemm_out(
    const u16* __restrict__ A, const u16* __restrict__ W,
    const float* __restrict__ bias, float* __restrict__ Cout, int M, int N, int K)
{
    __shared__ u16 Al[3][64 * 32];     // 12 KB
    __shared__ u16 Bl[3][128 * 32];    // 24 KB
    const int tid = threadIdx.x;
    const int m0 = blockIdx.x * 64;
    const int n0 = blockIdx.y * 128;
    const int w = tid >> 6, lane = tid & 63;
    const int wm = (w >> 1) * 32, wn = (w & 1) * 64;
    const int fr = lane & 15, fk = lane >> 4;

    f32x4 acc[2][4] = {};

    #pragma unroll
    for (int t0 = 0; t0 < 2; ++t0) {
        int k0 = t0 * 32;
        {
            int row = tid >> 2, cb = tid & 3;
            GL2LDS(&A[(size_t)(m0 + row) * K + k0 + (cb ^ GSW(row)) * 8], &Al[t0][tid * 8]);
        }
        #pragma unroll
        for (int p = 0; p < 2; ++p) {
            int s = tid + p * 256;
            int r2 = s >> 2, c2 = s & 3;
            GL2LDS(&W[(size_t)(n0 + r2) * K + k0 + (c2 ^ GSW(r2)) * 8], &Bl[t0][s * 8]);
        }
    }

    int cur = 0;
    #pragma unroll 1
    for (int t = 0; t < 16; ++t) {
        if (t < 15) asm volatile("s_waitcnt vmcnt(3)" ::: "memory");
        else        asm volatile("s_waitcnt vmcnt(0)" ::: "memory");
        __builtin_amdgcn_sched_barrier(0);
        __builtin_amdgcn_s_barrier();

        bf16x8 af[2], bfr[4];
        #pragma unroll
        for (int mf = 0; mf < 2; ++mf) {
            int row = wm + mf * 16 + fr;
            af[mf] = *(const bf16x8*)&Al[cur][GIDX(row, fk)];
        }
        #pragma unroll
        for (int nf = 0; nf < 4; ++nf) {
            int row = wn + nf * 16 + fr;
            bfr[nf] = *(const bf16x8*)&Bl[cur][GIDX(row, fk)];
        }

        if (t < 14) {
            const int k0 = (t + 2) * 32;
            const int stg = (cur + 2 >= 3) ? cur - 1 : cur + 2;
            {
                int row = tid >> 2, cb = tid & 3;
                GL2LDS(&A[(size_t)(m0 + row) * K + k0 + (cb ^ GSW(row)) * 8], &Al[stg][tid * 8]);
            }
            #pragma unroll
            for (int p = 0; p < 2; ++p) {
                int s = tid + p * 256;
                int r2 = s >> 2, c2 = s & 3;
                GL2LDS(&W[(size_t)(n0 + r2) * K + k0 + (c2 ^ GSW(r2)) * 8], &Bl[stg][s * 8]);
            }
        }
        #pragma unroll
        for (int mf = 0; mf < 2; ++mf)
            #pragma unroll
            for (int nf = 0; nf < 4; ++nf)
                acc[mf][nf] = __builtin_amdgcn_mfma_f32_16x16x32_bf16(
                    af[mf], bfr[nf], acc[mf][nf], 0, 0, 0);
        cur = (cur + 1 >= 3) ? 0 : cur + 1;
    }
    #pragma unroll
    for (int mf = 0; mf < 2; ++mf) {
        #pragma unroll
        for (int nf = 0; nf < 4; ++nf) {
            int col = n0 + wn + nf * 16 + fr;
            float bv = bias[col];
            #pragma unroll
            for (int r = 0; r < 4; ++r) {
                int rowg = m0 + wm + mf * 16 + fk * 4 + r;
                Cout[(size_t)rowg * N + col] = acc[mf][nf][r] + bv;
            }
        }
    }
}

// ---------------------------------------------------------------------------
// Fused 3x depthwise conv1d(k=5) + 3 scalar gates + mD + V-transpose
// (R16 proven version, unchanged).
// ---------------------------------------------------------------------------
__global__ void conv_gate_all(
    const float* __restrict__ xn, u16* __restrict__ pkv,
    u16* __restrict__ vpT,
    const float* __restrict__ WcT,
    const float* __restrict__ Wgq, const float* __restrict__ bgq,
    const float* __restrict__ Wgk, const float* __restrict__ bgk,
    const float* __restrict__ Wgv, const float* __restrict__ bgv,
    const float* __restrict__ WmD, const float* __restrict__ bmD,
    float* __restrict__ mD)
{
    __shared__ u16 lt[4][512];
    const int w = threadIdx.x >> 6, lane = threadIdx.x & 63;
    const int bt = blockIdx.x * 4 + w;
    const int b = bt >> 9, tpos = bt & (NT - 1);
    const int c0 = lane * 8;

    float x[5][8];
    #pragma unroll
    for (int j = 0; j < 5; ++j) {
        int tt = tpos + j - 2;
        if (tt >= 0 && tt < NT) {
            const float4* xp = (const float4*)&xn[((size_t)(b*NT + tt))*NSZ + c0];
            float4 u0 = xp[0], u1 = xp[1];
            x[j][0]=u0.x; x[j][1]=u0.y; x[j][2]=u0.z; x[j][3]=u0.w;
            x[j][4]=u1.x; x[j][5]=u1.y; x[j][6]=u1.z; x[j][7]=u1.w;
        } else {
            #pragma unroll
            for (int i = 0; i < 8; ++i) x[j][i] = 0.f;
        }
    }
    float aq[8] = {}, ak[8] = {}, av[8] = {};
    #pragma unroll
    for (int j = 0; j < 5; ++j) {
        const float* wq = &WcT[j * 512 + c0];
        const float* wk = &WcT[2560 + j * 512 + c0];
        const float* wv = &WcT[5120 + j * 512 + c0];
        float4 q0 = *(const float4*)wq, q1 = *(const float4*)(wq + 4);
        float4 k0 = *(const float4*)wk, k1 = *(const float4*)(wk + 4);
        float4 v0 = *(const float4*)wv, v1 = *(const float4*)(wv + 4);
        float wq8[8] = {q0.x,q0.y,q0.z,q0.w,q1.x,q1.y,q1.z,q1.w};
        float wk8[8] = {k0.x,k0.y,k0.z,k0.w,k1.x,k1.y,k1.z,k1.w};
        float wv8[8] = {v0.x,v0.y,v0.z,v0.w,v1.x,v1.y,v1.z,v1.w};
        #pragma unroll
        for (int i = 0; i < 8; ++i) {
            aq[i] += x[j][i] * wq8[i];
            ak[i] += x[j][i] * wk8[i];
            av[i] += x[j][i] * wv8[i];
        }
    }
    const size_t rb = (size_t)bt * 1536;
    u16x8 q8 = *(const u16x8*)&pkv[rb + c0];
    u16x8 k8 = *(const u16x8*)&pkv[rb + 512 + c0];
    u16x8 v8 = *(const u16x8*)&pkv[rb + 1024 + c0];

    float gql[8], gqh[8], gkl[8], gkh[8], gvl[8], gvh[8];
    {
        float4 a0 = *(const float4*)&Wgq[c0],      a1 = *(const float4*)&Wgq[c0 + 4];
        float4 a2 = *(const float4*)&Wgq[512 + c0], a3 = *(const float4*)&Wgq[512 + c0 + 4];
        gql[0]=a0.x;gql[1]=a0.y;gql[2]=a0.z;gql[3]=a0.w;gql[4]=a1.x;gql[5]=a1.y;gql[6]=a1.z;gql[7]=a1.w;
        gqh[0]=a2.x;gqh[1]=a2.y;gqh[2]=a2.z;gqh[3]=a2.w;gqh[4]=a3.x;gqh[5]=a3.y;gqh[6]=a3.z;gqh[7]=a3.w;
        float4 b0 = *(const float4*)&Wgk[c0],      b1 = *(const float4*)&Wgk[c0 + 4];
        float4 b2 = *(const float4*)&Wgk[512 + c0], b3 = *(const float4*)&Wgk[512 + c0 + 4];
        gkl[0]=b0.x;gkl[1]=b0.y;gkl[2]=b0.z;gkl[3]=b0.w;gkl[4]=b1.x;gkl[5]=b1.y;gkl[6]=b1.z;gkl[7]=b1.w;
        gkh[0]=b2.x;gkh[1]=b2.y;gkh[2]=b2.z;gkh[3]=b2.w;gkh[4]=b3.x;gkh[5]=b3.y;gkh[6]=b3.z;gkh[7]=b3.w;
        float4 c0v = *(const float4*)&Wgv[c0],      c1v = *(const float4*)&Wgv[c0 + 4];
        float4 c2v = *(const float4*)&Wgv[512 + c0], c3v = *(const float4*)&Wgv[512 + c0 + 4];
        gvl[0]=c0v.x;gvl[1]=c0v.y;gvl[2]=c0v.z;gvl[3]=c0v.w;gvl[4]=c1v.x;gvl[5]=c1v.y;gvl[6]=c1v.z;gvl[7]=c1v.w;
        gvh[0]=c2v.x;gvh[1]=c2v.y;gvh[2]=c2v.z;gvh[3]=c2v.w;gvh[4]=c3v.x;gvh[5]=c3v.y;gvh[6]=c3v.z;gvh[7]=c3v.w;
    }
    float sq = 0.f, sk = 0.f, sv = 0.f;
    #pragma unroll
    for (int i = 0; i < 8; ++i) {
        sq += b2f(q8[i]) * gql[i] + aq[i] * gqh[i];
        sk += b2f(k8[i]) * gkl[i] + ak[i] * gkh[i];
        sv += b2f(v8[i]) * gvl[i] + av[i] * gvh[i];
    }
    #pragma unroll
    for (int o = 1; o < 64; o <<= 1) {
        sq += __shfl_xor(sq, o, 64);
        sk += __shfl_xor(sk, o, 64);
        sv += __shfl_xor(sv, o, 64);
    }
    float gq = 1.f / (1.f + expf(-(sq + bgq[0])));
    float gk = 1.f / (1.f + expf(-(sk + bgk[0])));
    float gv = 1.f / (1.f + expf(-(sv + bgv[0])));

    float wm8[8];
    {
        float4 m0 = *(const float4*)&WmD[c0], m1 = *(const float4*)&WmD[c0 + 4];
        wm8[0]=m0.x;wm8[1]=m0.y;wm8[2]=m0.z;wm8[3]=m0.w;wm8[4]=m1.x;wm8[5]=m1.y;wm8[6]=m1.z;wm8[7]=m1.w;
    }
    u16x8 oq8, ok8, ov8;
    float smd = 0.f;
    #pragma unroll
    for (int i = 0; i < 8; ++i) {
        float oq = (1.f - gq) * b2f(q8[i]) + gq * aq[i];
        oq8[i] = f2b(oq);
        ok8[i] = f2b((1.f - gk) * b2f(k8[i]) + gk * ak[i]);
        ov8[i] = f2b((1.f - gv) * b2f(v8[i]) + gv * av[i]);
        smd += oq * wm8[i];
    }
    *(u16x8*)&pkv[rb + c0]       = oq8;
    *(u16x8*)&pkv[rb + 512 + c0] = ok8;
    *(u16x8*)&lt[w][c0] = ov8;
    #pragma unroll
    for (int o = 1; o < 64; o <<= 1) smd += __shfl_xor(smd, o, 64);
    if (lane == 0)
        mD[bt] = C_D0 + 2.f * C_STD * tanhf((smd + bmD[0]) / C_GAMMA);

    __syncthreads();
    const int t0g = (blockIdx.x * 4) & (NT - 1);
    const int b0g = (blockIdx.x * 4) >> 9;
    #pragma unroll
    for (int p2 = 0; p2 < 2; ++p2) {
        int c = threadIdx.x + p2 * 256;
        u16x4 o4;
        o4[0] = lt[0][c]; o4[1] = lt[1][c]; o4[2] = lt[2][c]; o4[3] = lt[3][c];
        *(u16x4*)&vpT[((size_t)(b0g * 512 + c)) * NT + t0g] = o4;
    }
}

// ---------------------------------------------------------------------------
// MFMA flash attention — R14 single-pass version (unchanged).
// ---------------------------------------------------------------------------
__global__ __launch_bounds__(256) void attn_mfma(
    const u16* __restrict__ pkv, const u16* __restrict__ vpT,
    const float* __restrict__ mD, const int* __restrict__ mask,
    const float* __restrict__ rpe, u16* __restrict__ cxh)
{
    __shared__ __align__(16) char smem[70400];
    u16*  Ql    = (u16*)(smem);
    u16*  Kl    = (u16*)(smem + 8192);
    u16*  Vl    = (u16*)(smem + 24576);
    u16*  Pl    = (u16*)(smem + 40960);
    u16*  rpk   = (u16*)(smem + 40960);
    u16*  wA16  = (u16*)(smem + 57344);
    u16*  qdrl  = (u16*)(smem + 65536);
    float* inv2s= (float*)(smem + 70144);

    const int tid  = threadIdx.x;
    const int lane = tid & 63;
    const int w    = tid >> 6;
    const int wq0  = w * 16;
    const int fr   = lane & 15;
    const int fq   = lane >> 4;
    const int b    = blockIdx.x >> 3;
    const int h    = blockIdx.x & 7;
    const int q0   = blockIdx.y * 64;

    const size_t qbase  = ((size_t)(b*NT + q0)) * 1536 + h * NHD;
    const size_t kbaseg = ((size_t)b * NT) * 1536 + 512 + h * NHD;
    const size_t vbaseg = ((size_t)((b*NH + h) * NHD)) * NT;

    int Lm = 512;
    #pragma unroll
    for (int j = 0; j < 8; ++j) {
        if (mask[b * NT + lane + 64 * j]) Lm = min(Lm, lane + 64 * j);
    }
    #pragma unroll
    for (int o = 1; o < 64; o <<= 1) Lm = min(Lm, __shfl_xor(Lm, o, 64));
    const int L = Lm;
    const int w0 = max(0, min(q0 - 32, L - 128));

    #pragma unroll
    for (int p = 0; p < 2; ++p) {
        int s = tid + p * 256;
        int r = s >> 3, c = s & 7;
        u16x8 v = *(const u16x8*)(pkv + qbase + (size_t)r * 1536 + c * 8);
        *(u16x8*)(Ql + SWU(r, c)) = v;
    }
    #pragma unroll
    for (int p = 0; p < 4; ++p) {
        int s = tid + p * 256;
        int r = s >> 3, c = s & 7;
        u16x8 v = *(const u16x8*)(pkv + kbaseg + (size_t)(w0 + r) * 1536 + c * 8);
        *(u16x8*)(Kl + SWU(r, c)) = v;
    }
    #pragma unroll
    for (int p = 0; p < 4; ++p) {
        int s = tid + p * 256;
        int d = s >> 4, cc = s & 15;
        u16x8 v = *(const u16x8*)(vpT + vbaseg + (size_t)d * NT + w0 + cc * 8);
        *(u16x8*)(Vl + SWU16(d, cc)) = v;
    }
    for (int idx = tid; idx < 264; idx += 256) {
        int r = idx >> 3, c = idx & 7;
        float4 f0 = *(const float4*)&rpe[r * 128 + c * 8];
        float4 f1 = *(const float4*)&rpe[r * 128 + c * 8 + 4];
        u16x8 vv;
        vv[0]=f2b(f0.x); vv[1]=f2b(f0.y); vv[2]=f2b(f0.z); vv[3]=f2b(f0.w);
        vv[4]=f2b(f1.x); vv[5]=f2b(f1.y); vv[6]=f2b(f1.z); vv[7]=f2b(f1.w);
        *(u16x8*)(rpk + SWU(r, c)) = vv;
    }
    if (tid < 120) {
        u16x8 vv = {0,0,0,0,0,0,0,0};
        *(u16x8*)(rpk + (((33 + (tid >> 3)) * 8) + (tid & 7)) * 8) = vv;
    }
    {
        u16x8 z = {0,0,0,0,0,0,0,0};
        #pragma unroll
        for (int p = 0; p < 2; ++p) *(u16x8*)(wA16 + (tid + p * 256) * 8) = z;
    }
    if (tid < 64) {
        float md = mD[b * NT + q0 + tid];
        inv2s[tid] = 2.f * LOG2E / (md * md);
    }
    __syncthreads();                        // (P0)

    bf16x8 aq0 = *(const bf16x8*)(Ql + SWU(wq0 + fr, fq));
    bf16x8 aq1 = *(const bf16x8*)(Ql + SWU(wq0 + fr, 4 + fq));

    {
        f32x4 qd[3] = {};
        #pragma unroll
        for (int nf = 0; nf < 3; ++nf) {
            bf16x8 b0 = *(const bf16x8*)(rpk + SWU(nf * 16 + fr, fq));
            bf16x8 b1 = *(const bf16x8*)(rpk + SWU(nf * 16 + fr, 4 + fq));
            qd[nf] = __builtin_amdgcn_mfma_f32_16x16x32_bf16(aq0, b0, qd[nf], 0, 0, 0);
            qd[nf] = __builtin_amdgcn_mfma_f32_16x16x32_bf16(aq1, b1, qd[nf], 0, 0, 0);
        }
        #pragma unroll
        for (int nf = 0; nf < 3; ++nf) {
            int rd = nf * 16 + fr;
            if (rd < 33) {
                #pragma unroll
                for (int r = 0; r < 4; ++r)
                    qdrl[(wq0 + fq * 4 + r) * 36 + rd] = f2b(qd[nf][r]);
            }
        }
    }
    __syncthreads();                        // (P1)

    f32x4 s_[8] = {};
    #pragma unroll
    for (int nf = 0; nf < 8; ++nf) {
        bf16x8 b0 = *(const bf16x8*)(Kl + SWU(nf * 16 + fr, fq));
        bf16x8 b1 = *(const bf16x8*)(Kl + SWU(nf * 16 + fr, 4 + fq));
        s_[nf] = __builtin_amdgcn_mfma_f32_16x16x32_bf16(aq0, b0, s_[nf], 0, 0, 0);
        s_[nf] = __builtin_amdgcn_mfma_f32_16x16x32_bf16(aq1, b1, s_[nf], 0, 0, 0);
    }

    float li[4];
    #pragma unroll
    for (int r = 0; r < 4; ++r) {
        const int lq = wq0 + fq * 4 + r;
        const int qg = q0 + lq;
        const float iv = inv2s[lq];
        float sc[8];
        float mx = NEGINF;
        #pragma unroll
        for (int nf = 0; nf < 8; ++nf) {
            const int kg = w0 + nf * 16 + fr;
            float v;
            if (kg >= L) v = NEGINF;
            else {
                int rd = min(max(kg - qg, -MAXR), MAXR) + MAXR;
                float qr = b2f(qdrl[lq * 36 + rd]);
                float fd = (float)(qg - kg);
                v = (s_[nf][r] + qr) * C1F - fd * fd * iv;
            }
            sc[nf] = v;
            mx = fmaxf(mx, v);
        }
        mx = fmaxf(mx, __shfl_xor(mx, 1, 64));
        mx = fmaxf(mx, __shfl_xor(mx, 2, 64));
        mx = fmaxf(mx, __shfl_xor(mx, 4, 64));
        mx = fmaxf(mx, __shfl_xor(mx, 8, 64));
        float rsum = 0.f, ls = 0.f, rs = 0.f;
        #pragma unroll
        for (int nf = 0; nf < 8; ++nf) {
            const int kg = w0 + nf * 16 + fr;
            float pv = exp2_fast(sc[nf] - mx);
            s_[nf][r] = pv;
            rsum += pv;
            int d = kg - qg;
            if (d <= -MAXR) ls += pv;
            else if (d >= MAXR) rs += pv;
            else {
                int bkt = d + MAXR;
                wA16[(lq * 8 + ((bkt >> 3) ^ (lq & 7))) * 8 + (bkt & 7)] = f2b(pv);
            }
        }
        rsum += __shfl_xor(rsum, 1, 64); rsum += __shfl_xor(rsum, 2, 64);
        rsum += __shfl_xor(rsum, 4, 64); rsum += __shfl_xor(rsum, 8, 64);
        ls += __shfl_xor(ls, 1, 64); ls += __shfl_xor(ls, 2, 64);
        ls += __shfl_xor(ls, 4, 64); ls += __shfl_xor(ls, 8, 64);
        rs += __shfl_xor(rs, 1, 64); rs += __shfl_xor(rs, 2, 64);
        rs += __shfl_xor(rs, 4, 64); rs += __shfl_xor(rs, 8, 64);
        li[r] = rsum;
        if (fr == 0) {
            wA16[(lq * 8 + (0 ^ (lq & 7))) * 8 + 0] = f2b(ls);
            wA16[(lq * 8 + (4 ^ (lq & 7))) * 8 + 0] = f2b(rs);
        }
    }

    #pragma unroll
    for (int r = 0; r < 4; ++r) {
        int lq = wq0 + fq * 4 + r;
        #pragma unroll
        for (int nf = 0; nf < 8; ++nf) {
            int k = nf * 16 + fr;
            int cc = k >> 3;
            Pl[(lq * 16 + (cc ^ (lq & 7))) * 8 + (k & 7)] = f2b(s_[nf][r]);
        }
    }

    f32x4 O[4] = {};
    #pragma unroll
    for (int ks = 0; ks < 4; ++ks) {
        bf16x8 ap = *(const bf16x8*)(Pl + ((wq0 + fr) * 16 + ((ks * 4 + fq) ^ (fr & 7))) * 8);
        #pragma unroll
        for (int nf = 0; nf < 4; ++nf) {
            bf16x8 vf = *(const bf16x8*)(Vl + ((nf * 16 + fr) * 16 + ((ks * 4 + fq) ^ (fr & 7))) * 8);
            O[nf] = __builtin_amdgcn_mfma_f32_16x16x32_bf16(ap, vf, O[nf], 0, 0, 0);
        }
    }
    __syncthreads();   // (E1)

    #pragma unroll
    for (int p = 0; p < 2; ++p) {
        int s = tid + p * 256;
        int d = s >> 3, cs = s & 7;
        u16x8 vv;
        #pragma unroll
        for (int j = 0; j < 8; ++j) {
            int rd = cs * 8 + j;
            vv[j] = (rd < 33) ? f2b(rpe[rd * 128 + 64 + d]) : (u16)0;
        }
        *(u16x8*)(Vl + SWU(d, cs)) = vv;
    }
    __syncthreads();   // (E2)

    {
        bf16x8 aw0 = *(const bf16x8*)(wA16 + SWU(wq0 + fr, fq));
        bf16x8 aw1 = *(const bf16x8*)(wA16 + SWU(wq0 + fr, 4 + fq));
        #pragma unroll
        for (int nf = 0; nf < 4; ++nf) {
            bf16x8 b0 = *(const bf16x8*)(Vl + SWU(nf * 16 + fr, fq));
            bf16x8 b1 = *(const bf16x8*)(Vl + SWU(nf * 16 + fr, 4 + fq));
            O[nf] = __builtin_amdgcn_mfma_f32_16x16x32_bf16(aw0, b0, O[nf], 0, 0, 0);
            O[nf] = __builtin_amdgcn_mfma_f32_16x16x32_bf16(aw1, b1, O[nf], 0, 0, 0);
        }
    }
    float invl[4];
    #pragma unroll
    for (int r = 0; r < 4; ++r) invl[r] = 1.f / li[r];
    #pragma unroll
    for (int r = 0; r < 4; ++r) {
        int lq = wq0 + fq * 4 + r;
        #pragma unroll
        for (int nf = 0; nf < 4; ++nf)
            Pl[lq * 64 + nf * 16 + fr] = f2b(O[nf][r] * invl[r]);
    }
    __syncthreads();   // (E3)
    #pragma unroll
    for (int j = 0; j < 2; ++j) {
        int s = w * 128 + j * 64 + lane;
        int rr = s >> 3, c8 = s & 7;
        u16x8 vv = *(const u16x8*)(Pl + rr * 64 + c8 * 8);
        *(u16x8*)&cxh[((size_t)(b*NT + q0 + rr)) * 512 + h * NHD + c8 * 8] = vv;
    }
}

// ---------------------------------------------------------------------------
extern "C" void kernel_launch(void* const* d_in, const int* in_sizes, int n_in,
                              void* d_out, int out_size, void* d_ws, size_t ws_size,
                              hipStream_t stream) {
    const float* key   = (const float*)d_in[0];
    const float* value = (const float*)d_in[1];
    const float* query = (const float*)d_in[2];
    const int*   mask  = (const int*)d_in[3];
    const float* Wq  = (const float*)d_in[4];
    const float* bq  = (const float*)d_in[5];
    const float* Wk  = (const float*)d_in[6];
    const float* bk  = (const float*)d_in[7];
    const float* Wv  = (const float*)d_in[8];
    const float* bv  = (const float*)d_in[9];
    const float* Wcq = (const float*)d_in[10];
    const float* Wck = (const float*)d_in[11];
    const float* Wcv = (const float*)d_in[12];
    const float* Wgq = (const float*)d_in[13];
    const float* bgq = (const float*)d_in[14];
    const float* Wgk = (const float*)d_in[15];
    const float* bgk = (const float*)d_in[16];
    const float* Wgv = (const float*)d_in[17];
    const float* bgv = (const float*)d_in[18];
    const float* WmD = (const float*)d_in[19];
    const float* bmD = (const float*)d_in[20];
    const float* rpe = (const float*)d_in[21];
    const float* Wo  = (const float*)d_in[22];
    const float* bo  = (const float*)d_in[23];
    float* out = (float*)d_out;

    const size_t NTOK = (size_t)NB * NT;            // 8192
    const size_t NE   = NTOK * NSZ;                 // 4,194,304
    const size_t NW   = (size_t)NSZ * NSZ;          // 262,144

    u16* ws16 = (u16*)d_ws;
    u16* pkv  = ws16;                // (8192, 1536) q|k|v
    u16* wcat = pkv + NTOK * 1536;   // 3 x (512,512)
    u16* woh  = wcat + 3 * NW;
    u16* vpT  = woh + NW;            // (16*8*64, 512)
    u16* cxh  = vpT + NE;            // (8192, 512)
    float* mDb = (float*)(cxh + NE);
    float* WcT = mDb + NTOK;         // 3 x (5,512) fp32

    cvt4_bf16<<<dim3((unsigned)(NW/8/256), 4), 256, 0, stream>>>(
        Wq, Wk, Wv, Wo, wcat, wcat + NW, wcat + 2*NW, woh, (int)NW);
    wprep<<<dim3(10, 3), 256, 0, stream>>>(Wcq, Wck, Wcv, WcT);

    gemm_qkv<<<dim3(128, 4, 3), 256, 0, stream>>>(
        query, key, value, wcat, bq, bk, bv, pkv);

    conv_gate_all<<<(int)(NTOK / 4), 256, 0, stream>>>(
        key, pkv, vpT, WcT, Wgq, bgq, Wgk, bgk, Wgv, bgv, WmD, bmD, mDb);

    attn_mfma<<<dim3(128, 8), 256, 0, stream>>>(pkv, vpT, mDb, mask, rpe, cxh);

    gemm_out<<<dim3(128, 4), 256, 0, stream>>>(cxh, woh, bo, out, (int)NTOK, NSZ, NSZ);
}

// Round 19
// 107.610 us; speedup vs baseline: 2.0749x; 1.0016x over previous
//
#include <hip/hip_runtime.h>
#include <math.h>

#define NB 16
#define NT 512
#define NSZ 512
#define NH 8
#define NHD 64
#define MAXR 16

#define C_D0 6.3f
#define C_STD 1.4f
#define C_GAMMA 2.0f

#define NEGINF (-1e30f)
#define LOG2E 1.4426950408889634f
#define C1F   0.18033688011112042f   // 0.125 * log2(e)

typedef unsigned short u16;
typedef __attribute__((ext_vector_type(8))) short bf16x8;
typedef __attribute__((ext_vector_type(4))) float f32x4;
typedef __attribute__((ext_vector_type(8))) unsigned short u16x8;
typedef __attribute__((ext_vector_type(4))) unsigned short u16x4;

__device__ __forceinline__ u16 f2b(float f) {
    union { float f; unsigned int u; } c; c.f = f;
    unsigned int u = c.u + 0x7FFFu + ((c.u >> 16) & 1u);
    return (u16)(u >> 16);
}
__device__ __forceinline__ float b2f(u16 h) {
    union { unsigned int u; float f; } c; c.u = ((unsigned int)h) << 16;
    return c.f;
}

#if __has_builtin(__builtin_amdgcn_exp2f)
__device__ __forceinline__ float exp2_fast(float x) { return __builtin_amdgcn_exp2f(x); }
#else
__device__ __forceinline__ float exp2_fast(float x) { return exp2f(x); }
#endif

#define GL2LDS(gp, lp) __builtin_amdgcn_global_load_lds( \
    (const __attribute__((address_space(1))) void*)(gp), \
    (__attribute__((address_space(3))) void*)(lp), 16, 0, 0)

// swizzled u16-index of 16B chunk c in row r (8-chunk rows = 64 bf16)
#define SWU(r, c) ((((r) * 8) + ((c) ^ ((r) & 7))) * 8)
// swizzled u16-index for 16-chunk rows (128 bf16 per row)
#define SWU16(r, c) ((((r) * 16) + ((c) ^ ((r) & 7))) * 8)

// ---------------------------------------------------------------------------
// fp32 -> bf16 convert (weights only)
// ---------------------------------------------------------------------------
__global__ __launch_bounds__(256) void cvt4_bf16(
    const float* __restrict__ s0, const float* __restrict__ s1,
    const float* __restrict__ s2, const float* __restrict__ s3,
    u16* __restrict__ d0, u16* __restrict__ d1,
    u16* __restrict__ d2, u16* __restrict__ d3, int n)
{
    const float* s; u16* d;
    switch (blockIdx.y) {
        case 0: s = s0; d = d0; break;
        case 1: s = s1; d = d1; break;
        case 2: s = s2; d = d2; break;
        default: s = s3; d = d3; break;
    }
    int i = (blockIdx.x * 256 + threadIdx.x) * 8;
    if (i >= n) return;
    float4 a = *(const float4*)&s[i];
    float4 b = *(const float4*)&s[i + 4];
    u16x8 v;
    v[0]=f2b(a.x); v[1]=f2b(a.y); v[2]=f2b(a.z); v[3]=f2b(a.w);
    v[4]=f2b(b.x); v[5]=f2b(b.y); v[6]=f2b(b.z); v[7]=f2b(b.w);
    *(u16x8*)&d[i] = v;
}

// ---------------------------------------------------------------------------
// Conv-weight transpose: Wc_z[512][5] -> WcT[z][5][512]  (fp32, one-time)
// ---------------------------------------------------------------------------
__global__ __launch_bounds__(256) void wprep(
    const float* __restrict__ Wcq, const float* __restrict__ Wck,
    const float* __restrict__ Wcv, float* __restrict__ WcT)
{
    const int z = blockIdx.y;
    const float* src = z == 0 ? Wcq : (z == 1 ? Wck : Wcv);
    int idx = blockIdx.x * 256 + threadIdx.x;
    if (idx >= 2560) return;
    int c = idx / 5, j = idx % 5;
    WcT[(size_t)z * 2560 + j * 512 + c] = src[idx];
}

// ---------------------------------------------------------------------------
// QKV projections, z-batched, 64x128 tile. R19: BK=64 — 8 K-steps x 16 MFMA
// per wave (was 16 x 8): halves the barrier count. 2-phase dbuf (48 KB),
// one __syncthreads per step (R15/R16-proven shape). SWU swizzle (rows =
// 64 bf16 = 8 chunks): A ds_write swizzled addr; W GL2LDS linear dest +
// pre-swizzled global source; frag reads same XOR. k-ascending MFMA order
// -> bit-identical accumulation.
// ---------------------------------------------------------------------------
__global__ __launch_bounds__(256) void gemm_qkv(
    const float* __restrict__ A0, const float* __restrict__ A1, const float* __restrict__ A2,
    const u16* __restrict__ Wc,
    const float* __restrict__ bq, const float* __restrict__ bk, const float* __restrict__ bv,
    u16* __restrict__ pkv)
{
    __shared__ u16 Al[2][64 * 64];    // 16 KB
    __shared__ u16 Wl[2][128 * 64];   // 32 KB
    const int z = blockIdx.z;
    const float* A = z == 0 ? A0 : (z == 1 ? A1 : A2);
    const u16* W = Wc + (size_t)z * NSZ * NSZ;
    const float* bias = z == 0 ? bq : (z == 1 ? bk : bv);
    const int tid = threadIdx.x;
    const int m0 = blockIdx.x * 64;
    const int n0 = blockIdx.y * 128;
    const int w = tid >> 6, lane = tid & 63;
    const int wm = (w >> 1) * 32, wn = (w & 1) * 64;
    const int fr = lane & 15, fk = lane >> 4;

    f32x4 acc[2][4] = {};

    // ---- prologue: stage t=0 ----
    float4 na[2], nb[2];
    #pragma unroll
    for (int p = 0; p < 2; ++p) {
        int s = tid + p * 256;
        int row = s >> 3, ch = s & 7;
        const float* ga = &A[(size_t)(m0 + row) * NSZ + ch * 8];
        na[p] = *(const float4*)ga;
        nb[p] = *(const float4*)(ga + 4);
    }
    #pragma unroll
    for (int p = 0; p < 4; ++p) {
        int s = tid + p * 256;
        int row = s >> 3, ch = s & 7;
        GL2LDS(&W[(size_t)(n0 + row) * NSZ + (ch ^ (row & 7)) * 8], &Wl[0][s * 8]);
    }
    #pragma unroll
    for (int p = 0; p < 2; ++p) {
        int s = tid + p * 256;
        int row = s >> 3, ch = s & 7;
        u16x8 v;
        v[0]=f2b(na[p].x); v[1]=f2b(na[p].y); v[2]=f2b(na[p].z); v[3]=f2b(na[p].w);
        v[4]=f2b(nb[p].x); v[5]=f2b(nb[p].y); v[6]=f2b(nb[p].z); v[7]=f2b(nb[p].w);
        *(u16x8*)&Al[0][SWU(row, ch)] = v;
    }
    __syncthreads();

    #pragma unroll 1
    for (int t = 0; t < 8; ++t) {
        const int cur = t & 1, nxt = cur ^ 1;
        const bool pre = (t < 7);
        if (pre) {
            const int k0 = (t + 1) * 64;
            #pragma unroll
            for (int p = 0; p < 2; ++p) {
                int s = tid + p * 256;
                int row = s >> 3, ch = s & 7;
                const float* ga = &A[(size_t)(m0 + row) * NSZ + k0 + ch * 8];
                na[p] = *(const float4*)ga;
                nb[p] = *(const float4*)(ga + 4);
            }
            #pragma unroll
            for (int p = 0; p < 4; ++p) {
                int s = tid + p * 256;
                int row = s >> 3, ch = s & 7;
                GL2LDS(&W[(size_t)(n0 + row) * NSZ + k0 + (ch ^ (row & 7)) * 8], &Wl[nxt][s * 8]);
            }
        }
        // ---- compute on buf[cur]: 2 k-slices x (2 mf x 4 nf) ----
        #pragma unroll
        for (int ks = 0; ks < 2; ++ks) {
            bf16x8 af[2], bfr[4];
            #pragma unroll
            for (int mf = 0; mf < 2; ++mf)
                af[mf] = *(const bf16x8*)&Al[cur][SWU(wm + mf * 16 + fr, ks * 4 + fk)];
            #pragma unroll
            for (int nf = 0; nf < 4; ++nf)
                bfr[nf] = *(const bf16x8*)&Wl[cur][SWU(wn + nf * 16 + fr, ks * 4 + fk)];
            #pragma unroll
            for (int mf = 0; mf < 2; ++mf)
                #pragma unroll
                for (int nf = 0; nf < 4; ++nf)
                    acc[mf][nf] = __builtin_amdgcn_mfma_f32_16x16x32_bf16(
                        af[mf], bfr[nf], acc[mf][nf], 0, 0, 0);
        }
        // ---- A(t+1) cvt + ds_write (after compute; load wait lands here) ----
        if (pre) {
            #pragma unroll
            for (int p = 0; p < 2; ++p) {
                int s = tid + p * 256;
                int row = s >> 3, ch = s & 7;
                u16x8 v;
                v[0]=f2b(na[p].x); v[1]=f2b(na[p].y); v[2]=f2b(na[p].z); v[3]=f2b(na[p].w);
                v[4]=f2b(nb[p].x); v[5]=f2b(nb[p].y); v[6]=f2b(nb[p].z); v[7]=f2b(nb[p].w);
                *(u16x8*)&Al[nxt][SWU(row, ch)] = v;
            }
        }
        __syncthreads();
    }
    #pragma unroll
    for (int mf = 0; mf < 2; ++mf) {
        #pragma unroll
        for (int nf = 0; nf < 4; ++nf) {
            int col = n0 + wn + nf * 16 + fr;
            float bvv = bias[col];
            #pragma unroll
            for (int r = 0; r < 4; ++r) {
                int rowg = m0 + wm + mf * 16 + fk * 4 + r;
                pkv[(size_t)rowg * 1536 + z * 512 + col] = f2b(acc[mf][nf][r] + bvv);
            }
        }
    }
}

// ---------------------------------------------------------------------------
// Output projection (fp32 out). R19: BK=64, 2-phase dbuf (48 KB), both
// operands GL2LDS (linear dest, pre-swizzled source), one barrier/step.
// ---------------------------------------------------------------------------
__global__ __launch_bounds__(256) void gemm_out(
    const u16* __restrict__ A, const u16* __restrict__ W,
    const float* __restrict__ bias, float* __restrict__ Cout, int M, int N, int K)
{
    __shared__ u16 Al[2][64 * 64];    // 16 KB
    __shared__ u16 Bl[2][128 * 64];   // 32 KB
    const int tid = threadIdx.x;
    const int m0 = blockIdx.x * 64;
    const int n0 = blockIdx.y * 128;
    const int w = tid >> 6, lane = tid & 63;
    const int wm = (w >> 1) * 32, wn = (w & 1) * 64;
    const int fr = lane & 15, fk = lane >> 4;

    f32x4 acc[2][4] = {};

    // prologue: stage t=0
    #pragma unroll
    for (int p = 0; p < 2; ++p) {
        int s = tid + p * 256;
        int row = s >> 3, ch = s & 7;
        GL2LDS(&A[(size_t)(m0 + row) * K + (ch ^ (row & 7)) * 8], &Al[0][s * 8]);
    }
    #pragma unroll
    for (int p = 0; p < 4; ++p) {
        int s = tid + p * 256;
        int row = s >> 3, ch = s & 7;
        GL2LDS(&W[(size_t)(n0 + row) * K + (ch ^ (row & 7)) * 8], &Bl[0][s * 8]);
    }
    __syncthreads();

    #pragma unroll 1
    for (int t = 0; t < 8; ++t) {
        const int cur = t & 1, nxt = cur ^ 1;
        if (t < 7) {
            const int k0 = (t + 1) * 64;
            #pragma unroll
            for (int p = 0; p < 2; ++p) {
                int s = tid + p * 256;
                int row = s >> 3, ch = s & 7;
                GL2LDS(&A[(size_t)(m0 + row) * K + k0 + (ch ^ (row & 7)) * 8], &Al[nxt][s * 8]);
            }
            #pragma unroll
            for (int p = 0; p < 4; ++p) {
                int s = tid + p * 256;
                int row = s >> 3, ch = s & 7;
                GL2LDS(&W[(size_t)(n0 + row) * K + k0 + (ch ^ (row & 7)) * 8], &Bl[nxt][s * 8]);
            }
        }
        #pragma unroll
        for (int ks = 0; ks < 2; ++ks) {
            bf16x8 af[2], bfr[4];
            #pragma unroll
            for (int mf = 0; mf < 2; ++mf)
                af[mf] = *(const bf16x8*)&Al[cur][SWU(wm + mf * 16 + fr, ks * 4 + fk)];
            #pragma unroll
            for (int nf = 0; nf < 4; ++nf)
                bfr[nf] = *(const bf16x8*)&Bl[cur][SWU(wn + nf * 16 + fr, ks * 4 + fk)];
            #pragma unroll
            for (int mf = 0; mf < 2; ++mf)
                #pragma unroll
                for (int nf = 0; nf < 4; ++nf)
                    acc[mf][nf] = __builtin_amdgcn_mfma_f32_16x16x32_bf16(
                        af[mf], bfr[nf], acc[mf][nf], 0, 0, 0);
        }
        __syncthreads();
    }
    #pragma unroll
    for (int mf = 0; mf < 2; ++mf) {
        #pragma unroll
        for (int nf = 0; nf < 4; ++nf) {
            int col = n0 + wn + nf * 16 + fr;
            float bv = bias[col];
            #pragma unroll
            for (int r = 0; r < 4; ++r) {
                int rowg = m0 + wm + mf * 16 + fk * 4 + r;
                Cout[(size_t)rowg * N + col] = acc[mf][nf][r] + bv;
            }
        }
    }
}

// ---------------------------------------------------------------------------
// Fused 3x depthwise conv1d(k=5) + 3 scalar gates + mD + V-transpose
// (R16 proven version, unchanged).
// ---------------------------------------------------------------------------
__global__ void conv_gate_all(
    const float* __restrict__ xn, u16* __restrict__ pkv,
    u16* __restrict__ vpT,
    const float* __restrict__ WcT,
    const float* __restrict__ Wgq, const float* __restrict__ bgq,
    const float* __restrict__ Wgk, const float* __restrict__ bgk,
    const float* __restrict__ Wgv, const float* __restrict__ bgv,
    const float* __restrict__ WmD, const float* __restrict__ bmD,
    float* __restrict__ mD)
{
    __shared__ u16 lt[4][512];
    const int w = threadIdx.x >> 6, lane = threadIdx.x & 63;
    const int bt = blockIdx.x * 4 + w;
    const int b = bt >> 9, tpos = bt & (NT - 1);
    const int c0 = lane * 8;

    float x[5][8];
    #pragma unroll
    for (int j = 0; j < 5; ++j) {
        int tt = tpos + j - 2;
        if (tt >= 0 && tt < NT) {
            const float4* xp = (const float4*)&xn[((size_t)(b*NT + tt))*NSZ + c0];
            float4 u0 = xp[0], u1 = xp[1];
            x[j][0]=u0.x; x[j][1]=u0.y; x[j][2]=u0.z; x[j][3]=u0.w;
            x[j][4]=u1.x; x[j][5]=u1.y; x[j][6]=u1.z; x[j][7]=u1.w;
        } else {
            #pragma unroll
            for (int i = 0; i < 8; ++i) x[j][i] = 0.f;
        }
    }
    float aq[8] = {}, ak[8] = {}, av[8] = {};
    #pragma unroll
    for (int j = 0; j < 5; ++j) {
        const float* wq = &WcT[j * 512 + c0];
        const float* wk = &WcT[2560 + j * 512 + c0];
        const float* wv = &WcT[5120 + j * 512 + c0];
        float4 q0 = *(const float4*)wq, q1 = *(const float4*)(wq + 4);
        float4 k0 = *(const float4*)wk, k1 = *(const float4*)(wk + 4);
        float4 v0 = *(const float4*)wv, v1 = *(const float4*)(wv + 4);
        float wq8[8] = {q0.x,q0.y,q0.z,q0.w,q1.x,q1.y,q1.z,q1.w};
        float wk8[8] = {k0.x,k0.y,k0.z,k0.w,k1.x,k1.y,k1.z,k1.w};
        float wv8[8] = {v0.x,v0.y,v0.z,v0.w,v1.x,v1.y,v1.z,v1.w};
        #pragma unroll
        for (int i = 0; i < 8; ++i) {
            aq[i] += x[j][i] * wq8[i];
            ak[i] += x[j][i] * wk8[i];
            av[i] += x[j][i] * wv8[i];
        }
    }
    const size_t rb = (size_t)bt * 1536;
    u16x8 q8 = *(const u16x8*)&pkv[rb + c0];
    u16x8 k8 = *(const u16x8*)&pkv[rb + 512 + c0];
    u16x8 v8 = *(const u16x8*)&pkv[rb + 1024 + c0];

    float gql[8], gqh[8], gkl[8], gkh[8], gvl[8], gvh[8];
    {
        float4 a0 = *(const float4*)&Wgq[c0],      a1 = *(const float4*)&Wgq[c0 + 4];
        float4 a2 = *(const float4*)&Wgq[512 + c0], a3 = *(const float4*)&Wgq[512 + c0 + 4];
        gql[0]=a0.x;gql[1]=a0.y;gql[2]=a0.z;gql[3]=a0.w;gql[4]=a1.x;gql[5]=a1.y;gql[6]=a1.z;gql[7]=a1.w;
        gqh[0]=a2.x;gqh[1]=a2.y;gqh[2]=a2.z;gqh[3]=a2.w;gqh[4]=a3.x;gqh[5]=a3.y;gqh[6]=a3.z;gqh[7]=a3.w;
        float4 b0 = *(const float4*)&Wgk[c0],      b1 = *(const float4*)&Wgk[c0 + 4];
        float4 b2 = *(const float4*)&Wgk[512 + c0], b3 = *(const float4*)&Wgk[512 + c0 + 4];
        gkl[0]=b0.x;gkl[1]=b0.y;gkl[2]=b0.z;gkl[3]=b0.w;gkl[4]=b1.x;gkl[5]=b1.y;gkl[6]=b1.z;gkl[7]=b1.w;
        gkh[0]=b2.x;gkh[1]=b2.y;gkh[2]=b2.z;gkh[3]=b2.w;gkh[4]=b3.x;gkh[5]=b3.y;gkh[6]=b3.z;gkh[7]=b3.w;
        float4 c0v = *(const float4*)&Wgv[c0],      c1v = *(const float4*)&Wgv[c0 + 4];
        float4 c2v = *(const float4*)&Wgv[512 + c0], c3v = *(const float4*)&Wgv[512 + c0 + 4];
        gvl[0]=c0v.x;gvl[1]=c0v.y;gvl[2]=c0v.z;gvl[3]=c0v.w;gvl[4]=c1v.x;gvl[5]=c1v.y;gvl[6]=c1v.z;gvl[7]=c1v.w;
        gvh[0]=c2v.x;gvh[1]=c2v.y;gvh[2]=c2v.z;gvh[3]=c2v.w;gvh[4]=c3v.x;gvh[5]=c3v.y;gvh[6]=c3v.z;gvh[7]=c3v.w;
    }
    float sq = 0.f, sk = 0.f, sv = 0.f;
    #pragma unroll
    for (int i = 0; i < 8; ++i) {
        sq += b2f(q8[i]) * gql[i] + aq[i] * gqh[i];
        sk += b2f(k8[i]) * gkl[i] + ak[i] * gkh[i];
        sv += b2f(v8[i]) * gvl[i] + av[i] * gvh[i];
    }
    #pragma unroll
    for (int o = 1; o < 64; o <<= 1) {
        sq += __shfl_xor(sq, o, 64);
        sk += __shfl_xor(sk, o, 64);
        sv += __shfl_xor(sv, o, 64);
    }
    float gq = 1.f / (1.f + expf(-(sq + bgq[0])));
    float gk = 1.f / (1.f + expf(-(sk + bgk[0])));
    float gv = 1.f / (1.f + expf(-(sv + bgv[0])));

    float wm8[8];
    {
        float4 m0 = *(const float4*)&WmD[c0], m1 = *(const float4*)&WmD[c0 + 4];
        wm8[0]=m0.x;wm8[1]=m0.y;wm8[2]=m0.z;wm8[3]=m0.w;wm8[4]=m1.x;wm8[5]=m1.y;wm8[6]=m1.z;wm8[7]=m1.w;
    }
    u16x8 oq8, ok8, ov8;
    float smd = 0.f;
    #pragma unroll
    for (int i = 0; i < 8; ++i) {
        float oq = (1.f - gq) * b2f(q8[i]) + gq * aq[i];
        oq8[i] = f2b(oq);
        ok8[i] = f2b((1.f - gk) * b2f(k8[i]) + gk * ak[i]);
        ov8[i] = f2b((1.f - gv) * b2f(v8[i]) + gv * av[i]);
        smd += oq * wm8[i];
    }
    *(u16x8*)&pkv[rb + c0]       = oq8;
    *(u16x8*)&pkv[rb + 512 + c0] = ok8;
    *(u16x8*)&lt[w][c0] = ov8;
    #pragma unroll
    for (int o = 1; o < 64; o <<= 1) smd += __shfl_xor(smd, o, 64);
    if (lane == 0)
        mD[bt] = C_D0 + 2.f * C_STD * tanhf((smd + bmD[0]) / C_GAMMA);

    __syncthreads();
    const int t0g = (blockIdx.x * 4) & (NT - 1);
    const int b0g = (blockIdx.x * 4) >> 9;
    #pragma unroll
    for (int p2 = 0; p2 < 2; ++p2) {
        int c = threadIdx.x + p2 * 256;
        u16x4 o4;
        o4[0] = lt[0][c]; o4[1] = lt[1][c]; o4[2] = lt[2][c]; o4[3] = lt[3][c];
        *(u16x4*)&vpT[((size_t)(b0g * 512 + c)) * NT + t0g] = o4;
    }
}

// ---------------------------------------------------------------------------
// MFMA flash attention — R14 single-pass version (unchanged).
// ---------------------------------------------------------------------------
__global__ __launch_bounds__(256) void attn_mfma(
    const u16* __restrict__ pkv, const u16* __restrict__ vpT,
    const float* __restrict__ mD, const int* __restrict__ mask,
    const float* __restrict__ rpe, u16* __restrict__ cxh)
{
    __shared__ __align__(16) char smem[70400];
    u16*  Ql    = (u16*)(smem);
    u16*  Kl    = (u16*)(smem + 8192);
    u16*  Vl    = (u16*)(smem + 24576);
    u16*  Pl    = (u16*)(smem + 40960);
    u16*  rpk   = (u16*)(smem + 40960);
    u16*  wA16  = (u16*)(smem + 57344);
    u16*  qdrl  = (u16*)(smem + 65536);
    float* inv2s= (float*)(smem + 70144);

    const int tid  = threadIdx.x;
    const int lane = tid & 63;
    const int w    = tid >> 6;
    const int wq0  = w * 16;
    const int fr   = lane & 15;
    const int fq   = lane >> 4;
    const int b    = blockIdx.x >> 3;
    const int h    = blockIdx.x & 7;
    const int q0   = blockIdx.y * 64;

    const size_t qbase  = ((size_t)(b*NT + q0)) * 1536 + h * NHD;
    const size_t kbaseg = ((size_t)b * NT) * 1536 + 512 + h * NHD;
    const size_t vbaseg = ((size_t)((b*NH + h) * NHD)) * NT;

    int Lm = 512;
    #pragma unroll
    for (int j = 0; j < 8; ++j) {
        if (mask[b * NT + lane + 64 * j]) Lm = min(Lm, lane + 64 * j);
    }
    #pragma unroll
    for (int o = 1; o < 64; o <<= 1) Lm = min(Lm, __shfl_xor(Lm, o, 64));
    const int L = Lm;
    const int w0 = max(0, min(q0 - 32, L - 128));

    #pragma unroll
    for (int p = 0; p < 2; ++p) {
        int s = tid + p * 256;
        int r = s >> 3, c = s & 7;
        u16x8 v = *(const u16x8*)(pkv + qbase + (size_t)r * 1536 + c * 8);
        *(u16x8*)(Ql + SWU(r, c)) = v;
    }
    #pragma unroll
    for (int p = 0; p < 4; ++p) {
        int s = tid + p * 256;
        int r = s >> 3, c = s & 7;
        u16x8 v = *(const u16x8*)(pkv + kbaseg + (size_t)(w0 + r) * 1536 + c * 8);
        *(u16x8*)(Kl + SWU(r, c)) = v;
    }
    #pragma unroll
    for (int p = 0; p < 4; ++p) {
        int s = tid + p * 256;
        int d = s >> 4, cc = s & 15;
        u16x8 v = *(const u16x8*)(vpT + vbaseg + (size_t)d * NT + w0 + cc * 8);
        *(u16x8*)(Vl + SWU16(d, cc)) = v;
    }
    for (int idx = tid; idx < 264; idx += 256) {
        int r = idx >> 3, c = idx & 7;
        float4 f0 = *(const float4*)&rpe[r * 128 + c * 8];
        float4 f1 = *(const float4*)&rpe[r * 128 + c * 8 + 4];
        u16x8 vv;
        vv[0]=f2b(f0.x); vv[1]=f2b(f0.y); vv[2]=f2b(f0.z); vv[3]=f2b(f0.w);
        vv[4]=f2b(f1.x); vv[5]=f2b(f1.y); vv[6]=f2b(f1.z); vv[7]=f2b(f1.w);
        *(u16x8*)(rpk + SWU(r, c)) = vv;
    }
    if (tid < 120) {
        u16x8 vv = {0,0,0,0,0,0,0,0};
        *(u16x8*)(rpk + (((33 + (tid >> 3)) * 8) + (tid & 7)) * 8) = vv;
    }
    {
        u16x8 z = {0,0,0,0,0,0,0,0};
        #pragma unroll
        for (int p = 0; p < 2; ++p) *(u16x8*)(wA16 + (tid + p * 256) * 8) = z;
    }
    if (tid < 64) {
        float md = mD[b * NT + q0 + tid];
        inv2s[tid] = 2.f * LOG2E / (md * md);
    }
    __syncthreads();                        // (P0)

    bf16x8 aq0 = *(const bf16x8*)(Ql + SWU(wq0 + fr, fq));
    bf16x8 aq1 = *(const bf16x8*)(Ql + SWU(wq0 + fr, 4 + fq));

    {
        f32x4 qd[3] = {};
        #pragma unroll
        for (int nf = 0; nf < 3; ++nf) {
            bf16x8 b0 = *(const bf16x8*)(rpk + SWU(nf * 16 + fr, fq));
            bf16x8 b1 = *(const bf16x8*)(rpk + SWU(nf * 16 + fr, 4 + fq));
            qd[nf] = __builtin_amdgcn_mfma_f32_16x16x32_bf16(aq0, b0, qd[nf], 0, 0, 0);
            qd[nf] = __builtin_amdgcn_mfma_f32_16x16x32_bf16(aq1, b1, qd[nf], 0, 0, 0);
        }
        #pragma unroll
        for (int nf = 0; nf < 3; ++nf) {
            int rd = nf * 16 + fr;
            if (rd < 33) {
                #pragma unroll
                for (int r = 0; r < 4; ++r)
                    qdrl[(wq0 + fq * 4 + r) * 36 + rd] = f2b(qd[nf][r]);
            }
        }
    }
    __syncthreads();                        // (P1)

    f32x4 s_[8] = {};
    #pragma unroll
    for (int nf = 0; nf < 8; ++nf) {
        bf16x8 b0 = *(const bf16x8*)(Kl + SWU(nf * 16 + fr, fq));
        bf16x8 b1 = *(const bf16x8*)(Kl + SWU(nf * 16 + fr, 4 + fq));
        s_[nf] = __builtin_amdgcn_mfma_f32_16x16x32_bf16(aq0, b0, s_[nf], 0, 0, 0);
        s_[nf] = __builtin_amdgcn_mfma_f32_16x16x32_bf16(aq1, b1, s_[nf], 0, 0, 0);
    }

    float li[4];
    #pragma unroll
    for (int r = 0; r < 4; ++r) {
        const int lq = wq0 + fq * 4 + r;
        const int qg = q0 + lq;
        const float iv = inv2s[lq];
        float sc[8];
        float mx = NEGINF;
        #pragma unroll
        for (int nf = 0; nf < 8; ++nf) {
            const int kg = w0 + nf * 16 + fr;
            float v;
            if (kg >= L) v = NEGINF;
            else {
                int rd = min(max(kg - qg, -MAXR), MAXR) + MAXR;
                float qr = b2f(qdrl[lq * 36 + rd]);
                float fd = (float)(qg - kg);
                v = (s_[nf][r] + qr) * C1F - fd * fd * iv;
            }
            sc[nf] = v;
            mx = fmaxf(mx, v);
        }
        mx = fmaxf(mx, __shfl_xor(mx, 1, 64));
        mx = fmaxf(mx, __shfl_xor(mx, 2, 64));
        mx = fmaxf(mx, __shfl_xor(mx, 4, 64));
        mx = fmaxf(mx, __shfl_xor(mx, 8, 64));
        float rsum = 0.f, ls = 0.f, rs = 0.f;
        #pragma unroll
        for (int nf = 0; nf < 8; ++nf) {
            const int kg = w0 + nf * 16 + fr;
            float pv = exp2_fast(sc[nf] - mx);
            s_[nf][r] = pv;
            rsum += pv;
            int d = kg - qg;
            if (d <= -MAXR) ls += pv;
            else if (d >= MAXR) rs += pv;
            else {
                int bkt = d + MAXR;
                wA16[(lq * 8 + ((bkt >> 3) ^ (lq & 7))) * 8 + (bkt & 7)] = f2b(pv);
            }
        }
        rsum += __shfl_xor(rsum, 1, 64); rsum += __shfl_xor(rsum, 2, 64);
        rsum += __shfl_xor(rsum, 4, 64); rsum += __shfl_xor(rsum, 8, 64);
        ls += __shfl_xor(ls, 1, 64); ls += __shfl_xor(ls, 2, 64);
        ls += __shfl_xor(ls, 4, 64); ls += __shfl_xor(ls, 8, 64);
        rs += __shfl_xor(rs, 1, 64); rs += __shfl_xor(rs, 2, 64);
        rs += __shfl_xor(rs, 4, 64); rs += __shfl_xor(rs, 8, 64);
        li[r] = rsum;
        if (fr == 0) {
            wA16[(lq * 8 + (0 ^ (lq & 7))) * 8 + 0] = f2b(ls);
            wA16[(lq * 8 + (4 ^ (lq & 7))) * 8 + 0] = f2b(rs);
        }
    }

    #pragma unroll
    for (int r = 0; r < 4; ++r) {
        int lq = wq0 + fq * 4 + r;
        #pragma unroll
        for (int nf = 0; nf < 8; ++nf) {
            int k = nf * 16 + fr;
            int cc = k >> 3;
            Pl[(lq * 16 + (cc ^ (lq & 7))) * 8 + (k & 7)] = f2b(s_[nf][r]);
        }
    }

    f32x4 O[4] = {};
    #pragma unroll
    for (int ks = 0; ks < 4; ++ks) {
        bf16x8 ap = *(const bf16x8*)(Pl + ((wq0 + fr) * 16 + ((ks * 4 + fq) ^ (fr & 7))) * 8);
        #pragma unroll
        for (int nf = 0; nf < 4; ++nf) {
            bf16x8 vf = *(const bf16x8*)(Vl + ((nf * 16 + fr) * 16 + ((ks * 4 + fq) ^ (fr & 7))) * 8);
            O[nf] = __builtin_amdgcn_mfma_f32_16x16x32_bf16(ap, vf, O[nf], 0, 0, 0);
        }
    }
    __syncthreads();   // (E1)

    #pragma unroll
    for (int p = 0; p < 2; ++p) {
        int s = tid + p * 256;
        int d = s >> 3, cs = s & 7;
        u16x8 vv;
        #pragma unroll
        for (int j = 0; j < 8; ++j) {
            int rd = cs * 8 + j;
            vv[j] = (rd < 33) ? f2b(rpe[rd * 128 + 64 + d]) : (u16)0;
        }
        *(u16x8*)(Vl + SWU(d, cs)) = vv;
    }
    __syncthreads();   // (E2)

    {
        bf16x8 aw0 = *(const bf16x8*)(wA16 + SWU(wq0 + fr, fq));
        bf16x8 aw1 = *(const bf16x8*)(wA16 + SWU(wq0 + fr, 4 + fq));
        #pragma unroll
        for (int nf = 0; nf < 4; ++nf) {
            bf16x8 b0 = *(const bf16x8*)(Vl + SWU(nf * 16 + fr, fq));
            bf16x8 b1 = *(const bf16x8*)(Vl + SWU(nf * 16 + fr, 4 + fq));
            O[nf] = __builtin_amdgcn_mfma_f32_16x16x32_bf16(aw0, b0, O[nf], 0, 0, 0);
            O[nf] = __builtin_amdgcn_mfma_f32_16x16x32_bf16(aw1, b1, O[nf], 0, 0, 0);
        }
    }
    float invl[4];
    #pragma unroll
    for (int r = 0; r < 4; ++r) invl[r] = 1.f / li[r];
    #pragma unroll
    for (int r = 0; r < 4; ++r) {
        int lq = wq0 + fq * 4 + r;
        #pragma unroll
        for (int nf = 0; nf < 4; ++nf)
            Pl[lq * 64 + nf * 16 + fr] = f2b(O[nf][r] * invl[r]);
    }
    __syncthreads();   // (E3)
    #pragma unroll
    for (int j = 0; j < 2; ++j) {
        int s = w * 128 + j * 64 + lane;
        int rr = s >> 3, c8 = s & 7;
        u16x8 vv = *(const u16x8*)(Pl + rr * 64 + c8 * 8);
        *(u16x8*)&cxh[((size_t)(b*NT + q0 + rr)) * 512 + h * NHD + c8 * 8] = vv;
    }
}

// ---------------------------------------------------------------------------
extern "C" void kernel_launch(void* const* d_in, const int* in_sizes, int n_in,
                              void* d_out, int out_size, void* d_ws, size_t ws_size,
                              hipStream_t stream) {
    const float* key   = (const float*)d_in[0];
    const float* value = (const float*)d_in[1];
    const float* query = (const float*)d_in[2];
    const int*   mask  = (const int*)d_in[3];
    const float* Wq  = (const float*)d_in[4];
    const float* bq  = (const float*)d_in[5];
    const float* Wk  = (const float*)d_in[6];
    const float* bk  = (const float*)d_in[7];
    const float* Wv  = (const float*)d_in[8];
    const float* bv  = (const float*)d_in[9];
    const float* Wcq = (const float*)d_in[10];
    const float* Wck = (const float*)d_in[11];
    const float* Wcv = (const float*)d_in[12];
    const float* Wgq = (const float*)d_in[13];
    const float* bgq = (const float*)d_in[14];
    const float* Wgk = (const float*)d_in[15];
    const float* bgk = (const float*)d_in[16];
    const float* Wgv = (const float*)d_in[17];
    const float* bgv = (const float*)d_in[18];
    const float* WmD = (const float*)d_in[19];
    const float* bmD = (const float*)d_in[20];
    const float* rpe = (const float*)d_in[21];
    const float* Wo  = (const float*)d_in[22];
    const float* bo  = (const float*)d_in[23];
    float* out = (float*)d_out;

    const size_t NTOK = (size_t)NB * NT;            // 8192
    const size_t NE   = NTOK * NSZ;                 // 4,194,304
    const size_t NW   = (size_t)NSZ * NSZ;          // 262,144

    u16* ws16 = (u16*)d_ws;
    u16* pkv  = ws16;                // (8192, 1536) q|k|v
    u16* wcat = pkv + NTOK * 1536;   // 3 x (512,512)
    u16* woh  = wcat + 3 * NW;
    u16* vpT  = woh + NW;            // (16*8*64, 512)
    u16* cxh  = vpT + NE;            // (8192, 512)
    float* mDb = (float*)(cxh + NE);
    float* WcT = mDb + NTOK;         // 3 x (5,512) fp32

    cvt4_bf16<<<dim3((unsigned)(NW/8/256), 4), 256, 0, stream>>>(
        Wq, Wk, Wv, Wo, wcat, wcat + NW, wcat + 2*NW, woh, (int)NW);
    wprep<<<dim3(10, 3), 256, 0, stream>>>(Wcq, Wck, Wcv, WcT);

    gemm_qkv<<<dim3(128, 4, 3), 256, 0, stream>>>(
        query, key, value, wcat, bq, bk, bv, pkv);

    conv_gate_all<<<(int)(NTOK / 4), 256, 0, stream>>>(
        key, pkv, vpT, WcT, Wgq, bgq, Wgk, bgk, Wgv, bgv, WmD, bmD, mDb);

    attn_mfma<<<dim3(128, 8), 256, 0, stream>>>(pkv, vpT, mDb, mask, rpe, cxh);

    gemm_out<<<dim3(128, 4), 256, 0, stream>>>(cxh, woh, bo, out, (int)NTOK, NSZ, NSZ);
}